// Round 2
// baseline (5371.712 us; speedup 1.0000x reference)
//
#include <hip/hip_runtime.h>
#include <math.h>

#define ROWS 4096   // B * L
#define LSEQ 2048
#define DM   512
#define DI   1024

__device__ __forceinline__ float siluf(float v) { return v / (1.f + expf(-v)); }
__device__ __forceinline__ float softplusf(float v) {
    return fmaxf(v, 0.f) + log1pf(expf(-fabsf(v)));
}

// ---------------- LayerNorm: one block per row of 512 ----------------
__global__ __launch_bounds__(256) void ln_kernel(const float* __restrict__ x,
                                                 const float* __restrict__ w,
                                                 const float* __restrict__ b,
                                                 float* __restrict__ out) {
    int row = blockIdx.x;
    int tid = threadIdx.x;
    const float* xr = x + (size_t)row * DM;
    float v0 = xr[tid], v1 = xr[tid + 256];
    float sum = v0 + v1, sq = v0 * v0 + v1 * v1;
    for (int o = 32; o > 0; o >>= 1) {
        sum += __shfl_down(sum, o);
        sq  += __shfl_down(sq, o);
    }
    __shared__ float s1[4], s2[4];
    int wid = tid >> 6, lane = tid & 63;
    if (lane == 0) { s1[wid] = sum; s2[wid] = sq; }
    __syncthreads();
    sum = s1[0] + s1[1] + s1[2] + s1[3];
    sq  = s2[0] + s2[1] + s2[2] + s2[3];
    float mu  = sum * (1.f / DM);
    float var = sq * (1.f / DM) - mu * mu;
    float r   = rsqrtf(var + 1e-5f);
    out[(size_t)row * DM + tid]       = (v0 - mu) * r * w[tid] + b[tid];
    out[(size_t)row * DM + tid + 256] = (v1 - mu) * r * w[tid + 256] + b[tid + 256];
}

// ---------------- RMSNorm: one block per row of 512 ----------------
__global__ __launch_bounds__(256) void rms_kernel(const float* __restrict__ x,
                                                  const float* __restrict__ w,
                                                  float* __restrict__ out) {
    int row = blockIdx.x;
    int tid = threadIdx.x;
    const float* xr = x + (size_t)row * DM;
    float v0 = xr[tid], v1 = xr[tid + 256];
    float sq = v0 * v0 + v1 * v1;
    for (int o = 32; o > 0; o >>= 1) sq += __shfl_down(sq, o);
    __shared__ float s2[4];
    int wid = tid >> 6, lane = tid & 63;
    if (lane == 0) s2[wid] = sq;
    __syncthreads();
    sq = s2[0] + s2[1] + s2[2] + s2[3];
    float r = rsqrtf(sq * (1.f / DM) + 1e-5f);
    out[(size_t)row * DM + tid]       = v0 * r * w[tid];
    out[(size_t)row * DM + tid + 256] = v1 * r * w[tid + 256];
}

// ---------------- Generic fp32 tiled GEMM: C = A @ W^T (+bias)(+res)(+relu)
// A: (M,K) lda; W: (N,K) ldb; C: (M,N) ldc. All tile dims divide evenly.
template <int ACT, bool BIAS, bool RES>
__global__ __launch_bounds__(256) void gemm_kernel(
    const float* __restrict__ A, const float* __restrict__ W,
    const float* __restrict__ bias, const float* __restrict__ res,
    float* __restrict__ C, int M, int N, int K, int lda, int ldb, int ldc) {
    __shared__ float As[16][65];
    __shared__ float Bs[16][65];
    const int tid = threadIdx.x;
    const int tx = tid & 15, ty = tid >> 4;
    const int bm = blockIdx.y * 64, bn = blockIdx.x * 64;
    float acc[4][4] = {};
    for (int k0 = 0; k0 < K; k0 += 16) {
#pragma unroll
        for (int l = 0; l < 4; ++l) {
            int id = tid + l * 256;
            int r = id >> 4, c = id & 15;
            As[c][r] = A[(size_t)(bm + r) * lda + k0 + c];
            Bs[c][r] = W[(size_t)(bn + r) * ldb + k0 + c];
        }
        __syncthreads();
#pragma unroll
        for (int k = 0; k < 16; ++k) {
            float a4[4], b4[4];
#pragma unroll
            for (int i = 0; i < 4; ++i) a4[i] = As[k][ty * 4 + i];
#pragma unroll
            for (int j = 0; j < 4; ++j) b4[j] = Bs[k][tx * 4 + j];
#pragma unroll
            for (int i = 0; i < 4; ++i)
#pragma unroll
                for (int j = 0; j < 4; ++j)
                    acc[i][j] = fmaf(a4[i], b4[j], acc[i][j]);
        }
        __syncthreads();
    }
#pragma unroll
    for (int i = 0; i < 4; ++i) {
        int row = bm + ty * 4 + i;
#pragma unroll
        for (int j = 0; j < 4; ++j) {
            int col = bn + tx * 4 + j;
            float v = acc[i][j];
            if (BIAS) v += bias[col];
            if (RES) v += res[(size_t)row * ldc + col];
            if (ACT == 1) v = fmaxf(v, 0.f);
            C[(size_t)row * ldc + col] = v;
        }
    }
}

// ---------------- causal depthwise conv (D_CONV=4) + SiLU ----------------
// in: xz (ROWS, 2048), cols [0,1024) are the conv channel; out: (ROWS, 1024)
__global__ __launch_bounds__(256) void conv_silu_kernel(
    const float* __restrict__ xz, const float* __restrict__ cw,
    const float* __restrict__ cb, float* __restrict__ out) {
    int idx = blockIdx.x * blockDim.x + threadIdx.x;  // ROWS*DI
    int c = idx & (DI - 1);
    int row = idx >> 10;
    int t = row & (LSEQ - 1);
    float acc = cb[c];
#pragma unroll
    for (int k = 0; k < 4; ++k) {
        int st = t + k - 3;
        if (st >= 0) acc = fmaf(cw[c * 4 + k], xz[(size_t)(row + k - 3) * 2048 + c], acc);
    }
    out[idx] = siluf(acc);
}

// ---------------- fused selective scan + C-contraction + D-skip + gate ----
// thread = (b, e, n): n = lane%16. Per t: h = exp(softplus(dp)*A)*h + d*xc*B;
// y = sum_n h*C + Dp*xc; yg = y * silu(z).
__global__ __launch_bounds__(256) void scan_kernel(
    const float* __restrict__ delta_pre,  // (ROWS, DI)
    const float* __restrict__ xc,         // (ROWS, DI)
    const float* __restrict__ dbc,        // (ROWS, 64): [.,32:48]=B, [.,48:64]=C
    const float* __restrict__ xz,         // (ROWS, 2048): cols 1024+ are z
    const float* __restrict__ A_log,      // (DI, 16)
    const float* __restrict__ Dp,         // (DI)
    float* __restrict__ yg) {             // (ROWS, DI)
    int tid = blockIdx.x * blockDim.x + threadIdx.x;  // 2*DI*16 = 32768
    int n = tid & 15;
    int e = (tid >> 4) & (DI - 1);
    int b = tid >> 14;
    float Aen = -expf(A_log[e * 16 + n]);
    float Dpe = Dp[e];
    float h = 0.f;
    int rowbase = b * LSEQ;
    for (int t = 0; t < LSEQ; ++t) {
        int row = rowbase + t;
        float dp  = delta_pre[(size_t)row * DI + e];
        float d   = softplusf(dp);
        float xcv = xc[(size_t)row * DI + e];
        float Bv  = dbc[(size_t)row * 64 + 32 + n];
        float Cv  = dbc[(size_t)row * 64 + 48 + n];
        float dA  = expf(d * Aen);
        h = fmaf(dA, h, d * xcv * Bv);
        float p = h * Cv;
        p += __shfl_xor(p, 1, 16);
        p += __shfl_xor(p, 2, 16);
        p += __shfl_xor(p, 4, 16);
        p += __shfl_xor(p, 8, 16);
        if (n == 0) {
            float z = xz[(size_t)row * 2048 + 1024 + e];
            float y = p + Dpe * xcv;
            yg[(size_t)row * DI + e] = y * siluf(z);
        }
    }
}

// ---------------- elementwise add ----------------
__global__ __launch_bounds__(256) void add_kernel(const float* __restrict__ a,
                                                  const float* __restrict__ b,
                                                  float* __restrict__ c, int n) {
    int i = blockIdx.x * blockDim.x + threadIdx.x;
    if (i < n) c[i] = a[i] + b[i];
}

extern "C" void kernel_launch(void* const* d_in, const int* in_sizes, int n_in,
                              void* d_out, int out_size, void* d_ws, size_t ws_size,
                              hipStream_t stream) {
    const float* x    = (const float*)d_in[0];
    const float* ipw  = (const float*)d_in[1];
    const float* cw   = (const float*)d_in[2];
    const float* cb   = (const float*)d_in[3];
    const float* xpw  = (const float*)d_in[4];
    const float* dtw  = (const float*)d_in[5];
    const float* dtb  = (const float*)d_in[6];
    const float* alog = (const float*)d_in[7];
    const float* dpar = (const float*)d_in[8];
    const float* opw  = (const float*)d_in[9];
    const float* rmsw = (const float*)d_in[10];
    const float* ln1w = (const float*)d_in[11];
    const float* ln1b = (const float*)d_in[12];
    const float* ln2w = (const float*)d_in[13];
    const float* ln2b = (const float*)d_in[14];
    const float* fw1  = (const float*)d_in[15];
    const float* fb1  = (const float*)d_in[16];
    const float* fw2  = (const float*)d_in[17];
    const float* fb2  = (const float*)d_in[18];
    const float* finw = (const float*)d_in[19];
    const float* finb = (const float*)d_in[20];
    float* out = (float*)d_out;

    float* ws = (float*)d_ws;
    float* h     = ws;                          // 2M floats
    float* hn    = h   + (size_t)ROWS * DM;     // 2M
    float* xz    = hn  + (size_t)ROWS * DM;     // 8M
    float* xc    = xz  + (size_t)ROWS * 2048;   // 4M (reused as x2 later)
    float* dbc   = xc  + (size_t)ROWS * DI;     // 256K
    float* delta = dbc + (size_t)ROWS * 64;     // 4M
    float* yg    = delta + (size_t)ROWS * DI;   // 4M (reused as x3 later)
    // total ≈ 24.25M floats ≈ 97 MB

    // 1. h = LN1(x)
    ln_kernel<<<ROWS, 256, 0, stream>>>(x, ln1w, ln1b, h);

    for (int i = 0; i < 2; ++i) {
        const float* ipw_i  = ipw  + (size_t)i * 2048 * 512;
        const float* cw_i   = cw   + (size_t)i * DI * 4;
        const float* cb_i   = cb   + (size_t)i * DI;
        const float* xpw_i  = xpw  + (size_t)i * 64 * DI;
        const float* dtw_i  = dtw  + (size_t)i * DI * 32;
        const float* dtb_i  = dtb  + (size_t)i * DI;
        const float* alog_i = alog + (size_t)i * DI * 16;
        const float* dp_i   = dpar + (size_t)i * DI;
        const float* opw_i  = opw  + (size_t)i * DM * DI;
        const float* rms_i  = rmsw + (size_t)i * DM;

        // hn = RMS(h)
        rms_kernel<<<ROWS, 256, 0, stream>>>(h, rms_i, hn);
        // xz = hn @ ipw^T   (4096 x 2048 x 512)
        gemm_kernel<0, false, false><<<dim3(2048 / 64, ROWS / 64), 256, 0, stream>>>(
            hn, ipw_i, nullptr, nullptr, xz, ROWS, 2048, 512, 512, 512, 2048);
        // xc = silu(conv(xz[:, :1024]))
        conv_silu_kernel<<<ROWS * DI / 256, 256, 0, stream>>>(xz, cw_i, cb_i, xc);
        // dbc = xc @ xpw^T  (4096 x 64 x 1024)
        gemm_kernel<0, false, false><<<dim3(1, ROWS / 64), 256, 0, stream>>>(
            xc, xpw_i, nullptr, nullptr, dbc, ROWS, 64, 1024, 1024, 1024, 64);
        // delta_pre = dbc[:, :32] @ dtw^T + dtb  (4096 x 1024 x 32)
        gemm_kernel<0, true, false><<<dim3(1024 / 64, ROWS / 64), 256, 0, stream>>>(
            dbc, dtw_i, dtb_i, nullptr, delta, ROWS, 1024, 32, 64, 32, 1024);
        // yg = scan(...)
        scan_kernel<<<128, 256, 0, stream>>>(delta, xc, dbc, xz, alog_i, dp_i, yg);
        // h = h + yg @ opw^T  (4096 x 512 x 1024)
        gemm_kernel<0, false, true><<<dim3(DM / 64, ROWS / 64), 256, 0, stream>>>(
            yg, opw_i, nullptr, h, h, ROWS, DM, DI, DI, DI, DM);
    }

    // x2 = x + h  (store in xc slot)
    float* x2 = xc;
    add_kernel<<<ROWS * DM / 256, 256, 0, stream>>>(x, h, x2, ROWS * DM);
    // hn = LN2(x2)
    ln_kernel<<<ROWS, 256, 0, stream>>>(x2, ln2w, ln2b, hn);
    // mid = relu(hn @ fw1^T + fb1)  (4096 x 1024 x 512), store in xz slot
    float* mid = xz;
    gemm_kernel<1, true, false><<<dim3(DI / 64, ROWS / 64), 256, 0, stream>>>(
        hn, fw1, fb1, nullptr, mid, ROWS, DI, DM, DM, DM, DI);
    // x3 = x2 + mid @ fw2^T + fb2  (4096 x 512 x 1024), store in yg slot
    float* x3 = yg;
    gemm_kernel<0, true, true><<<dim3(DM / 64, ROWS / 64), 256, 0, stream>>>(
        mid, fw2, fb2, x2, x3, ROWS, DM, DI, DI, DI, DM);
    // out = x3 @ finw^T + finb  (4096 x 512 x 512)
    gemm_kernel<0, true, false><<<dim3(DM / 64, ROWS / 64), 256, 0, stream>>>(
        x3, finw, finb, nullptr, out, ROWS, DM, DM, DM, DM, DM);
}

// Round 3
// 2312.996 us; speedup vs baseline: 2.3224x; 2.3224x over previous
//
#include <hip/hip_runtime.h>
#include <math.h>

#define ROWS 4096   // B * L
#define LSEQ 2048
#define DM   512
#define DI   1024
#define NCH  16            // scan chunks per sequence
#define CHT  (LSEQ / NCH)  // 128 timesteps per chunk

__device__ __forceinline__ float siluf(float v) { return v / (1.f + expf(-v)); }
__device__ __forceinline__ float softplusf(float v) {
    return fmaxf(v, 0.f) + log1pf(expf(-fabsf(v)));
}

// ---------------- LayerNorm: one block per row of 512 ----------------
__global__ __launch_bounds__(256) void ln_kernel(const float* __restrict__ x,
                                                 const float* __restrict__ w,
                                                 const float* __restrict__ b,
                                                 float* __restrict__ out) {
    int row = blockIdx.x;
    int tid = threadIdx.x;
    const float* xr = x + (size_t)row * DM;
    float v0 = xr[tid], v1 = xr[tid + 256];
    float sum = v0 + v1, sq = v0 * v0 + v1 * v1;
    for (int o = 32; o > 0; o >>= 1) {
        sum += __shfl_down(sum, o);
        sq  += __shfl_down(sq, o);
    }
    __shared__ float s1[4], s2[4];
    int wid = tid >> 6, lane = tid & 63;
    if (lane == 0) { s1[wid] = sum; s2[wid] = sq; }
    __syncthreads();
    sum = s1[0] + s1[1] + s1[2] + s1[3];
    sq  = s2[0] + s2[1] + s2[2] + s2[3];
    float mu  = sum * (1.f / DM);
    float var = sq * (1.f / DM) - mu * mu;
    float r   = rsqrtf(var + 1e-5f);
    out[(size_t)row * DM + tid]       = (v0 - mu) * r * w[tid] + b[tid];
    out[(size_t)row * DM + tid + 256] = (v1 - mu) * r * w[tid + 256] + b[tid + 256];
}

// ---------------- RMSNorm: one block per row of 512 ----------------
__global__ __launch_bounds__(256) void rms_kernel(const float* __restrict__ x,
                                                  const float* __restrict__ w,
                                                  float* __restrict__ out) {
    int row = blockIdx.x;
    int tid = threadIdx.x;
    const float* xr = x + (size_t)row * DM;
    float v0 = xr[tid], v1 = xr[tid + 256];
    float sq = v0 * v0 + v1 * v1;
    for (int o = 32; o > 0; o >>= 1) sq += __shfl_down(sq, o);
    __shared__ float s2[4];
    int wid = tid >> 6, lane = tid & 63;
    if (lane == 0) s2[wid] = sq;
    __syncthreads();
    sq = s2[0] + s2[1] + s2[2] + s2[3];
    float r = rsqrtf(sq * (1.f / DM) + 1e-5f);
    out[(size_t)row * DM + tid]       = v0 * r * w[tid];
    out[(size_t)row * DM + tid + 256] = v1 * r * w[tid + 256];
}

// ---------------- Generic fp32 tiled GEMM: C = A @ W^T (+bias)(+res)(+relu)
template <int ACT, bool BIAS, bool RES>
__global__ __launch_bounds__(256) void gemm_kernel(
    const float* __restrict__ A, const float* __restrict__ W,
    const float* __restrict__ bias, const float* __restrict__ res,
    float* __restrict__ C, int M, int N, int K, int lda, int ldb, int ldc) {
    __shared__ float As[16][65];
    __shared__ float Bs[16][65];
    const int tid = threadIdx.x;
    const int tx = tid & 15, ty = tid >> 4;
    const int bm = blockIdx.y * 64, bn = blockIdx.x * 64;
    float acc[4][4] = {};
    for (int k0 = 0; k0 < K; k0 += 16) {
#pragma unroll
        for (int l = 0; l < 4; ++l) {
            int id = tid + l * 256;
            int r = id >> 4, c = id & 15;
            As[c][r] = A[(size_t)(bm + r) * lda + k0 + c];
            Bs[c][r] = W[(size_t)(bn + r) * ldb + k0 + c];
        }
        __syncthreads();
#pragma unroll
        for (int k = 0; k < 16; ++k) {
            float a4[4], b4[4];
#pragma unroll
            for (int i = 0; i < 4; ++i) a4[i] = As[k][ty * 4 + i];
#pragma unroll
            for (int j = 0; j < 4; ++j) b4[j] = Bs[k][tx * 4 + j];
#pragma unroll
            for (int i = 0; i < 4; ++i)
#pragma unroll
                for (int j = 0; j < 4; ++j)
                    acc[i][j] = fmaf(a4[i], b4[j], acc[i][j]);
        }
        __syncthreads();
    }
#pragma unroll
    for (int i = 0; i < 4; ++i) {
        int row = bm + ty * 4 + i;
#pragma unroll
        for (int j = 0; j < 4; ++j) {
            int col = bn + tx * 4 + j;
            float v = acc[i][j];
            if (BIAS) v += bias[col];
            if (RES) v += res[(size_t)row * ldc + col];
            if (ACT == 1) v = fmaxf(v, 0.f);
            C[(size_t)row * ldc + col] = v;
        }
    }
}

// ---------------- causal depthwise conv (D_CONV=4) + SiLU ----------------
__global__ __launch_bounds__(256) void conv_silu_kernel(
    const float* __restrict__ xz, const float* __restrict__ cw,
    const float* __restrict__ cb, float* __restrict__ out) {
    int idx = blockIdx.x * blockDim.x + threadIdx.x;  // ROWS*DI
    int c = idx & (DI - 1);
    int row = idx >> 10;
    int t = row & (LSEQ - 1);
    float acc = cb[c];
#pragma unroll
    for (int k = 0; k < 4; ++k) {
        int st = t + k - 3;
        if (st >= 0) acc = fmaf(cw[c * 4 + k], xz[(size_t)(row + k - 3) * 2048 + c], acc);
    }
    out[idx] = siluf(acc);
}

// ---------------- chunked parallel scan ----------------
// Linear recurrence h_t = dA_t * h_{t-1} + dBx_t, decomposed into NCH chunks.
// Thread bits: n=tid[0:4), e=tid[4:14), ch=tid[14:18), b=tid[18].
// scan1: per-chunk summary (aprod = prod dA, bacc = folded dBx).
__global__ __launch_bounds__(256) void scan1_kernel(
    const float* __restrict__ delta_pre,  // (ROWS, DI)
    const float* __restrict__ xc,         // (ROWS, DI)
    const float* __restrict__ dbc,        // (ROWS, 64): [32:48]=B
    const float* __restrict__ A_log,      // (DI, 16)
    float* __restrict__ aprod, float* __restrict__ bacc) {
    int tid = blockIdx.x * 256 + threadIdx.x;
    int n  = tid & 15;
    int e  = (tid >> 4) & (DI - 1);
    int ch = (tid >> 14) & (NCH - 1);
    int b  = tid >> 18;
    float Aen = -expf(A_log[e * 16 + n]);
    float ap = 1.f, bc = 0.f;
    int row0 = b * LSEQ + ch * CHT;
    for (int t = 0; t < CHT; ++t) {
        int row = row0 + t;
        float d   = softplusf(delta_pre[(size_t)row * DI + e]);
        float xcv = xc[(size_t)row * DI + e];
        float Bv  = dbc[(size_t)row * 64 + 32 + n];
        float dA  = expf(d * Aen);
        ap *= dA;
        bc = fmaf(dA, bc, d * xcv * Bv);
    }
    size_t idx = ((size_t)(b * NCH + ch) * DI + e) * 16 + n;
    aprod[idx] = ap;
    bacc[idx]  = bc;
}

// scan2: serial combine across 16 chunks -> h_init per chunk. Tiny.
__global__ __launch_bounds__(256) void scan2_kernel(
    const float* __restrict__ aprod, const float* __restrict__ bacc,
    float* __restrict__ hinit) {
    int tid = blockIdx.x * 256 + threadIdx.x;  // 32768 = (b,e,n)
    int n = tid & 15;
    int e = (tid >> 4) & (DI - 1);
    int b = tid >> 14;
    float h = 0.f;
    for (int ch = 0; ch < NCH; ++ch) {
        size_t idx = ((size_t)(b * NCH + ch) * DI + e) * 16 + n;
        hinit[idx] = h;
        h = fmaf(aprod[idx], h, bacc[idx]);
    }
}

// scan3: re-run each chunk from its h_init; fuse C-contraction + D-skip + gate.
__global__ __launch_bounds__(256) void scan3_kernel(
    const float* __restrict__ delta_pre, const float* __restrict__ xc,
    const float* __restrict__ dbc,       // [32:48]=B, [48:64]=C
    const float* __restrict__ xz,        // cols 1024+ are z
    const float* __restrict__ A_log, const float* __restrict__ Dp,
    const float* __restrict__ hinit, float* __restrict__ yg) {
    int tid = blockIdx.x * 256 + threadIdx.x;
    int n  = tid & 15;
    int e  = (tid >> 4) & (DI - 1);
    int ch = (tid >> 14) & (NCH - 1);
    int b  = tid >> 18;
    float Aen = -expf(A_log[e * 16 + n]);
    float Dpe = Dp[e];
    float h = hinit[((size_t)(b * NCH + ch) * DI + e) * 16 + n];
    int row0 = b * LSEQ + ch * CHT;
    for (int t = 0; t < CHT; ++t) {
        int row = row0 + t;
        float d   = softplusf(delta_pre[(size_t)row * DI + e]);
        float xcv = xc[(size_t)row * DI + e];
        float Bv  = dbc[(size_t)row * 64 + 32 + n];
        float Cv  = dbc[(size_t)row * 64 + 48 + n];
        float dA  = expf(d * Aen);
        h = fmaf(dA, h, d * xcv * Bv);
        float p = h * Cv;
        p += __shfl_xor(p, 1, 16);
        p += __shfl_xor(p, 2, 16);
        p += __shfl_xor(p, 4, 16);
        p += __shfl_xor(p, 8, 16);
        if (n == 0) {
            float z = xz[(size_t)row * 2048 + 1024 + e];
            float y = p + Dpe * xcv;
            yg[(size_t)row * DI + e] = y * siluf(z);
        }
    }
}

// ---------------- elementwise add ----------------
__global__ __launch_bounds__(256) void add_kernel(const float* __restrict__ a,
                                                  const float* __restrict__ b,
                                                  float* __restrict__ c, int n) {
    int i = blockIdx.x * blockDim.x + threadIdx.x;
    if (i < n) c[i] = a[i] + b[i];
}

extern "C" void kernel_launch(void* const* d_in, const int* in_sizes, int n_in,
                              void* d_out, int out_size, void* d_ws, size_t ws_size,
                              hipStream_t stream) {
    const float* x    = (const float*)d_in[0];
    const float* ipw  = (const float*)d_in[1];
    const float* cw   = (const float*)d_in[2];
    const float* cb   = (const float*)d_in[3];
    const float* xpw  = (const float*)d_in[4];
    const float* dtw  = (const float*)d_in[5];
    const float* dtb  = (const float*)d_in[6];
    const float* alog = (const float*)d_in[7];
    const float* dpar = (const float*)d_in[8];
    const float* opw  = (const float*)d_in[9];
    const float* rmsw = (const float*)d_in[10];
    const float* ln1w = (const float*)d_in[11];
    const float* ln1b = (const float*)d_in[12];
    const float* ln2w = (const float*)d_in[13];
    const float* ln2b = (const float*)d_in[14];
    const float* fw1  = (const float*)d_in[15];
    const float* fb1  = (const float*)d_in[16];
    const float* fw2  = (const float*)d_in[17];
    const float* fb2  = (const float*)d_in[18];
    const float* finw = (const float*)d_in[19];
    const float* finb = (const float*)d_in[20];
    float* out = (float*)d_out;

    float* ws = (float*)d_ws;
    float* h     = ws;                          // 2M floats
    float* hn    = h   + (size_t)ROWS * DM;     // 2M (scan summaries overlay)
    float* xz    = hn  + (size_t)ROWS * DM;     // 8M
    float* xc    = xz  + (size_t)ROWS * 2048;   // 4M (reused as x2 later)
    float* dbc   = xc  + (size_t)ROWS * DI;     // 256K
    float* delta = dbc + (size_t)ROWS * 64;     // 4M
    float* yg    = delta + (size_t)ROWS * DI;   // 4M (reused as x3 later)
    // total ~= 24.25M floats ~= 97 MB

    // scan chunk summaries overlay hn (free between in_proj and next rms):
    const size_t SUMN = (size_t)2 * NCH * DI * 16;  // 524288
    float* aprod = hn;
    float* bacc  = hn + SUMN;
    float* hinit = hn + 2 * SUMN;  // 1.5M floats total <= 2M slot

    // 1. h = LN1(x)
    ln_kernel<<<ROWS, 256, 0, stream>>>(x, ln1w, ln1b, h);

    for (int i = 0; i < 2; ++i) {
        const float* ipw_i  = ipw  + (size_t)i * 2048 * 512;
        const float* cw_i   = cw   + (size_t)i * DI * 4;
        const float* cb_i   = cb   + (size_t)i * DI;
        const float* xpw_i  = xpw  + (size_t)i * 64 * DI;
        const float* dtw_i  = dtw  + (size_t)i * DI * 32;
        const float* dtb_i  = dtb  + (size_t)i * DI;
        const float* alog_i = alog + (size_t)i * DI * 16;
        const float* dp_i   = dpar + (size_t)i * DI;
        const float* opw_i  = opw  + (size_t)i * DM * DI;
        const float* rms_i  = rmsw + (size_t)i * DM;

        // hn = RMS(h)
        rms_kernel<<<ROWS, 256, 0, stream>>>(h, rms_i, hn);
        // xz = hn @ ipw^T   (4096 x 2048 x 512)
        gemm_kernel<0, false, false><<<dim3(2048 / 64, ROWS / 64), 256, 0, stream>>>(
            hn, ipw_i, nullptr, nullptr, xz, ROWS, 2048, 512, 512, 512, 2048);
        // xc = silu(conv(xz[:, :1024]))
        conv_silu_kernel<<<ROWS * DI / 256, 256, 0, stream>>>(xz, cw_i, cb_i, xc);
        // dbc = xc @ xpw^T  (4096 x 64 x 1024)
        gemm_kernel<0, false, false><<<dim3(1, ROWS / 64), 256, 0, stream>>>(
            xc, xpw_i, nullptr, nullptr, dbc, ROWS, 64, 1024, 1024, 1024, 64);
        // delta_pre = dbc[:, :32] @ dtw^T + dtb  (4096 x 1024 x 32)
        gemm_kernel<0, true, false><<<dim3(1024 / 64, ROWS / 64), 256, 0, stream>>>(
            dbc, dtw_i, dtb_i, nullptr, delta, ROWS, 1024, 32, 64, 32, 1024);
        // chunked parallel scan (hn slot is free here)
        scan1_kernel<<<2048, 256, 0, stream>>>(delta, xc, dbc, alog_i, aprod, bacc);
        scan2_kernel<<<128, 256, 0, stream>>>(aprod, bacc, hinit);
        scan3_kernel<<<2048, 256, 0, stream>>>(delta, xc, dbc, xz, alog_i, dp_i,
                                               hinit, yg);
        // h = h + yg @ opw^T  (4096 x 512 x 1024)
        gemm_kernel<0, false, true><<<dim3(DM / 64, ROWS / 64), 256, 0, stream>>>(
            yg, opw_i, nullptr, h, h, ROWS, DM, DI, DI, DI, DM);
    }

    // x2 = x + h  (store in xc slot)
    float* x2 = xc;
    add_kernel<<<ROWS * DM / 256, 256, 0, stream>>>(x, h, x2, ROWS * DM);
    // hn = LN2(x2)
    ln_kernel<<<ROWS, 256, 0, stream>>>(x2, ln2w, ln2b, hn);
    // mid = relu(hn @ fw1^T + fb1)  (4096 x 1024 x 512)
    float* mid = xz;
    gemm_kernel<1, true, false><<<dim3(DI / 64, ROWS / 64), 256, 0, stream>>>(
        hn, fw1, fb1, nullptr, mid, ROWS, DI, DM, DM, DM, DI);
    // x3 = x2 + mid @ fw2^T + fb2  (4096 x 512 x 1024)
    float* x3 = yg;
    gemm_kernel<0, true, true><<<dim3(DM / 64, ROWS / 64), 256, 0, stream>>>(
        mid, fw2, fb2, x2, x3, ROWS, DM, DI, DI, DI, DM);
    // out = x3 @ finw^T + finb  (4096 x 512 x 512)
    gemm_kernel<0, true, false><<<dim3(DM / 64, ROWS / 64), 256, 0, stream>>>(
        x3, finw, finb, nullptr, out, ROWS, DM, DM, DM, DM, DM);
}

// Round 5
// 1480.308 us; speedup vs baseline: 3.6288x; 1.5625x over previous
//
#include <hip/hip_runtime.h>
#include <math.h>

#define ROWS 4096   // B * L
#define LSEQ 2048
#define DM   512
#define DI   1024
#define NCH  32            // scan chunks per sequence
#define CHT  (LSEQ / NCH)  // 64 timesteps per chunk

__device__ __forceinline__ float siluf(float v) { return v / (1.f + expf(-v)); }
__device__ __forceinline__ float softplusf(float v) {
    return fmaxf(v, 0.f) + log1pf(expf(-fabsf(v)));
}

// ---------------- LayerNorm: one block per row of 512 ----------------
__global__ __launch_bounds__(256) void ln_kernel(const float* __restrict__ x,
                                                 const float* __restrict__ w,
                                                 const float* __restrict__ b,
                                                 float* __restrict__ out) {
    int row = blockIdx.x;
    int tid = threadIdx.x;
    const float* xr = x + (size_t)row * DM;
    float v0 = xr[tid], v1 = xr[tid + 256];
    float sum = v0 + v1, sq = v0 * v0 + v1 * v1;
    for (int o = 32; o > 0; o >>= 1) {
        sum += __shfl_down(sum, o);
        sq  += __shfl_down(sq, o);
    }
    __shared__ float s1[4], s2[4];
    int wid = tid >> 6, lane = tid & 63;
    if (lane == 0) { s1[wid] = sum; s2[wid] = sq; }
    __syncthreads();
    sum = s1[0] + s1[1] + s1[2] + s1[3];
    sq  = s2[0] + s2[1] + s2[2] + s2[3];
    float mu  = sum * (1.f / DM);
    float var = sq * (1.f / DM) - mu * mu;
    float r   = rsqrtf(var + 1e-5f);
    out[(size_t)row * DM + tid]       = (v0 - mu) * r * w[tid] + b[tid];
    out[(size_t)row * DM + tid + 256] = (v1 - mu) * r * w[tid + 256] + b[tid + 256];
}

// ---------------- RMSNorm: one block per row of 512 ----------------
__global__ __launch_bounds__(256) void rms_kernel(const float* __restrict__ x,
                                                  const float* __restrict__ w,
                                                  float* __restrict__ out) {
    int row = blockIdx.x;
    int tid = threadIdx.x;
    const float* xr = x + (size_t)row * DM;
    float v0 = xr[tid], v1 = xr[tid + 256];
    float sq = v0 * v0 + v1 * v1;
    for (int o = 32; o > 0; o >>= 1) sq += __shfl_down(sq, o);
    __shared__ float s2[4];
    int wid = tid >> 6, lane = tid & 63;
    if (lane == 0) s2[wid] = sq;
    __syncthreads();
    sq = s2[0] + s2[1] + s2[2] + s2[3];
    float r = rsqrtf(sq * (1.f / DM) + 1e-5f);
    out[(size_t)row * DM + tid]       = v0 * r * w[tid];
    out[(size_t)row * DM + tid + 256] = v1 * r * w[tid + 256];
}

// ---------------- Generic fp32 tiled GEMM: C = A @ W^T (+bias)(+res)(+act)
// ACT: 0=none, 1=relu, 2=softplus + C2 = softplus(v)*res (dt-path epilogue)
template <int ACT, bool BIAS, bool RES>
__global__ __launch_bounds__(256) void gemm_kernel(
    const float* __restrict__ A, const float* __restrict__ W,
    const float* __restrict__ bias, const float* __restrict__ res,
    float* __restrict__ C, float* __restrict__ C2,
    int M, int N, int K, int lda, int ldb, int ldc, int ldc2) {
    __shared__ float As[16][65];
    __shared__ float Bs[16][65];
    const int tid = threadIdx.x;
    const int tx = tid & 15, ty = tid >> 4;
    const int bm = blockIdx.y * 64, bn = blockIdx.x * 64;
    float acc[4][4] = {};
    for (int k0 = 0; k0 < K; k0 += 16) {
#pragma unroll
        for (int l = 0; l < 4; ++l) {
            int id = tid + l * 256;
            int r = id >> 4, c = id & 15;
            As[c][r] = A[(size_t)(bm + r) * lda + k0 + c];
            Bs[c][r] = W[(size_t)(bn + r) * ldb + k0 + c];
        }
        __syncthreads();
#pragma unroll
        for (int k = 0; k < 16; ++k) {
            float a4[4], b4[4];
#pragma unroll
            for (int i = 0; i < 4; ++i) a4[i] = As[k][ty * 4 + i];
#pragma unroll
            for (int j = 0; j < 4; ++j) b4[j] = Bs[k][tx * 4 + j];
#pragma unroll
            for (int i = 0; i < 4; ++i)
#pragma unroll
                for (int j = 0; j < 4; ++j)
                    acc[i][j] = fmaf(a4[i], b4[j], acc[i][j]);
        }
        __syncthreads();
    }
#pragma unroll
    for (int i = 0; i < 4; ++i) {
        int row = bm + ty * 4 + i;
#pragma unroll
        for (int j = 0; j < 4; ++j) {
            int col = bn + tx * 4 + j;
            float v = acc[i][j];
            if (BIAS) v += bias[col];
            if (RES) v += res[(size_t)row * ldc + col];
            if (ACT == 1) v = fmaxf(v, 0.f);
            if (ACT == 2) {
                v = softplusf(v);
                C2[(size_t)row * ldc2 + col] = v * res[(size_t)row * ldc + col];
            }
            C[(size_t)row * ldc + col] = v;
        }
    }
}

// ---------------- causal depthwise conv (D_CONV=4) + SiLU ----------------
__global__ __launch_bounds__(256) void conv_silu_kernel(
    const float* __restrict__ xz, const float* __restrict__ cw,
    const float* __restrict__ cb, float* __restrict__ out) {
    int idx = blockIdx.x * blockDim.x + threadIdx.x;  // ROWS*DI
    int c = idx & (DI - 1);
    int row = idx >> 10;
    int t = row & (LSEQ - 1);
    float acc = cb[c];
#pragma unroll
    for (int k = 0; k < 4; ++k) {
        int st = t + k - 3;
        if (st >= 0) acc = fmaf(cw[c * 4 + k], xz[(size_t)(row + k - 3) * 2048 + c], acc);
    }
    out[idx] = siluf(acc);
}

// ---------------- chunked parallel scan, register-state version ----------
// h_t = dA_t h_{t-1} + dBx_t with dA = exp2(d * cAn), dBx = dxc * B.
// Thread owns one e and all 16 n-states in registers.
// grid: (eblk=4, ch=NCH, b=2), block 256.  d: (ROWS,DI) precomputed softplus.
// dxc: strided in xz cols [0,1024).
__global__ __launch_bounds__(256) void scan1_kernel(
    const float* __restrict__ dbuf, const float* __restrict__ xzbuf,
    const float* __restrict__ dbc, const float* __restrict__ A_log,
    float* __restrict__ aprod, float* __restrict__ bacc) {
    int e  = blockIdx.x * 256 + threadIdx.x;
    int ch = blockIdx.y;
    int b  = blockIdx.z;
    float cAn[16];
#pragma unroll
    for (int n = 0; n < 16; ++n)
        cAn[n] = -expf(A_log[e * 16 + n]) * 1.4426950408889634f;
    float ap[16], bc[16];
#pragma unroll
    for (int n = 0; n < 16; ++n) { ap[n] = 1.f; bc[n] = 0.f; }
    int row0 = b * LSEQ + ch * CHT;
    float d_c   = dbuf[(size_t)row0 * DI + e];
    float dxc_c = xzbuf[(size_t)row0 * 2048 + e];
    for (int t = 0; t < CHT; ++t) {
        int row = row0 + t;
        float d_n = 0.f, dxc_n = 0.f;
        if (t + 1 < CHT) {
            d_n   = dbuf[(size_t)(row + 1) * DI + e];
            dxc_n = xzbuf[(size_t)(row + 1) * 2048 + e];
        }
        const float* brow = dbc + (size_t)row * 64 + 32;  // block-uniform
        float Bn[16];
#pragma unroll
        for (int n = 0; n < 16; ++n) Bn[n] = brow[n];
#pragma unroll
        for (int n = 0; n < 16; ++n) {
            float dA = exp2f(d_c * cAn[n]);
            ap[n] *= dA;
            bc[n] = fmaf(dA, bc[n], dxc_c * Bn[n]);
        }
        d_c = d_n; dxc_c = dxc_n;
    }
    size_t idx = ((size_t)((b * NCH + ch) * DI + e)) * 16;
    float4* apo = (float4*)(aprod + idx);
    float4* bco = (float4*)(bacc + idx);
#pragma unroll
    for (int q = 0; q < 4; ++q) {
        apo[q] = make_float4(ap[q * 4], ap[q * 4 + 1], ap[q * 4 + 2], ap[q * 4 + 3]);
        bco[q] = make_float4(bc[q * 4], bc[q * 4 + 1], bc[q * 4 + 2], bc[q * 4 + 3]);
    }
}

// scan2: serial combine across NCH chunks -> h_init per chunk.
// NOTE: hinit aliases aprod (read-before-write per index) — no __restrict__.
__global__ __launch_bounds__(256) void scan2_kernel(
    const float* aprod, const float* bacc, float* hinit) {
    int tid = blockIdx.x * 256 + threadIdx.x;  // 32768 = (b,e,n)
    int n = tid & 15;
    int e = (tid >> 4) & (DI - 1);
    int b = tid >> 14;
    float h = 0.f;
    for (int ch = 0; ch < NCH; ++ch) {
        size_t idx = ((size_t)((b * NCH + ch) * DI + e)) * 16 + n;
        float a  = aprod[idx];
        float bb = bacc[idx];
        hinit[idx] = h;
        h = fmaf(a, h, bb);
    }
}

// scan3: re-run each chunk from h_init; fuse C-contraction + D-skip + gate.
__global__ __launch_bounds__(256) void scan3_kernel(
    const float* __restrict__ dbuf, const float* __restrict__ xzbuf,
    const float* __restrict__ xc, const float* __restrict__ dbc,
    const float* __restrict__ A_log, const float* __restrict__ Dp,
    const float* __restrict__ hinit, float* __restrict__ yg) {
    int e  = blockIdx.x * 256 + threadIdx.x;
    int ch = blockIdx.y;
    int b  = blockIdx.z;
    float cAn[16];
#pragma unroll
    for (int n = 0; n < 16; ++n)
        cAn[n] = -expf(A_log[e * 16 + n]) * 1.4426950408889634f;
    float h[16];
    {
        const float4* hp = (const float4*)(hinit + ((size_t)((b * NCH + ch) * DI + e)) * 16);
#pragma unroll
        for (int q = 0; q < 4; ++q) {
            float4 v = hp[q];
            h[q * 4] = v.x; h[q * 4 + 1] = v.y; h[q * 4 + 2] = v.z; h[q * 4 + 3] = v.w;
        }
    }
    float Dpe = Dp[e];
    int row0 = b * LSEQ + ch * CHT;
    float d_c   = dbuf[(size_t)row0 * DI + e];
    float dxc_c = xzbuf[(size_t)row0 * 2048 + e];
    float xc_c  = xc[(size_t)row0 * DI + e];
    float z_c   = xzbuf[(size_t)row0 * 2048 + 1024 + e];
    for (int t = 0; t < CHT; ++t) {
        int row = row0 + t;
        float d_n = 0.f, dxc_n = 0.f, xc_n = 0.f, z_n = 0.f;
        if (t + 1 < CHT) {
            d_n   = dbuf[(size_t)(row + 1) * DI + e];
            dxc_n = xzbuf[(size_t)(row + 1) * 2048 + e];
            xc_n  = xc[(size_t)(row + 1) * DI + e];
            z_n   = xzbuf[(size_t)(row + 1) * 2048 + 1024 + e];
        }
        const float* brow = dbc + (size_t)row * 64 + 32;  // block-uniform
        float Bn[16], Cn[16];
#pragma unroll
        for (int n = 0; n < 16; ++n) { Bn[n] = brow[n]; Cn[n] = brow[16 + n]; }
        float y = Dpe * xc_c;
#pragma unroll
        for (int n = 0; n < 16; ++n) {
            float dA = exp2f(d_c * cAn[n]);
            h[n] = fmaf(dA, h[n], dxc_c * Bn[n]);
            y = fmaf(h[n], Cn[n], y);
        }
        yg[(size_t)row * DI + e] = y * siluf(z_c);
        d_c = d_n; dxc_c = dxc_n; xc_c = xc_n; z_c = z_n;
    }
}

// ---------------- elementwise add ----------------
__global__ __launch_bounds__(256) void add_kernel(const float* __restrict__ a,
                                                  const float* __restrict__ b,
                                                  float* __restrict__ c, int n) {
    int i = blockIdx.x * blockDim.x + threadIdx.x;
    if (i < n) c[i] = a[i] + b[i];
}

extern "C" void kernel_launch(void* const* d_in, const int* in_sizes, int n_in,
                              void* d_out, int out_size, void* d_ws, size_t ws_size,
                              hipStream_t stream) {
    const float* x    = (const float*)d_in[0];
    const float* ipw  = (const float*)d_in[1];
    const float* cw   = (const float*)d_in[2];
    const float* cb   = (const float*)d_in[3];
    const float* xpw  = (const float*)d_in[4];
    const float* dtw  = (const float*)d_in[5];
    const float* dtb  = (const float*)d_in[6];
    const float* alog = (const float*)d_in[7];
    const float* dpar = (const float*)d_in[8];
    const float* opw  = (const float*)d_in[9];
    const float* rmsw = (const float*)d_in[10];
    const float* ln1w = (const float*)d_in[11];
    const float* ln1b = (const float*)d_in[12];
    const float* ln2w = (const float*)d_in[13];
    const float* ln2b = (const float*)d_in[14];
    const float* fw1  = (const float*)d_in[15];
    const float* fb1  = (const float*)d_in[16];
    const float* fw2  = (const float*)d_in[17];
    const float* fb2  = (const float*)d_in[18];
    const float* finw = (const float*)d_in[19];
    const float* finb = (const float*)d_in[20];
    float* out = (float*)d_out;

    float* ws = (float*)d_ws;
    float* h     = ws;                          // 2M floats
    float* hn    = h   + (size_t)ROWS * DM;     // 2M (scan summaries overlay)
    float* xz    = hn  + (size_t)ROWS * DM;     // 8M (cols 0-1023 reused as dxc)
    float* xc    = xz  + (size_t)ROWS * 2048;   // 4M (reused as x2 later)
    float* dbc   = xc  + (size_t)ROWS * DI;     // 256K
    float* dbuf  = dbc + (size_t)ROWS * 64;     // 4M  (d = softplus(delta))
    float* yg    = dbuf + (size_t)ROWS * DI;    // 4M (reused as x3 later)
    // total ~= 24.25M floats ~= 97 MB

    // scan chunk summaries overlay hn: aprod/bacc = 1M floats each; hinit
    // deliberately aliases aprod (scan2 reads each slot before overwriting).
    const size_t SUMN = (size_t)2 * NCH * DI * 16;  // 1M floats
    float* aprod = hn;
    float* bacc  = hn + SUMN;
    float* hinit = aprod;

    // 1. h = LN1(x)
    ln_kernel<<<ROWS, 256, 0, stream>>>(x, ln1w, ln1b, h);

    for (int i = 0; i < 2; ++i) {
        const float* ipw_i  = ipw  + (size_t)i * 2048 * 512;
        const float* cw_i   = cw   + (size_t)i * DI * 4;
        const float* cb_i   = cb   + (size_t)i * DI;
        const float* xpw_i  = xpw  + (size_t)i * 64 * DI;
        const float* dtw_i  = dtw  + (size_t)i * DI * 32;
        const float* dtb_i  = dtb  + (size_t)i * DI;
        const float* alog_i = alog + (size_t)i * DI * 16;
        const float* dp_i   = dpar + (size_t)i * DI;
        const float* opw_i  = opw  + (size_t)i * DM * DI;
        const float* rms_i  = rmsw + (size_t)i * DM;

        // hn = RMS(h)
        rms_kernel<<<ROWS, 256, 0, stream>>>(h, rms_i, hn);
        // xz = hn @ ipw^T   (4096 x 2048 x 512)
        gemm_kernel<0, false, false><<<dim3(2048 / 64, ROWS / 64), 256, 0, stream>>>(
            hn, ipw_i, nullptr, nullptr, xz, nullptr, ROWS, 2048, 512, 512, 512, 2048, 0);
        // xc = silu(conv(xz[:, :1024]))
        conv_silu_kernel<<<ROWS * DI / 256, 256, 0, stream>>>(xz, cw_i, cb_i, xc);
        // dbc = xc @ xpw^T  (4096 x 64 x 1024)
        gemm_kernel<0, false, false><<<dim3(1, ROWS / 64), 256, 0, stream>>>(
            xc, xpw_i, nullptr, nullptr, dbc, nullptr, ROWS, 64, 1024, 1024, 1024, 64, 0);
        // d = softplus(dbc[:, :32] @ dtw^T + dtb); dxc = d*xc -> xz[:, :1024]
        gemm_kernel<2, true, false><<<dim3(1024 / 64, ROWS / 64), 256, 0, stream>>>(
            dbc, dtw_i, dtb_i, xc, dbuf, xz, ROWS, 1024, 32, 64, 32, 1024, 2048);
        // chunked parallel scan (hn slot is free here)
        scan1_kernel<<<dim3(4, NCH, 2), 256, 0, stream>>>(dbuf, xz, dbc, alog_i,
                                                          aprod, bacc);
        scan2_kernel<<<128, 256, 0, stream>>>(aprod, bacc, hinit);
        scan3_kernel<<<dim3(4, NCH, 2), 256, 0, stream>>>(dbuf, xz, xc, dbc, alog_i,
                                                          dp_i, hinit, yg);
        // h = h + yg @ opw^T  (4096 x 512 x 1024)
        gemm_kernel<0, false, true><<<dim3(DM / 64, ROWS / 64), 256, 0, stream>>>(
            yg, opw_i, nullptr, h, h, nullptr, ROWS, DM, DI, DI, DI, DM, 0);
    }

    // x2 = x + h  (store in xc slot)
    float* x2 = xc;
    add_kernel<<<ROWS * DM / 256, 256, 0, stream>>>(x, h, x2, ROWS * DM);
    // hn = LN2(x2)
    ln_kernel<<<ROWS, 256, 0, stream>>>(x2, ln2w, ln2b, hn);
    // mid = relu(hn @ fw1^T + fb1)  (4096 x 1024 x 512)
    float* mid = xz;
    gemm_kernel<1, true, false><<<dim3(DI / 64, ROWS / 64), 256, 0, stream>>>(
        hn, fw1, fb1, nullptr, mid, nullptr, ROWS, DI, DM, DM, DM, DI, 0);
    // x3 = x2 + mid @ fw2^T + fb2  (4096 x 512 x 1024)
    float* x3 = yg;
    gemm_kernel<0, true, true><<<dim3(DM / 64, ROWS / 64), 256, 0, stream>>>(
        mid, fw2, fb2, x2, x3, nullptr, ROWS, DM, DI, DI, DI, DM, 0);
    // out = x3 @ finw^T + finb  (4096 x 512 x 512)
    gemm_kernel<0, true, false><<<dim3(DM / 64, ROWS / 64), 256, 0, stream>>>(
        x3, finw, finb, nullptr, out, nullptr, ROWS, DM, DM, DM, DM, DM, 0);
}

// Round 6
// 872.691 us; speedup vs baseline: 6.1553x; 1.6963x over previous
//
#include <hip/hip_runtime.h>
#include <math.h>

#define ROWS 4096   // B * L
#define LSEQ 2048
#define DM   512
#define DI   1024
#define NCH  32            // scan chunks per sequence
#define CHT  (LSEQ / NCH)  // 64 timesteps per chunk

typedef __bf16 bf16_t;
typedef bf16_t bf16x8 __attribute__((ext_vector_type(8)));
typedef float f32x4 __attribute__((ext_vector_type(4)));

__device__ __forceinline__ float siluf(float v) { return v / (1.f + expf(-v)); }
__device__ __forceinline__ float softplusf(float v) {
    return fmaxf(v, 0.f) + log1pf(expf(-fabsf(v)));
}

// ---------------- LayerNorm: one block per row of 512 ----------------
__global__ __launch_bounds__(256) void ln_kernel(const float* __restrict__ x,
                                                 const float* __restrict__ w,
                                                 const float* __restrict__ b,
                                                 float* __restrict__ out) {
    int row = blockIdx.x;
    int tid = threadIdx.x;
    const float* xr = x + (size_t)row * DM;
    float v0 = xr[tid], v1 = xr[tid + 256];
    float sum = v0 + v1, sq = v0 * v0 + v1 * v1;
    for (int o = 32; o > 0; o >>= 1) {
        sum += __shfl_down(sum, o);
        sq  += __shfl_down(sq, o);
    }
    __shared__ float s1[4], s2[4];
    int wid = tid >> 6, lane = tid & 63;
    if (lane == 0) { s1[wid] = sum; s2[wid] = sq; }
    __syncthreads();
    sum = s1[0] + s1[1] + s1[2] + s1[3];
    sq  = s2[0] + s2[1] + s2[2] + s2[3];
    float mu  = sum * (1.f / DM);
    float var = sq * (1.f / DM) - mu * mu;
    float r   = rsqrtf(var + 1e-5f);
    out[(size_t)row * DM + tid]       = (v0 - mu) * r * w[tid] + b[tid];
    out[(size_t)row * DM + tid + 256] = (v1 - mu) * r * w[tid + 256] + b[tid + 256];
}

// ---------------- RMSNorm: one block per row of 512 ----------------
__global__ __launch_bounds__(256) void rms_kernel(const float* __restrict__ x,
                                                  const float* __restrict__ w,
                                                  float* __restrict__ out) {
    int row = blockIdx.x;
    int tid = threadIdx.x;
    const float* xr = x + (size_t)row * DM;
    float v0 = xr[tid], v1 = xr[tid + 256];
    float sq = v0 * v0 + v1 * v1;
    for (int o = 32; o > 0; o >>= 1) sq += __shfl_down(sq, o);
    __shared__ float s2[4];
    int wid = tid >> 6, lane = tid & 63;
    if (lane == 0) s2[wid] = sq;
    __syncthreads();
    sq = s2[0] + s2[1] + s2[2] + s2[3];
    float r = rsqrtf(sq * (1.f / DM) + 1e-5f);
    out[(size_t)row * DM + tid]       = v0 * r * w[tid];
    out[(size_t)row * DM + tid + 256] = v1 * r * w[tid + 256];
}

// ---------------- bf16 MFMA GEMM: C = A @ W^T (+bias)(+res)(+relu) --------
// A:(M,K) fp32, W:(N,K) fp32; staged to LDS as bf16; fp32 accum via MFMA.
// 128x128 tile, 4 waves of 64x64, BK=32, 16x16x32 bf16 MFMA.
// All of M,N % 128 == 0, K % 32 == 0.
template <int ACT, bool BIAS, bool RES>
__global__ __launch_bounds__(256) void mgemm_kernel(
    const float* __restrict__ A, const float* __restrict__ W,
    const float* __restrict__ bias, const float* __restrict__ res,
    float* __restrict__ C, int M, int N, int K, int lda, int ldb, int ldc) {
    __shared__ bf16_t As[128][32];
    __shared__ bf16_t Bs[128][32];
    const int tid  = threadIdx.x;
    const int lane = tid & 63;
    const int wave = tid >> 6;
    const int wr = wave >> 1, wc = wave & 1;   // 2x2 wave grid
    const int bm = blockIdx.y * 128, bn = blockIdx.x * 128;
    const int srow = tid >> 1;                 // staging row 0..127
    const int scol = (tid & 1) * 16;           // staging k-offset 0/16
    const int kgrp = lane >> 4, l16 = lane & 15;

    f32x4 acc[4][4] = {};

    const float* pa = A + (size_t)(bm + srow) * lda + scol;
    const float* pb = W + (size_t)(bn + srow) * ldb + scol;

    for (int k0 = 0; k0 < K; k0 += 32) {
        f32x4 av[4], bv[4];
#pragma unroll
        for (int q = 0; q < 4; ++q) {
            av[q] = *(const f32x4*)(pa + k0 + q * 4);
            bv[q] = *(const f32x4*)(pb + k0 + q * 4);
        }
        bf16_t at[16], bt[16];
#pragma unroll
        for (int q = 0; q < 4; ++q)
#pragma unroll
            for (int j = 0; j < 4; ++j) {
                at[q * 4 + j] = (bf16_t)av[q][j];
                bt[q * 4 + j] = (bf16_t)bv[q][j];
            }
        __syncthreads();  // previous iter's LDS reads complete
        *(bf16x8*)&As[srow][scol]     = *(bf16x8*)&at[0];
        *(bf16x8*)&As[srow][scol + 8] = *(bf16x8*)&at[8];
        *(bf16x8*)&Bs[srow][scol]     = *(bf16x8*)&bt[0];
        *(bf16x8*)&Bs[srow][scol + 8] = *(bf16x8*)&bt[8];
        __syncthreads();
        bf16x8 af[4], bfr[4];
#pragma unroll
        for (int i = 0; i < 4; ++i) {
            af[i]  = *(bf16x8*)&As[wr * 64 + i * 16 + l16][kgrp * 8];
            bfr[i] = *(bf16x8*)&Bs[wc * 64 + i * 16 + l16][kgrp * 8];
        }
#pragma unroll
        for (int i = 0; i < 4; ++i)
#pragma unroll
            for (int j = 0; j < 4; ++j)
                acc[i][j] = __builtin_amdgcn_mfma_f32_16x16x32_bf16(
                    af[i], bfr[j], acc[i][j], 0, 0, 0);
    }
    // epilogue: C/D layout col=lane&15, row=(lane>>4)*4+q  [m89/m91 verified]
#pragma unroll
    for (int i = 0; i < 4; ++i) {
#pragma unroll
        for (int j = 0; j < 4; ++j) {
            int col = bn + wc * 64 + j * 16 + l16;
            float badd = BIAS ? bias[col] : 0.f;
#pragma unroll
            for (int q = 0; q < 4; ++q) {
                int row = bm + wr * 64 + i * 16 + kgrp * 4 + q;
                float v = acc[i][j][q] + badd;
                if (RES) v += res[(size_t)row * ldc + col];
                if (ACT == 1) v = fmaxf(v, 0.f);
                C[(size_t)row * ldc + col] = v;
            }
        }
    }
}

// ---------------- fp32 tiled GEMM (small shapes): C = A @ W^T -------------
// ACT: 0=none, 1=relu, 2=softplus + C2 = softplus(v)*res (dt-path epilogue)
template <int ACT, bool BIAS, bool RES>
__global__ __launch_bounds__(256) void gemm_kernel(
    const float* __restrict__ A, const float* __restrict__ W,
    const float* __restrict__ bias, const float* __restrict__ res,
    float* __restrict__ C, float* __restrict__ C2,
    int M, int N, int K, int lda, int ldb, int ldc, int ldc2) {
    __shared__ float As[16][65];
    __shared__ float Bs[16][65];
    const int tid = threadIdx.x;
    const int tx = tid & 15, ty = tid >> 4;
    const int bm = blockIdx.y * 64, bn = blockIdx.x * 64;
    float acc[4][4] = {};
    for (int k0 = 0; k0 < K; k0 += 16) {
#pragma unroll
        for (int l = 0; l < 4; ++l) {
            int id = tid + l * 256;
            int r = id >> 4, c = id & 15;
            As[c][r] = A[(size_t)(bm + r) * lda + k0 + c];
            Bs[c][r] = W[(size_t)(bn + r) * ldb + k0 + c];
        }
        __syncthreads();
#pragma unroll
        for (int k = 0; k < 16; ++k) {
            float a4[4], b4[4];
#pragma unroll
            for (int i = 0; i < 4; ++i) a4[i] = As[k][ty * 4 + i];
#pragma unroll
            for (int j = 0; j < 4; ++j) b4[j] = Bs[k][tx * 4 + j];
#pragma unroll
            for (int i = 0; i < 4; ++i)
#pragma unroll
                for (int j = 0; j < 4; ++j)
                    acc[i][j] = fmaf(a4[i], b4[j], acc[i][j]);
        }
        __syncthreads();
    }
#pragma unroll
    for (int i = 0; i < 4; ++i) {
        int row = bm + ty * 4 + i;
#pragma unroll
        for (int j = 0; j < 4; ++j) {
            int col = bn + tx * 4 + j;
            float v = acc[i][j];
            if (BIAS) v += bias[col];
            if (RES) v += res[(size_t)row * ldc + col];
            if (ACT == 1) v = fmaxf(v, 0.f);
            if (ACT == 2) {
                v = softplusf(v);
                C2[(size_t)row * ldc2 + col] = v * res[(size_t)row * ldc + col];
            }
            C[(size_t)row * ldc + col] = v;
        }
    }
}

// ---------------- causal depthwise conv (D_CONV=4) + SiLU ----------------
__global__ __launch_bounds__(256) void conv_silu_kernel(
    const float* __restrict__ xz, const float* __restrict__ cw,
    const float* __restrict__ cb, float* __restrict__ out) {
    int idx = blockIdx.x * blockDim.x + threadIdx.x;  // ROWS*DI
    int c = idx & (DI - 1);
    int row = idx >> 10;
    int t = row & (LSEQ - 1);
    float acc = cb[c];
#pragma unroll
    for (int k = 0; k < 4; ++k) {
        int st = t + k - 3;
        if (st >= 0) acc = fmaf(cw[c * 4 + k], xz[(size_t)(row + k - 3) * 2048 + c], acc);
    }
    out[idx] = siluf(acc);
}

// ---------------- chunked parallel scan, register-state version ----------
__global__ __launch_bounds__(256) void scan1_kernel(
    const float* __restrict__ dbuf, const float* __restrict__ xzbuf,
    const float* __restrict__ dbc, const float* __restrict__ A_log,
    float* __restrict__ aprod, float* __restrict__ bacc) {
    int e  = blockIdx.x * 256 + threadIdx.x;
    int ch = blockIdx.y;
    int b  = blockIdx.z;
    float cAn[16];
#pragma unroll
    for (int n = 0; n < 16; ++n)
        cAn[n] = -expf(A_log[e * 16 + n]) * 1.4426950408889634f;
    float ap[16], bc[16];
#pragma unroll
    for (int n = 0; n < 16; ++n) { ap[n] = 1.f; bc[n] = 0.f; }
    int row0 = b * LSEQ + ch * CHT;
    float d_c   = dbuf[(size_t)row0 * DI + e];
    float dxc_c = xzbuf[(size_t)row0 * 2048 + e];
    for (int t = 0; t < CHT; ++t) {
        int row = row0 + t;
        float d_n = 0.f, dxc_n = 0.f;
        if (t + 1 < CHT) {
            d_n   = dbuf[(size_t)(row + 1) * DI + e];
            dxc_n = xzbuf[(size_t)(row + 1) * 2048 + e];
        }
        const float* brow = dbc + (size_t)row * 64 + 32;  // block-uniform
        float Bn[16];
#pragma unroll
        for (int n = 0; n < 16; ++n) Bn[n] = brow[n];
#pragma unroll
        for (int n = 0; n < 16; ++n) {
            float dA = exp2f(d_c * cAn[n]);
            ap[n] *= dA;
            bc[n] = fmaf(dA, bc[n], dxc_c * Bn[n]);
        }
        d_c = d_n; dxc_c = dxc_n;
    }
    size_t idx = ((size_t)((b * NCH + ch) * DI + e)) * 16;
    float4* apo = (float4*)(aprod + idx);
    float4* bco = (float4*)(bacc + idx);
#pragma unroll
    for (int q = 0; q < 4; ++q) {
        apo[q] = make_float4(ap[q * 4], ap[q * 4 + 1], ap[q * 4 + 2], ap[q * 4 + 3]);
        bco[q] = make_float4(bc[q * 4], bc[q * 4 + 1], bc[q * 4 + 2], bc[q * 4 + 3]);
    }
}

// scan2: serial combine across NCH chunks -> h_init per chunk.
// NOTE: hinit aliases aprod (read-before-write per index) — no __restrict__.
__global__ __launch_bounds__(256) void scan2_kernel(
    const float* aprod, const float* bacc, float* hinit) {
    int tid = blockIdx.x * 256 + threadIdx.x;  // 32768 = (b,e,n)
    int n = tid & 15;
    int e = (tid >> 4) & (DI - 1);
    int b = tid >> 14;
    float h = 0.f;
    for (int ch = 0; ch < NCH; ++ch) {
        size_t idx = ((size_t)((b * NCH + ch) * DI + e)) * 16 + n;
        float a  = aprod[idx];
        float bb = bacc[idx];
        hinit[idx] = h;
        h = fmaf(a, h, bb);
    }
}

// scan3: re-run each chunk from h_init; fuse C-contraction + D-skip + gate.
__global__ __launch_bounds__(256) void scan3_kernel(
    const float* __restrict__ dbuf, const float* __restrict__ xzbuf,
    const float* __restrict__ xc, const float* __restrict__ dbc,
    const float* __restrict__ A_log, const float* __restrict__ Dp,
    const float* __restrict__ hinit, float* __restrict__ yg) {
    int e  = blockIdx.x * 256 + threadIdx.x;
    int ch = blockIdx.y;
    int b  = blockIdx.z;
    float cAn[16];
#pragma unroll
    for (int n = 0; n < 16; ++n)
        cAn[n] = -expf(A_log[e * 16 + n]) * 1.4426950408889634f;
    float h[16];
    {
        const float4* hp = (const float4*)(hinit + ((size_t)((b * NCH + ch) * DI + e)) * 16);
#pragma unroll
        for (int q = 0; q < 4; ++q) {
            float4 v = hp[q];
            h[q * 4] = v.x; h[q * 4 + 1] = v.y; h[q * 4 + 2] = v.z; h[q * 4 + 3] = v.w;
        }
    }
    float Dpe = Dp[e];
    int row0 = b * LSEQ + ch * CHT;
    float d_c   = dbuf[(size_t)row0 * DI + e];
    float dxc_c = xzbuf[(size_t)row0 * 2048 + e];
    float xc_c  = xc[(size_t)row0 * DI + e];
    float z_c   = xzbuf[(size_t)row0 * 2048 + 1024 + e];
    for (int t = 0; t < CHT; ++t) {
        int row = row0 + t;
        float d_n = 0.f, dxc_n = 0.f, xc_n = 0.f, z_n = 0.f;
        if (t + 1 < CHT) {
            d_n   = dbuf[(size_t)(row + 1) * DI + e];
            dxc_n = xzbuf[(size_t)(row + 1) * 2048 + e];
            xc_n  = xc[(size_t)(row + 1) * DI + e];
            z_n   = xzbuf[(size_t)(row + 1) * 2048 + 1024 + e];
        }
        const float* brow = dbc + (size_t)row * 64 + 32;  // block-uniform
        float Bn[16], Cn[16];
#pragma unroll
        for (int n = 0; n < 16; ++n) { Bn[n] = brow[n]; Cn[n] = brow[16 + n]; }
        float y = Dpe * xc_c;
#pragma unroll
        for (int n = 0; n < 16; ++n) {
            float dA = exp2f(d_c * cAn[n]);
            h[n] = fmaf(dA, h[n], dxc_c * Bn[n]);
            y = fmaf(h[n], Cn[n], y);
        }
        yg[(size_t)row * DI + e] = y * siluf(z_c);
        d_c = d_n; dxc_c = dxc_n; xc_c = xc_n; z_c = z_n;
    }
}

// ---------------- elementwise add ----------------
__global__ __launch_bounds__(256) void add_kernel(const float* __restrict__ a,
                                                  const float* __restrict__ b,
                                                  float* __restrict__ c, int n) {
    int i = blockIdx.x * blockDim.x + threadIdx.x;
    if (i < n) c[i] = a[i] + b[i];
}

extern "C" void kernel_launch(void* const* d_in, const int* in_sizes, int n_in,
                              void* d_out, int out_size, void* d_ws, size_t ws_size,
                              hipStream_t stream) {
    const float* x    = (const float*)d_in[0];
    const float* ipw  = (const float*)d_in[1];
    const float* cw   = (const float*)d_in[2];
    const float* cb   = (const float*)d_in[3];
    const float* xpw  = (const float*)d_in[4];
    const float* dtw  = (const float*)d_in[5];
    const float* dtb  = (const float*)d_in[6];
    const float* alog = (const float*)d_in[7];
    const float* dpar = (const float*)d_in[8];
    const float* opw  = (const float*)d_in[9];
    const float* rmsw = (const float*)d_in[10];
    const float* ln1w = (const float*)d_in[11];
    const float* ln1b = (const float*)d_in[12];
    const float* ln2w = (const float*)d_in[13];
    const float* ln2b = (const float*)d_in[14];
    const float* fw1  = (const float*)d_in[15];
    const float* fb1  = (const float*)d_in[16];
    const float* fw2  = (const float*)d_in[17];
    const float* fb2  = (const float*)d_in[18];
    const float* finw = (const float*)d_in[19];
    const float* finb = (const float*)d_in[20];
    float* out = (float*)d_out;

    float* ws = (float*)d_ws;
    float* h     = ws;                          // 2M floats
    float* hn    = h   + (size_t)ROWS * DM;     // 2M (scan summaries overlay)
    float* xz    = hn  + (size_t)ROWS * DM;     // 8M (cols 0-1023 reused as dxc)
    float* xc    = xz  + (size_t)ROWS * 2048;   // 4M (reused as x2 later)
    float* dbc   = xc  + (size_t)ROWS * DI;     // 256K
    float* dbuf  = dbc + (size_t)ROWS * 64;     // 4M  (d = softplus(delta))
    float* yg    = dbuf + (size_t)ROWS * DI;    // 4M (reused as x3 later)
    // total ~= 24.25M floats ~= 97 MB

    // scan chunk summaries overlay hn: aprod/bacc = 1M floats each; hinit
    // deliberately aliases aprod (scan2 reads each slot before overwriting).
    const size_t SUMN = (size_t)2 * NCH * DI * 16;  // 1M floats
    float* aprod = hn;
    float* bacc  = hn + SUMN;
    float* hinit = aprod;

    // 1. h = LN1(x)
    ln_kernel<<<ROWS, 256, 0, stream>>>(x, ln1w, ln1b, h);

    for (int i = 0; i < 2; ++i) {
        const float* ipw_i  = ipw  + (size_t)i * 2048 * 512;
        const float* cw_i   = cw   + (size_t)i * DI * 4;
        const float* cb_i   = cb   + (size_t)i * DI;
        const float* xpw_i  = xpw  + (size_t)i * 64 * DI;
        const float* dtw_i  = dtw  + (size_t)i * DI * 32;
        const float* dtb_i  = dtb  + (size_t)i * DI;
        const float* alog_i = alog + (size_t)i * DI * 16;
        const float* dp_i   = dpar + (size_t)i * DI;
        const float* opw_i  = opw  + (size_t)i * DM * DI;
        const float* rms_i  = rmsw + (size_t)i * DM;

        // hn = RMS(h)
        rms_kernel<<<ROWS, 256, 0, stream>>>(h, rms_i, hn);
        // xz = hn @ ipw^T   (4096 x 2048 x 512)  [bf16 MFMA]
        mgemm_kernel<0, false, false><<<dim3(2048 / 128, ROWS / 128), 256, 0, stream>>>(
            hn, ipw_i, nullptr, nullptr, xz, ROWS, 2048, 512, 512, 512, 2048);
        // xc = silu(conv(xz[:, :1024]))
        conv_silu_kernel<<<ROWS * DI / 256, 256, 0, stream>>>(xz, cw_i, cb_i, xc);
        // dbc = xc @ xpw^T  (4096 x 64 x 1024)  [fp32, thin]
        gemm_kernel<0, false, false><<<dim3(1, ROWS / 64), 256, 0, stream>>>(
            xc, xpw_i, nullptr, nullptr, dbc, nullptr, ROWS, 64, 1024, 1024, 1024, 64, 0);
        // d = softplus(dbc[:, :32] @ dtw^T + dtb); dxc = d*xc -> xz[:, :1024]
        gemm_kernel<2, true, false><<<dim3(1024 / 64, ROWS / 64), 256, 0, stream>>>(
            dbc, dtw_i, dtb_i, xc, dbuf, xz, ROWS, 1024, 32, 64, 32, 1024, 2048);
        // chunked parallel scan (hn slot is free here)
        scan1_kernel<<<dim3(4, NCH, 2), 256, 0, stream>>>(dbuf, xz, dbc, alog_i,
                                                          aprod, bacc);
        scan2_kernel<<<128, 256, 0, stream>>>(aprod, bacc, hinit);
        scan3_kernel<<<dim3(4, NCH, 2), 256, 0, stream>>>(dbuf, xz, xc, dbc, alog_i,
                                                          dp_i, hinit, yg);
        // h = h + yg @ opw^T  (4096 x 512 x 1024)  [bf16 MFMA + residual]
        mgemm_kernel<0, false, true><<<dim3(DM / 128, ROWS / 128), 256, 0, stream>>>(
            yg, opw_i, nullptr, h, h, ROWS, DM, DI, DI, DI, DM);
    }

    // x2 = x + h  (store in xc slot)
    float* x2 = xc;
    add_kernel<<<ROWS * DM / 256, 256, 0, stream>>>(x, h, x2, ROWS * DM);
    // hn = LN2(x2)
    ln_kernel<<<ROWS, 256, 0, stream>>>(x2, ln2w, ln2b, hn);
    // mid = relu(hn @ fw1^T + fb1)  (4096 x 1024 x 512)  [bf16 MFMA]
    float* mid = xz;
    mgemm_kernel<1, true, false><<<dim3(DI / 128, ROWS / 128), 256, 0, stream>>>(
        hn, fw1, fb1, nullptr, mid, ROWS, DI, DM, DM, DM, DI);
    // x3 = x2 + mid @ fw2^T + fb2  (4096 x 512 x 1024)  [bf16 MFMA]
    float* x3 = yg;
    mgemm_kernel<0, true, true><<<dim3(DM / 128, ROWS / 128), 256, 0, stream>>>(
        mid, fw2, fb2, x2, x3, ROWS, DM, DI, DI, DI, DM);
    // out = x3 @ finw^T + finb  (4096 x 512 x 512)  [bf16 MFMA]
    mgemm_kernel<0, true, false><<<dim3(DM / 128, ROWS / 128), 256, 0, stream>>>(
        x3, finw, finb, nullptr, out, ROWS, DM, DM, DM, DM, DM);
}

// Round 7
// 837.591 us; speedup vs baseline: 6.4133x; 1.0419x over previous
//
#include <hip/hip_runtime.h>
#include <math.h>

#define ROWS 4096   // B * L
#define LSEQ 2048
#define DM   512
#define DI   1024
#define NCH  32            // scan chunks per sequence
#define CHT  (LSEQ / NCH)  // 64 timesteps per chunk
#define NCOMB 1152         // combined x_proj/dt GEMM N (1024 delta + 32 B/C + 96 pad)

typedef __bf16 bf16_t;
typedef bf16_t bf16x8 __attribute__((ext_vector_type(8)));
typedef float f32x4 __attribute__((ext_vector_type(4)));

__device__ __forceinline__ float siluf(float v) { return v / (1.f + expf(-v)); }
__device__ __forceinline__ float softplusf(float v) {
    return fmaxf(v, 0.f) + log1pf(expf(-fabsf(v)));
}

// ---------------- LayerNorm: one block per row of 512 ----------------
__global__ __launch_bounds__(256) void ln_kernel(const float* __restrict__ x,
                                                 const float* __restrict__ w,
                                                 const float* __restrict__ b,
                                                 float* __restrict__ out) {
    int row = blockIdx.x;
    int tid = threadIdx.x;
    const float* xr = x + (size_t)row * DM;
    float v0 = xr[tid], v1 = xr[tid + 256];
    float sum = v0 + v1, sq = v0 * v0 + v1 * v1;
    for (int o = 32; o > 0; o >>= 1) {
        sum += __shfl_down(sum, o);
        sq  += __shfl_down(sq, o);
    }
    __shared__ float s1[4], s2[4];
    int wid = tid >> 6, lane = tid & 63;
    if (lane == 0) { s1[wid] = sum; s2[wid] = sq; }
    __syncthreads();
    sum = s1[0] + s1[1] + s1[2] + s1[3];
    sq  = s2[0] + s2[1] + s2[2] + s2[3];
    float mu  = sum * (1.f / DM);
    float var = sq * (1.f / DM) - mu * mu;
    float r   = rsqrtf(var + 1e-5f);
    out[(size_t)row * DM + tid]       = (v0 - mu) * r * w[tid] + b[tid];
    out[(size_t)row * DM + tid + 256] = (v1 - mu) * r * w[tid + 256] + b[tid + 256];
}

// ---------------- RMSNorm: one block per row of 512 ----------------
__global__ __launch_bounds__(256) void rms_kernel(const float* __restrict__ x,
                                                  const float* __restrict__ w,
                                                  float* __restrict__ out) {
    int row = blockIdx.x;
    int tid = threadIdx.x;
    const float* xr = x + (size_t)row * DM;
    float v0 = xr[tid], v1 = xr[tid + 256];
    float sq = v0 * v0 + v1 * v1;
    for (int o = 32; o > 0; o >>= 1) sq += __shfl_down(sq, o);
    __shared__ float s2[4];
    int wid = tid >> 6, lane = tid & 63;
    if (lane == 0) s2[wid] = sq;
    __syncthreads();
    sq = s2[0] + s2[1] + s2[2] + s2[3];
    float r = rsqrtf(sq * (1.f / DM) + 1e-5f);
    out[(size_t)row * DM + tid]       = v0 * r * w[tid];
    out[(size_t)row * DM + tid + 256] = v1 * r * w[tid + 256];
}

// ---------------- bf16 MFMA GEMM: C = A @ W^T ----------------------------
// A:(M,K) fp32, W:(N,K) fp32; staged to LDS as bf16; fp32 accum via MFMA.
// 128x128 tile, 4 waves (2x2) of 64x64, BK=32, 16x16x32 bf16 MFMA.
// LDS rows padded to 40 bf16 (80B) to break the 8-way read bank conflict.
// ACT: 0=none, 1=relu, 2=combined mamba epilogue:
//   col<1024 : d=softplus(v+bias[col]); C[row*ldc+col]=d; dxc[row*2048+col]=d*xcp[..]
//   col<1056 : bcb[row*32 + col-1024] = v   (B/C rows)
//   else     : discard (zero-pad region)
template <int ACT, bool BIAS, bool RES>
__global__ __launch_bounds__(256) void mgemm_kernel(
    const float* __restrict__ A, const float* __restrict__ W,
    const float* __restrict__ bias, const float* __restrict__ res,
    float* __restrict__ C, int M, int N, int K, int lda, int ldb, int ldc,
    const float* __restrict__ xcp, float* __restrict__ dxc,
    float* __restrict__ bcb) {
    __shared__ bf16_t As[128][40];
    __shared__ bf16_t Bs[128][40];
    const int tid  = threadIdx.x;
    const int lane = tid & 63;
    const int wave = tid >> 6;
    const int wr = wave >> 1, wc = wave & 1;   // 2x2 wave grid
    const int bm = blockIdx.y * 128, bn = blockIdx.x * 128;
    const int srow = tid >> 1;                 // staging row 0..127
    const int scol = (tid & 1) * 16;           // staging k-offset 0/16
    const int kgrp = lane >> 4, l16 = lane & 15;

    f32x4 acc[4][4] = {};

    const float* pa = A + (size_t)(bm + srow) * lda + scol;
    const float* pb = W + (size_t)(bn + srow) * ldb + scol;

    for (int k0 = 0; k0 < K; k0 += 32) {
        f32x4 av[4], bv[4];
#pragma unroll
        for (int q = 0; q < 4; ++q) {
            av[q] = *(const f32x4*)(pa + k0 + q * 4);
            bv[q] = *(const f32x4*)(pb + k0 + q * 4);
        }
        bf16_t at[16], bt[16];
#pragma unroll
        for (int q = 0; q < 4; ++q)
#pragma unroll
            for (int j = 0; j < 4; ++j) {
                at[q * 4 + j] = (bf16_t)av[q][j];
                bt[q * 4 + j] = (bf16_t)bv[q][j];
            }
        __syncthreads();  // previous iter's LDS reads complete
        *(bf16x8*)&As[srow][scol]     = *(bf16x8*)&at[0];
        *(bf16x8*)&As[srow][scol + 8] = *(bf16x8*)&at[8];
        *(bf16x8*)&Bs[srow][scol]     = *(bf16x8*)&bt[0];
        *(bf16x8*)&Bs[srow][scol + 8] = *(bf16x8*)&bt[8];
        __syncthreads();
        bf16x8 af[4], bfr[4];
#pragma unroll
        for (int i = 0; i < 4; ++i) {
            af[i]  = *(bf16x8*)&As[wr * 64 + i * 16 + l16][kgrp * 8];
            bfr[i] = *(bf16x8*)&Bs[wc * 64 + i * 16 + l16][kgrp * 8];
        }
#pragma unroll
        for (int i = 0; i < 4; ++i)
#pragma unroll
            for (int j = 0; j < 4; ++j)
                acc[i][j] = __builtin_amdgcn_mfma_f32_16x16x32_bf16(
                    af[i], bfr[j], acc[i][j], 0, 0, 0);
    }
    // epilogue: C/D layout col=lane&15, row=(lane>>4)*4+q  [m89/m91 verified]
#pragma unroll
    for (int i = 0; i < 4; ++i) {
#pragma unroll
        for (int j = 0; j < 4; ++j) {
            int col = bn + wc * 64 + j * 16 + l16;
            if (ACT == 2) {
                if (col < 1024) {
                    float badd = bias[col];
#pragma unroll
                    for (int q = 0; q < 4; ++q) {
                        int row = bm + wr * 64 + i * 16 + kgrp * 4 + q;
                        float d = softplusf(acc[i][j][q] + badd);
                        C[(size_t)row * ldc + col] = d;
                        dxc[(size_t)row * 2048 + col] =
                            d * xcp[(size_t)row * 1024 + col];
                    }
                } else if (col < 1056) {
#pragma unroll
                    for (int q = 0; q < 4; ++q) {
                        int row = bm + wr * 64 + i * 16 + kgrp * 4 + q;
                        bcb[(size_t)row * 32 + (col - 1024)] = acc[i][j][q];
                    }
                }
            } else {
                float badd = BIAS ? bias[col] : 0.f;
#pragma unroll
                for (int q = 0; q < 4; ++q) {
                    int row = bm + wr * 64 + i * 16 + kgrp * 4 + q;
                    float v = acc[i][j][q] + badd;
                    if (RES) v += res[(size_t)row * ldc + col];
                    if (ACT == 1) v = fmaxf(v, 0.f);
                    C[(size_t)row * ldc + col] = v;
                }
            }
        }
    }
}

// ---------------- Wcomb builder: rows 0-1023 = dtw @ xpw[:32] (fp32),
// rows 1024-1055 = xpw[32:64] (B/C rows), rows 1056-1151 = 0.
__global__ __launch_bounds__(256) void wd_kernel(
    const float* __restrict__ dtw, const float* __restrict__ xpw,
    float* __restrict__ wcomb) {
    int idx = blockIdx.x * 256 + threadIdx.x;  // NCOMB*1024
    int j = idx & 1023;
    int i = idx >> 10;
    float v;
    if (i < 1024) {
        const float* dr = dtw + i * 32;
        v = 0.f;
#pragma unroll
        for (int k = 0; k < 32; ++k) v = fmaf(dr[k], xpw[k * 1024 + j], v);
    } else if (i < 1056) {
        v = xpw[(i - 1024 + 32) * 1024 + j];
    } else {
        v = 0.f;
    }
    wcomb[idx] = v;
}

// ---------------- causal depthwise conv (D_CONV=4) + SiLU ----------------
__global__ __launch_bounds__(256) void conv_silu_kernel(
    const float* __restrict__ xz, const float* __restrict__ cw,
    const float* __restrict__ cb, float* __restrict__ out) {
    int idx = blockIdx.x * blockDim.x + threadIdx.x;  // ROWS*DI
    int c = idx & (DI - 1);
    int row = idx >> 10;
    int t = row & (LSEQ - 1);
    float acc = cb[c];
#pragma unroll
    for (int k = 0; k < 4; ++k) {
        int st = t + k - 3;
        if (st >= 0) acc = fmaf(cw[c * 4 + k], xz[(size_t)(row + k - 3) * 2048 + c], acc);
    }
    out[idx] = siluf(acc);
}

// ---------------- chunked parallel scan, register-state version ----------
// h_t = dA_t h_{t-1} + dBx_t with dA = exp2(d * cAn), dBx = dxc * B.
// bc: (ROWS, 32) = [B(16) | C(16)] per row.
__global__ __launch_bounds__(256) void scan1_kernel(
    const float* __restrict__ dbuf, const float* __restrict__ xzbuf,
    const float* __restrict__ bc_in, const float* __restrict__ A_log,
    float* __restrict__ aprod, float* __restrict__ bacc) {
    int e  = blockIdx.x * 256 + threadIdx.x;
    int ch = blockIdx.y;
    int b  = blockIdx.z;
    float cAn[16];
#pragma unroll
    for (int n = 0; n < 16; ++n)
        cAn[n] = -expf(A_log[e * 16 + n]) * 1.4426950408889634f;
    float ap[16], bc[16];
#pragma unroll
    for (int n = 0; n < 16; ++n) { ap[n] = 1.f; bc[n] = 0.f; }
    int row0 = b * LSEQ + ch * CHT;
    float d_c   = dbuf[(size_t)row0 * DI + e];
    float dxc_c = xzbuf[(size_t)row0 * 2048 + e];
    for (int t = 0; t < CHT; ++t) {
        int row = row0 + t;
        float d_n = 0.f, dxc_n = 0.f;
        if (t + 1 < CHT) {
            d_n   = dbuf[(size_t)(row + 1) * DI + e];
            dxc_n = xzbuf[(size_t)(row + 1) * 2048 + e];
        }
        const float* brow = bc_in + (size_t)row * 32;  // block-uniform
        float Bn[16];
#pragma unroll
        for (int n = 0; n < 16; ++n) Bn[n] = brow[n];
#pragma unroll
        for (int n = 0; n < 16; ++n) {
            float dA = exp2f(d_c * cAn[n]);
            ap[n] *= dA;
            bc[n] = fmaf(dA, bc[n], dxc_c * Bn[n]);
        }
        d_c = d_n; dxc_c = dxc_n;
    }
    size_t idx = ((size_t)((b * NCH + ch) * DI + e)) * 16;
    float4* apo = (float4*)(aprod + idx);
    float4* bco = (float4*)(bacc + idx);
#pragma unroll
    for (int q = 0; q < 4; ++q) {
        apo[q] = make_float4(ap[q * 4], ap[q * 4 + 1], ap[q * 4 + 2], ap[q * 4 + 3]);
        bco[q] = make_float4(bc[q * 4], bc[q * 4 + 1], bc[q * 4 + 2], bc[q * 4 + 3]);
    }
}

// scan2: serial combine across NCH chunks -> h_init per chunk.
// NOTE: hinit aliases aprod (read-before-write per index) — no __restrict__.
__global__ __launch_bounds__(256) void scan2_kernel(
    const float* aprod, const float* bacc, float* hinit) {
    int tid = blockIdx.x * 256 + threadIdx.x;  // 32768 = (b,e,n)
    int n = tid & 15;
    int e = (tid >> 4) & (DI - 1);
    int b = tid >> 14;
    float h = 0.f;
    for (int ch = 0; ch < NCH; ++ch) {
        size_t idx = ((size_t)((b * NCH + ch) * DI + e)) * 16 + n;
        float a  = aprod[idx];
        float bb = bacc[idx];
        hinit[idx] = h;
        h = fmaf(a, h, bb);
    }
}

// scan3: re-run each chunk from h_init; fuse C-contraction + D-skip + gate.
__global__ __launch_bounds__(256) void scan3_kernel(
    const float* __restrict__ dbuf, const float* __restrict__ xzbuf,
    const float* __restrict__ xc, const float* __restrict__ bc_in,
    const float* __restrict__ A_log, const float* __restrict__ Dp,
    const float* __restrict__ hinit, float* __restrict__ yg) {
    int e  = blockIdx.x * 256 + threadIdx.x;
    int ch = blockIdx.y;
    int b  = blockIdx.z;
    float cAn[16];
#pragma unroll
    for (int n = 0; n < 16; ++n)
        cAn[n] = -expf(A_log[e * 16 + n]) * 1.4426950408889634f;
    float h[16];
    {
        const float4* hp = (const float4*)(hinit + ((size_t)((b * NCH + ch) * DI + e)) * 16);
#pragma unroll
        for (int q = 0; q < 4; ++q) {
            float4 v = hp[q];
            h[q * 4] = v.x; h[q * 4 + 1] = v.y; h[q * 4 + 2] = v.z; h[q * 4 + 3] = v.w;
        }
    }
    float Dpe = Dp[e];
    int row0 = b * LSEQ + ch * CHT;
    float d_c   = dbuf[(size_t)row0 * DI + e];
    float dxc_c = xzbuf[(size_t)row0 * 2048 + e];
    float xc_c  = xc[(size_t)row0 * DI + e];
    float z_c   = xzbuf[(size_t)row0 * 2048 + 1024 + e];
    for (int t = 0; t < CHT; ++t) {
        int row = row0 + t;
        float d_n = 0.f, dxc_n = 0.f, xc_n = 0.f, z_n = 0.f;
        if (t + 1 < CHT) {
            d_n   = dbuf[(size_t)(row + 1) * DI + e];
            dxc_n = xzbuf[(size_t)(row + 1) * 2048 + e];
            xc_n  = xc[(size_t)(row + 1) * DI + e];
            z_n   = xzbuf[(size_t)(row + 1) * 2048 + 1024 + e];
        }
        const float* brow = bc_in + (size_t)row * 32;  // block-uniform
        float Bn[16], Cn[16];
#pragma unroll
        for (int n = 0; n < 16; ++n) { Bn[n] = brow[n]; Cn[n] = brow[16 + n]; }
        float y = Dpe * xc_c;
#pragma unroll
        for (int n = 0; n < 16; ++n) {
            float dA = exp2f(d_c * cAn[n]);
            h[n] = fmaf(dA, h[n], dxc_c * Bn[n]);
            y = fmaf(h[n], Cn[n], y);
        }
        yg[(size_t)row * DI + e] = y * siluf(z_c);
        d_c = d_n; dxc_c = dxc_n; xc_c = xc_n; z_c = z_n;
    }
}

// ---------------- elementwise add ----------------
__global__ __launch_bounds__(256) void add_kernel(const float* __restrict__ a,
                                                  const float* __restrict__ b,
                                                  float* __restrict__ c, int n) {
    int i = blockIdx.x * blockDim.x + threadIdx.x;
    if (i < n) c[i] = a[i] + b[i];
}

extern "C" void kernel_launch(void* const* d_in, const int* in_sizes, int n_in,
                              void* d_out, int out_size, void* d_ws, size_t ws_size,
                              hipStream_t stream) {
    const float* x    = (const float*)d_in[0];
    const float* ipw  = (const float*)d_in[1];
    const float* cw   = (const float*)d_in[2];
    const float* cb   = (const float*)d_in[3];
    const float* xpw  = (const float*)d_in[4];
    const float* dtw  = (const float*)d_in[5];
    const float* dtb  = (const float*)d_in[6];
    const float* alog = (const float*)d_in[7];
    const float* dpar = (const float*)d_in[8];
    const float* opw  = (const float*)d_in[9];
    const float* rmsw = (const float*)d_in[10];
    const float* ln1w = (const float*)d_in[11];
    const float* ln1b = (const float*)d_in[12];
    const float* ln2w = (const float*)d_in[13];
    const float* ln2b = (const float*)d_in[14];
    const float* fw1  = (const float*)d_in[15];
    const float* fb1  = (const float*)d_in[16];
    const float* fw2  = (const float*)d_in[17];
    const float* fb2  = (const float*)d_in[18];
    const float* finw = (const float*)d_in[19];
    const float* finb = (const float*)d_in[20];
    float* out = (float*)d_out;

    float* ws = (float*)d_ws;
    float* h     = ws;                          // 2M floats
    float* hn    = h   + (size_t)ROWS * DM;     // 2M (scan summaries overlay)
    float* xz    = hn  + (size_t)ROWS * DM;     // 8M (cols 0-1023 reused as dxc)
    float* xc    = xz  + (size_t)ROWS * 2048;   // 4M (reused as x2 later)
    float* bcbuf = xc  + (size_t)ROWS * DI;     // 256K slot (uses ROWS*32)
    float* dbuf  = bcbuf + (size_t)ROWS * 64;   // 4M  (d = softplus(delta))
    float* yg    = dbuf + (size_t)ROWS * DI;    // 4M (reused: wcomb, x3)
    // total ~= 24.25M floats ~= 97 MB

    // scan chunk summaries overlay hn: aprod/bacc = 1M floats each; hinit
    // deliberately aliases aprod (scan2 reads each slot before overwriting).
    const size_t SUMN = (size_t)2 * NCH * DI * 16;  // 1M floats
    float* aprod = hn;
    float* bacc  = hn + SUMN;
    float* hinit = aprod;
    // wcomb (1152x1024 fp32 = 1.18M) overlays yg: dead before scan3 writes yg.
    float* wcomb = yg;

    // 1. h = LN1(x)
    ln_kernel<<<ROWS, 256, 0, stream>>>(x, ln1w, ln1b, h);

    for (int i = 0; i < 2; ++i) {
        const float* ipw_i  = ipw  + (size_t)i * 2048 * 512;
        const float* cw_i   = cw   + (size_t)i * DI * 4;
        const float* cb_i   = cb   + (size_t)i * DI;
        const float* xpw_i  = xpw  + (size_t)i * 64 * DI;
        const float* dtw_i  = dtw  + (size_t)i * DI * 32;
        const float* dtb_i  = dtb  + (size_t)i * DI;
        const float* alog_i = alog + (size_t)i * DI * 16;
        const float* dp_i   = dpar + (size_t)i * DI;
        const float* opw_i  = opw  + (size_t)i * DM * DI;
        const float* rms_i  = rmsw + (size_t)i * DM;

        // hn = RMS(h)
        rms_kernel<<<ROWS, 256, 0, stream>>>(h, rms_i, hn);
        // xz = hn @ ipw^T   (4096 x 2048 x 512)  [bf16 MFMA]
        mgemm_kernel<0, false, false><<<dim3(2048 / 128, ROWS / 128), 256, 0, stream>>>(
            hn, ipw_i, nullptr, nullptr, xz, ROWS, 2048, 512, 512, 512, 2048,
            nullptr, nullptr, nullptr);
        // xc = silu(conv(xz[:, :1024]))
        conv_silu_kernel<<<ROWS * DI / 256, 256, 0, stream>>>(xz, cw_i, cb_i, xc);
        // wcomb = [dtw @ xpw[:32] ; xpw[32:64] ; 0]  (1152 x 1024 fp32)
        wd_kernel<<<NCOMB * 1024 / 256, 256, 0, stream>>>(dtw_i, xpw_i, wcomb);
        // combined: d=softplus(xc@Wd^T+dtb) -> dbuf; dxc=d*xc -> xz[:,:1024];
        //           B/C = xc@xpw[32:64]^T -> bcbuf   [bf16 MFMA, N=1152]
        mgemm_kernel<2, false, false><<<dim3(NCOMB / 128, ROWS / 128), 256, 0, stream>>>(
            xc, wcomb, dtb_i, nullptr, dbuf, ROWS, NCOMB, 1024, 1024, 1024, 1024,
            xc, xz, bcbuf);
        // chunked parallel scan (hn slot is free here)
        scan1_kernel<<<dim3(4, NCH, 2), 256, 0, stream>>>(dbuf, xz, bcbuf, alog_i,
                                                          aprod, bacc);
        scan2_kernel<<<128, 256, 0, stream>>>(aprod, bacc, hinit);
        scan3_kernel<<<dim3(4, NCH, 2), 256, 0, stream>>>(dbuf, xz, xc, bcbuf, alog_i,
                                                          dp_i, hinit, yg);
        // h = h + yg @ opw^T  (4096 x 512 x 1024)  [bf16 MFMA + residual]
        mgemm_kernel<0, false, true><<<dim3(DM / 128, ROWS / 128), 256, 0, stream>>>(
            yg, opw_i, nullptr, h, h, ROWS, DM, DI, DI, DI, DM,
            nullptr, nullptr, nullptr);
    }

    // x2 = x + h  (store in xc slot)
    float* x2 = xc;
    add_kernel<<<ROWS * DM / 256, 256, 0, stream>>>(x, h, x2, ROWS * DM);
    // hn = LN2(x2)
    ln_kernel<<<ROWS, 256, 0, stream>>>(x2, ln2w, ln2b, hn);
    // mid = relu(hn @ fw1^T + fb1)  (4096 x 1024 x 512)  [bf16 MFMA]
    float* mid = xz;
    mgemm_kernel<1, true, false><<<dim3(DI / 128, ROWS / 128), 256, 0, stream>>>(
        hn, fw1, fb1, nullptr, mid, ROWS, DI, DM, DM, DM, DI,
        nullptr, nullptr, nullptr);
    // x3 = x2 + mid @ fw2^T + fb2  (4096 x 512 x 1024)  [bf16 MFMA]
    float* x3 = yg;
    mgemm_kernel<0, true, true><<<dim3(DM / 128, ROWS / 128), 256, 0, stream>>>(
        mid, fw2, fb2, x2, x3, ROWS, DM, DI, DI, DI, DM,
        nullptr, nullptr, nullptr);
    // out = x3 @ finw^T + finb  (4096 x 512 x 512)  [bf16 MFMA]
    mgemm_kernel<0, true, false><<<dim3(DM / 128, ROWS / 128), 256, 0, stream>>>(
        x3, finw, finb, nullptr, out, ROWS, DM, DM, DM, DM, DM,
        nullptr, nullptr, nullptr);
}

// Round 8
// 699.857 us; speedup vs baseline: 7.6754x; 1.1968x over previous
//
#include <hip/hip_runtime.h>
#include <math.h>

#define ROWS 4096   // B * L
#define LSEQ 2048
#define DM   512
#define DI   1024
#define NCH  32            // scan chunks per sequence
#define CHT  (LSEQ / NCH)  // 64 timesteps per chunk
#define NCOMB 1152         // combined x_proj/dt GEMM N (1024 delta + 32 B/C + 96 pad)

typedef __bf16 bf16_t;
typedef bf16_t bf16x8 __attribute__((ext_vector_type(8)));
typedef float f32x4 __attribute__((ext_vector_type(4)));
typedef unsigned int u32;
typedef const __attribute__((address_space(1))) u32* gp32;
typedef __attribute__((address_space(3))) u32* lp32;

__device__ __forceinline__ float siluf(float v) { return v / (1.f + expf(-v)); }
__device__ __forceinline__ float softplusf(float v) {
    return fmaxf(v, 0.f) + log1pf(expf(-fabsf(v)));
}

// ---------------- LayerNorm: one block per row of 512 ----------------
template <bool OUTBF>
__global__ __launch_bounds__(256) void ln_kernel(const float* __restrict__ x,
                                                 const float* __restrict__ w,
                                                 const float* __restrict__ b,
                                                 void* __restrict__ outv) {
    int row = blockIdx.x;
    int tid = threadIdx.x;
    const float* xr = x + (size_t)row * DM;
    float v0 = xr[tid], v1 = xr[tid + 256];
    float sum = v0 + v1, sq = v0 * v0 + v1 * v1;
    for (int o = 32; o > 0; o >>= 1) {
        sum += __shfl_down(sum, o);
        sq  += __shfl_down(sq, o);
    }
    __shared__ float s1[4], s2[4];
    int wid = tid >> 6, lane = tid & 63;
    if (lane == 0) { s1[wid] = sum; s2[wid] = sq; }
    __syncthreads();
    sum = s1[0] + s1[1] + s1[2] + s1[3];
    sq  = s2[0] + s2[1] + s2[2] + s2[3];
    float mu  = sum * (1.f / DM);
    float var = sq * (1.f / DM) - mu * mu;
    float r   = rsqrtf(var + 1e-5f);
    float o0 = (v0 - mu) * r * w[tid] + b[tid];
    float o1 = (v1 - mu) * r * w[tid + 256] + b[tid + 256];
    if (OUTBF) {
        bf16_t* out = (bf16_t*)outv;
        out[(size_t)row * DM + tid]       = (bf16_t)o0;
        out[(size_t)row * DM + tid + 256] = (bf16_t)o1;
    } else {
        float* out = (float*)outv;
        out[(size_t)row * DM + tid]       = o0;
        out[(size_t)row * DM + tid + 256] = o1;
    }
}

// ---------------- RMSNorm: one block per row of 512, bf16 out -------------
__global__ __launch_bounds__(256) void rms_kernel(const float* __restrict__ x,
                                                  const float* __restrict__ w,
                                                  bf16_t* __restrict__ out) {
    int row = blockIdx.x;
    int tid = threadIdx.x;
    const float* xr = x + (size_t)row * DM;
    float v0 = xr[tid], v1 = xr[tid + 256];
    float sq = v0 * v0 + v1 * v1;
    for (int o = 32; o > 0; o >>= 1) sq += __shfl_down(sq, o);
    __shared__ float s2[4];
    int wid = tid >> 6, lane = tid & 63;
    if (lane == 0) s2[wid] = sq;
    __syncthreads();
    sq = s2[0] + s2[1] + s2[2] + s2[3];
    float r = rsqrtf(sq * (1.f / DM) + 1e-5f);
    out[(size_t)row * DM + tid]       = (bf16_t)(v0 * r * w[tid]);
    out[(size_t)row * DM + tid + 256] = (bf16_t)(v1 * r * w[tid + 256]);
}

// ---------------- weight f32 -> bf16 arena converter ----------------------
__global__ __launch_bounds__(256) void cvt_kernel(
    const float* __restrict__ ipw, const float* __restrict__ opw,
    const float* __restrict__ fw1, const float* __restrict__ fw2,
    const float* __restrict__ finw, bf16_t* __restrict__ arena) {
    int idx = blockIdx.x * 256 + threadIdx.x;
    float v;
    if (idx < 2097152)      v = ipw[idx];
    else if (idx < 3145728) v = opw[idx - 2097152];
    else if (idx < 3670016) v = fw1[idx - 3145728];
    else if (idx < 4194304) v = fw2[idx - 3670016];
    else                    v = finw[idx - 4194304];
    arena[idx] = (bf16_t)v;
}

// ---------------- Wcomb builder (bf16 out) --------------------------------
// rows 0-1023 = dtw @ xpw[:32]; rows 1024-1055 = xpw[32:64]; rest 0.
__global__ __launch_bounds__(256) void wd_kernel(
    const float* __restrict__ dtw, const float* __restrict__ xpw,
    bf16_t* __restrict__ wcomb) {
    int idx = blockIdx.x * 256 + threadIdx.x;  // NCOMB*1024
    int j = idx & 1023;
    int i = idx >> 10;
    float v;
    if (i < 1024) {
        const float* dr = dtw + i * 32;
        v = 0.f;
#pragma unroll
        for (int k = 0; k < 32; ++k) v = fmaf(dr[k], xpw[k * 1024 + j], v);
    } else if (i < 1056) {
        v = xpw[(i - 1024 + 32) * 1024 + j];
    } else {
        v = 0.f;
    }
    wcomb[idx] = (bf16_t)v;
}

// ---------------- bf16 MFMA GEMM: C = A @ W^T -----------------------------
// A:(M,K) bf16, W:(N,K) bf16. BK=64, 128x128 tile, 4 waves (2x2) of 64x64.
// global_load_lds(16B) direct staging; XOR swizzle piece^=(row&7) applied to
// BOTH the global source (inverse) and the ds_read (rule #21) -> conflict-free.
// ACT: 0 none, 1 relu, 2 comb-mamba epilogue, 3 in_proj split epilogue.
template <int ACT, bool BIAS, bool RES, bool OUTBF>
__global__ __launch_bounds__(256) void mgemm_kernel(
    const bf16_t* __restrict__ A, const bf16_t* __restrict__ W,
    const float* __restrict__ bias, const float* __restrict__ res,
    void* __restrict__ Cv, int M, int N, int K, int ldc,
    const bf16_t* __restrict__ xcp, float* __restrict__ dxc,
    float* __restrict__ bcb, void* __restrict__ aux) {
    __shared__ bf16_t As[128 * 64];
    __shared__ bf16_t Bs[128 * 64];
    const int tid  = threadIdx.x;
    const int lane = tid & 63;
    const int wave = tid >> 6;
    const int wr = wave >> 1, wc = wave & 1;
    const int bm = blockIdx.y * 128, bn = blockIdx.x * 128;
    const int l16 = lane & 15, kgrp = lane >> 4;
    const int prow = tid >> 3;      // staging row (0..31) per iteration
    const int pp   = tid & 7;       // staging 16B piece within 128B row
    const int wbase = (tid & ~63) * 8;  // wave-uniform LDS bf16 offset

    f32x4 acc[4][4] = {};

    for (int k0 = 0; k0 < K; k0 += 64) {
        __syncthreads();
#pragma unroll
        for (int it = 0; it < 4; ++it) {
            int r  = it * 32 + prow;
            int gc = k0 + ((pp ^ (r & 7)) << 3);  // inverse-swizzled source col
            const bf16_t* ga = A + (size_t)(bm + r) * K + gc;
            const bf16_t* gb = W + (size_t)(bn + r) * K + gc;
            __builtin_amdgcn_global_load_lds((gp32)(const void*)ga,
                (lp32)(void*)(As + it * 2048 + wbase), 16, 0, 0);
            __builtin_amdgcn_global_load_lds((gp32)(const void*)gb,
                (lp32)(void*)(Bs + it * 2048 + wbase), 16, 0, 0);
        }
        __syncthreads();
#pragma unroll
        for (int ks = 0; ks < 2; ++ks) {
            bf16x8 af[4], bv[4];
#pragma unroll
            for (int i = 0; i < 4; ++i) {
                int ra = wr * 64 + i * 16 + l16;
                int rb = wc * 64 + i * 16 + l16;
                af[i] = *(const bf16x8*)(As + ra * 64 + ((((ks << 2) | kgrp) ^ (ra & 7)) << 3));
                bv[i] = *(const bf16x8*)(Bs + rb * 64 + ((((ks << 2) | kgrp) ^ (rb & 7)) << 3));
            }
#pragma unroll
            for (int i = 0; i < 4; ++i)
#pragma unroll
                for (int j = 0; j < 4; ++j)
                    acc[i][j] = __builtin_amdgcn_mfma_f32_16x16x32_bf16(
                        af[i], bv[j], acc[i][j], 0, 0, 0);
        }
    }
    // epilogue: C/D layout col=lane&15, row=(lane>>4)*4+q  [m89/m91 verified]
#pragma unroll
    for (int i = 0; i < 4; ++i) {
#pragma unroll
        for (int j = 0; j < 4; ++j) {
            int col = bn + wc * 64 + j * 16 + l16;
            if (ACT == 2) {
                if (col < 1024) {
                    float badd = bias[col];
#pragma unroll
                    for (int q = 0; q < 4; ++q) {
                        int row = bm + wr * 64 + i * 16 + kgrp * 4 + q;
                        float d = softplusf(acc[i][j][q] + badd);
                        ((float*)Cv)[(size_t)row * 1024 + col] = d;
                        dxc[(size_t)row * 1024 + col] =
                            d * (float)xcp[(size_t)row * 1024 + col];
                    }
                } else if (col < 1056) {
#pragma unroll
                    for (int q = 0; q < 4; ++q) {
                        int row = bm + wr * 64 + i * 16 + kgrp * 4 + q;
                        bcb[(size_t)row * 32 + (col - 1024)] = acc[i][j][q];
                    }
                }
            } else if (ACT == 3) {
#pragma unroll
                for (int q = 0; q < 4; ++q) {
                    int row = bm + wr * 64 + i * 16 + kgrp * 4 + q;
                    float v = acc[i][j][q];
                    if (col < 1024)
                        ((float*)Cv)[(size_t)row * 1024 + col] = v;
                    else
                        ((bf16_t*)aux)[(size_t)row * 1024 + (col - 1024)] = (bf16_t)v;
                }
            } else {
                float badd = BIAS ? bias[col] : 0.f;
#pragma unroll
                for (int q = 0; q < 4; ++q) {
                    int row = bm + wr * 64 + i * 16 + kgrp * 4 + q;
                    float v = acc[i][j][q] + badd;
                    if (RES) v += res[(size_t)row * ldc + col];
                    if (ACT == 1) v = fmaxf(v, 0.f);
                    if (OUTBF) ((bf16_t*)Cv)[(size_t)row * ldc + col] = (bf16_t)v;
                    else       ((float*)Cv)[(size_t)row * ldc + col] = v;
                }
            }
        }
    }
}

// ---------------- causal depthwise conv (D_CONV=4) + SiLU -> bf16 ---------
__global__ __launch_bounds__(256) void conv_silu_kernel(
    const float* __restrict__ xraw, const float* __restrict__ cw,
    const float* __restrict__ cb, bf16_t* __restrict__ out) {
    int idx = blockIdx.x * blockDim.x + threadIdx.x;  // ROWS*DI
    int c = idx & (DI - 1);
    int row = idx >> 10;
    int t = row & (LSEQ - 1);
    float acc = cb[c];
#pragma unroll
    for (int k = 0; k < 4; ++k) {
        int st = t + k - 3;
        if (st >= 0) acc = fmaf(cw[c * 4 + k], xraw[(size_t)(row + k - 3) * 1024 + c], acc);
    }
    out[idx] = (bf16_t)siluf(acc);
}

// ---------------- chunked parallel scan, register-state version ----------
__global__ __launch_bounds__(256) void scan1_kernel(
    const float* __restrict__ dbuf, const float* __restrict__ dxcb,
    const float* __restrict__ bc_in, const float* __restrict__ A_log,
    float* __restrict__ aprod, float* __restrict__ bacc) {
    int e  = blockIdx.x * 256 + threadIdx.x;
    int ch = blockIdx.y;
    int b  = blockIdx.z;
    float cAn[16];
#pragma unroll
    for (int n = 0; n < 16; ++n)
        cAn[n] = -expf(A_log[e * 16 + n]) * 1.4426950408889634f;
    float ap[16], bc[16];
#pragma unroll
    for (int n = 0; n < 16; ++n) { ap[n] = 1.f; bc[n] = 0.f; }
    int row0 = b * LSEQ + ch * CHT;
    float d_c   = dbuf[(size_t)row0 * DI + e];
    float dxc_c = dxcb[(size_t)row0 * 1024 + e];
    for (int t = 0; t < CHT; ++t) {
        int row = row0 + t;
        float d_n = 0.f, dxc_n = 0.f;
        if (t + 1 < CHT) {
            d_n   = dbuf[(size_t)(row + 1) * DI + e];
            dxc_n = dxcb[(size_t)(row + 1) * 1024 + e];
        }
        const float* brow = bc_in + (size_t)row * 32;  // block-uniform
        float Bn[16];
#pragma unroll
        for (int n = 0; n < 16; ++n) Bn[n] = brow[n];
#pragma unroll
        for (int n = 0; n < 16; ++n) {
            float dA = exp2f(d_c * cAn[n]);
            ap[n] *= dA;
            bc[n] = fmaf(dA, bc[n], dxc_c * Bn[n]);
        }
        d_c = d_n; dxc_c = dxc_n;
    }
    size_t idx = ((size_t)((b * NCH + ch) * DI + e)) * 16;
    float4* apo = (float4*)(aprod + idx);
    float4* bco = (float4*)(bacc + idx);
#pragma unroll
    for (int q = 0; q < 4; ++q) {
        apo[q] = make_float4(ap[q * 4], ap[q * 4 + 1], ap[q * 4 + 2], ap[q * 4 + 3]);
        bco[q] = make_float4(bc[q * 4], bc[q * 4 + 1], bc[q * 4 + 2], bc[q * 4 + 3]);
    }
}

// scan2: serial combine across NCH chunks -> h_init per chunk.
// NOTE: hinit aliases aprod (read-before-write per index) — no __restrict__.
__global__ __launch_bounds__(256) void scan2_kernel(
    const float* aprod, const float* bacc, float* hinit) {
    int tid = blockIdx.x * 256 + threadIdx.x;  // 32768 = (b,e,n)
    int n = tid & 15;
    int e = (tid >> 4) & (DI - 1);
    int b = tid >> 14;
    float h = 0.f;
    for (int ch = 0; ch < NCH; ++ch) {
        size_t idx = ((size_t)((b * NCH + ch) * DI + e)) * 16 + n;
        float a  = aprod[idx];
        float bb = bacc[idx];
        hinit[idx] = h;
        h = fmaf(a, h, bb);
    }
}

// scan3: re-run each chunk from h_init; fuse C-contraction + D-skip + gate.
__global__ __launch_bounds__(256) void scan3_kernel(
    const float* __restrict__ dbuf, const float* __restrict__ dxcb,
    const bf16_t* __restrict__ xcb, const bf16_t* __restrict__ zb,
    const float* __restrict__ bc_in, const float* __restrict__ A_log,
    const float* __restrict__ Dp, const float* __restrict__ hinit,
    bf16_t* __restrict__ yg) {
    int e  = blockIdx.x * 256 + threadIdx.x;
    int ch = blockIdx.y;
    int b  = blockIdx.z;
    float cAn[16];
#pragma unroll
    for (int n = 0; n < 16; ++n)
        cAn[n] = -expf(A_log[e * 16 + n]) * 1.4426950408889634f;
    float h[16];
    {
        const float4* hp = (const float4*)(hinit + ((size_t)((b * NCH + ch) * DI + e)) * 16);
#pragma unroll
        for (int q = 0; q < 4; ++q) {
            float4 v = hp[q];
            h[q * 4] = v.x; h[q * 4 + 1] = v.y; h[q * 4 + 2] = v.z; h[q * 4 + 3] = v.w;
        }
    }
    float Dpe = Dp[e];
    int row0 = b * LSEQ + ch * CHT;
    float d_c   = dbuf[(size_t)row0 * DI + e];
    float dxc_c = dxcb[(size_t)row0 * 1024 + e];
    float xc_c  = (float)xcb[(size_t)row0 * 1024 + e];
    float z_c   = (float)zb[(size_t)row0 * 1024 + e];
    for (int t = 0; t < CHT; ++t) {
        int row = row0 + t;
        float d_n = 0.f, dxc_n = 0.f, xc_n = 0.f, z_n = 0.f;
        if (t + 1 < CHT) {
            d_n   = dbuf[(size_t)(row + 1) * DI + e];
            dxc_n = dxcb[(size_t)(row + 1) * 1024 + e];
            xc_n  = (float)xcb[(size_t)(row + 1) * 1024 + e];
            z_n   = (float)zb[(size_t)(row + 1) * 1024 + e];
        }
        const float* brow = bc_in + (size_t)row * 32;  // block-uniform
        float Bn[16], Cn[16];
#pragma unroll
        for (int n = 0; n < 16; ++n) { Bn[n] = brow[n]; Cn[n] = brow[16 + n]; }
        float y = Dpe * xc_c;
#pragma unroll
        for (int n = 0; n < 16; ++n) {
            float dA = exp2f(d_c * cAn[n]);
            h[n] = fmaf(dA, h[n], dxc_c * Bn[n]);
            y = fmaf(h[n], Cn[n], y);
        }
        yg[(size_t)row * DI + e] = (bf16_t)(y * siluf(z_c));
        d_c = d_n; dxc_c = dxc_n; xc_c = xc_n; z_c = z_n;
    }
}

// ---------------- elementwise add ----------------
__global__ __launch_bounds__(256) void add_kernel(const float* __restrict__ a,
                                                  const float* __restrict__ b,
                                                  float* __restrict__ c, int n) {
    int i = blockIdx.x * blockDim.x + threadIdx.x;
    if (i < n) c[i] = a[i] + b[i];
}

extern "C" void kernel_launch(void* const* d_in, const int* in_sizes, int n_in,
                              void* d_out, int out_size, void* d_ws, size_t ws_size,
                              hipStream_t stream) {
    const float* x    = (const float*)d_in[0];
    const float* ipw  = (const float*)d_in[1];
    const float* cw   = (const float*)d_in[2];
    const float* cb   = (const float*)d_in[3];
    const float* xpw  = (const float*)d_in[4];
    const float* dtw  = (const float*)d_in[5];
    const float* dtb  = (const float*)d_in[6];
    const float* alog = (const float*)d_in[7];
    const float* dpar = (const float*)d_in[8];
    const float* opw  = (const float*)d_in[9];
    const float* rmsw = (const float*)d_in[10];
    const float* ln1w = (const float*)d_in[11];
    const float* ln1b = (const float*)d_in[12];
    const float* ln2w = (const float*)d_in[13];
    const float* ln2b = (const float*)d_in[14];
    const float* fw1  = (const float*)d_in[15];
    const float* fb1  = (const float*)d_in[16];
    const float* fw2  = (const float*)d_in[17];
    const float* fb2  = (const float*)d_in[18];
    const float* finw = (const float*)d_in[19];
    const float* finb = (const float*)d_in[20];
    float* out = (float*)d_out;

    const size_t MF = 1u << 20;
    float*  ws   = (float*)d_ws;
    float*  h    = ws;                                  // 2 MF fp32
    bf16_t* hnb  = (bf16_t*)(ws + 2 * MF);              // 2 MF bf16 (hn / ln2-out)
    float*  xdx  = ws + 3 * MF;                         // 4 MF fp32 (xraw -> dxc -> mid)
    bf16_t* zb   = (bf16_t*)(ws + 7 * MF);              // 4 MF bf16 (z -> x3b)
    bf16_t* xcb  = (bf16_t*)(ws + 9 * MF);              // 4 MF bf16
    float*  bcbuf = ws + 11 * MF;                       // 128K fp32 (slot 256K)
    float*  dbuf = ws + 11 * MF + MF / 4;               // 4 MF fp32 (-> x2)
    bf16_t* ygb  = (bf16_t*)(ws + 15 * MF + MF / 4);    // 4 MF bf16
    float*  aprod = ws + 17 * MF + MF / 4;              // 1 MF
    float*  bacc  = ws + 18 * MF + MF / 4;              // 1 MF
    bf16_t* warena = (bf16_t*)(ws + 19 * MF + MF / 4);  // 5.64M bf16
    float*  hinit = aprod;                              // alias (scan2 RAW-safe)
    // arena offsets (bf16 elements)
    const size_t IPW_OFF = 0, OPW_OFF = 2097152, FW1_OFF = 3145728,
                 FW2_OFF = 3670016, FINW_OFF = 4194304, WC_OFF = 4456448;

    // 0. weights -> bf16 arena (17408 blocks covers 4456448 elements)
    cvt_kernel<<<17408, 256, 0, stream>>>(ipw, opw, fw1, fw2, finw, warena);
    // 1. h = LN1(x)  (fp32)
    ln_kernel<false><<<ROWS, 256, 0, stream>>>(x, ln1w, ln1b, h);

    for (int i = 0; i < 2; ++i) {
        const bf16_t* ipwb_i = warena + IPW_OFF + (size_t)i * 2048 * 512;
        const bf16_t* opwb_i = warena + OPW_OFF + (size_t)i * 512 * 1024;
        bf16_t* wcombb = warena + WC_OFF;
        const float* cw_i   = cw   + (size_t)i * DI * 4;
        const float* cb_i   = cb   + (size_t)i * DI;
        const float* xpw_i  = xpw  + (size_t)i * 64 * DI;
        const float* dtw_i  = dtw  + (size_t)i * DI * 32;
        const float* dtb_i  = dtb  + (size_t)i * DI;
        const float* alog_i = alog + (size_t)i * DI * 16;
        const float* dp_i   = dpar + (size_t)i * DI;
        const float* rms_i  = rmsw + (size_t)i * DM;

        // hnb = RMS(h) bf16
        rms_kernel<<<ROWS, 256, 0, stream>>>(h, rms_i, hnb);
        // in_proj: cols<1024 -> xdx fp32 (conv input), cols>=1024 -> zb bf16
        mgemm_kernel<3, false, false, false><<<dim3(16, 32), 256, 0, stream>>>(
            hnb, ipwb_i, nullptr, nullptr, xdx, ROWS, 2048, 512, 1024,
            nullptr, nullptr, nullptr, zb);
        // xcb = silu(conv(xdx)) bf16
        conv_silu_kernel<<<ROWS * DI / 256, 256, 0, stream>>>(xdx, cw_i, cb_i, xcb);
        // wcombb = [dtw @ xpw[:32] ; xpw[32:64] ; 0]  bf16
        wd_kernel<<<NCOMB * 1024 / 256, 256, 0, stream>>>(dtw_i, xpw_i, wcombb);
        // combined: d=softplus(.)->dbuf; dxc=d*xc->xdx; B/C->bcbuf
        mgemm_kernel<2, false, false, false><<<dim3(NCOMB / 128, 32), 256, 0, stream>>>(
            xcb, wcombb, dtb_i, nullptr, dbuf, ROWS, NCOMB, 1024, 1024,
            xcb, xdx, bcbuf, nullptr);
        // chunked parallel scan
        scan1_kernel<<<dim3(4, NCH, 2), 256, 0, stream>>>(dbuf, xdx, bcbuf, alog_i,
                                                          aprod, bacc);
        scan2_kernel<<<128, 256, 0, stream>>>(aprod, bacc, hinit);
        scan3_kernel<<<dim3(4, NCH, 2), 256, 0, stream>>>(dbuf, xdx, xcb, zb, bcbuf,
                                                          alog_i, dp_i, hinit, ygb);
        // h = h + ygb @ opw^T
        mgemm_kernel<0, false, true, false><<<dim3(4, 32), 256, 0, stream>>>(
            ygb, opwb_i, nullptr, h, h, ROWS, DM, 1024, DM,
            nullptr, nullptr, nullptr, nullptr);
    }

    // x2 = x + h  (fp32, in dbuf slot)
    float* x2 = dbuf;
    add_kernel<<<ROWS * DM / 256, 256, 0, stream>>>(x, h, x2, ROWS * DM);
    // hnb = LN2(x2) bf16
    ln_kernel<true><<<ROWS, 256, 0, stream>>>(x2, ln2w, ln2b, hnb);
    // mid = relu(hnb @ fw1^T + fb1) bf16 (in xdx slot)
    bf16_t* midb = (bf16_t*)xdx;
    mgemm_kernel<1, true, false, true><<<dim3(8, 32), 256, 0, stream>>>(
        hnb, warena + FW1_OFF, fb1, nullptr, midb, ROWS, DI, 512, DI,
        nullptr, nullptr, nullptr, nullptr);
    // x3 = x2 + mid @ fw2^T + fb2  bf16 (in zb slot)
    bf16_t* x3b = zb;
    mgemm_kernel<0, true, true, true><<<dim3(4, 32), 256, 0, stream>>>(
        midb, warena + FW2_OFF, fb2, x2, x3b, ROWS, DM, 1024, DM,
        nullptr, nullptr, nullptr, nullptr);
    // out = x3 @ finw^T + finb  fp32
    mgemm_kernel<0, true, false, false><<<dim3(4, 32), 256, 0, stream>>>(
        x3b, warena + FINW_OFF, finb, nullptr, out, ROWS, DM, 512, DM,
        nullptr, nullptr, nullptr, nullptr);
}

// Round 9
// 568.711 us; speedup vs baseline: 9.4454x; 1.2306x over previous
//
#include <hip/hip_runtime.h>
#include <math.h>

#define ROWS 4096   // B * L
#define LSEQ 2048
#define DM   512
#define DI   1024
#define NCH  64            // scan chunks per sequence
#define CHT  (LSEQ / NCH)  // 32 timesteps per chunk
#define NCOMB 1152         // combined x_proj/dt GEMM N (1024 delta + 32 B/C + 96 pad)

typedef __bf16 bf16_t;
typedef bf16_t bf16x8 __attribute__((ext_vector_type(8)));
typedef float f32x4 __attribute__((ext_vector_type(4)));
typedef unsigned int u32;
typedef const __attribute__((address_space(1))) u32* gp32;
typedef __attribute__((address_space(3))) u32* lp32;

__device__ __forceinline__ float siluf(float v) { return v / (1.f + expf(-v)); }
__device__ __forceinline__ float softplusf(float v) {
    return fmaxf(v, 0.f) + log1pf(expf(-fabsf(v)));
}

// ---------------- LayerNorm: one block per row of 512 ----------------
template <bool OUTBF>
__global__ __launch_bounds__(256) void ln_kernel(const float* __restrict__ x,
                                                 const float* __restrict__ w,
                                                 const float* __restrict__ b,
                                                 void* __restrict__ outv) {
    int row = blockIdx.x;
    int tid = threadIdx.x;
    const float* xr = x + (size_t)row * DM;
    float v0 = xr[tid], v1 = xr[tid + 256];
    float sum = v0 + v1, sq = v0 * v0 + v1 * v1;
    for (int o = 32; o > 0; o >>= 1) {
        sum += __shfl_down(sum, o);
        sq  += __shfl_down(sq, o);
    }
    __shared__ float s1[4], s2[4];
    int wid = tid >> 6, lane = tid & 63;
    if (lane == 0) { s1[wid] = sum; s2[wid] = sq; }
    __syncthreads();
    sum = s1[0] + s1[1] + s1[2] + s1[3];
    sq  = s2[0] + s2[1] + s2[2] + s2[3];
    float mu  = sum * (1.f / DM);
    float var = sq * (1.f / DM) - mu * mu;
    float r   = rsqrtf(var + 1e-5f);
    float o0 = (v0 - mu) * r * w[tid] + b[tid];
    float o1 = (v1 - mu) * r * w[tid + 256] + b[tid + 256];
    if (OUTBF) {
        bf16_t* out = (bf16_t*)outv;
        out[(size_t)row * DM + tid]       = (bf16_t)o0;
        out[(size_t)row * DM + tid + 256] = (bf16_t)o1;
    } else {
        float* out = (float*)outv;
        out[(size_t)row * DM + tid]       = o0;
        out[(size_t)row * DM + tid + 256] = o1;
    }
}

// ---------------- RMSNorm: one block per row of 512, bf16 out -------------
__global__ __launch_bounds__(256) void rms_kernel(const float* __restrict__ x,
                                                  const float* __restrict__ w,
                                                  bf16_t* __restrict__ out) {
    int row = blockIdx.x;
    int tid = threadIdx.x;
    const float* xr = x + (size_t)row * DM;
    float v0 = xr[tid], v1 = xr[tid + 256];
    float sq = v0 * v0 + v1 * v1;
    for (int o = 32; o > 0; o >>= 1) sq += __shfl_down(sq, o);
    __shared__ float s2[4];
    int wid = tid >> 6, lane = tid & 63;
    if (lane == 0) s2[wid] = sq;
    __syncthreads();
    sq = s2[0] + s2[1] + s2[2] + s2[3];
    float r = rsqrtf(sq * (1.f / DM) + 1e-5f);
    out[(size_t)row * DM + tid]       = (bf16_t)(v0 * r * w[tid]);
    out[(size_t)row * DM + tid + 256] = (bf16_t)(v1 * r * w[tid + 256]);
}

// ---------------- weight f32 -> bf16 arena converter ----------------------
__global__ __launch_bounds__(256) void cvt_kernel(
    const float* __restrict__ ipw, const float* __restrict__ opw,
    const float* __restrict__ fw1, const float* __restrict__ fw2,
    const float* __restrict__ finw, bf16_t* __restrict__ arena) {
    int idx = blockIdx.x * 256 + threadIdx.x;
    float v;
    if (idx < 2097152)      v = ipw[idx];
    else if (idx < 3145728) v = opw[idx - 2097152];
    else if (idx < 3670016) v = fw1[idx - 3145728];
    else if (idx < 4194304) v = fw2[idx - 3670016];
    else                    v = finw[idx - 4194304];
    arena[idx] = (bf16_t)v;
}

// ---------------- Wcomb builder (bf16 out) --------------------------------
// rows 0-1023 = dtw @ xpw[:32]; rows 1024-1055 = xpw[32:64]; rest 0.
__global__ __launch_bounds__(256) void wd_kernel(
    const float* __restrict__ dtw, const float* __restrict__ xpw,
    bf16_t* __restrict__ wcomb) {
    int idx = blockIdx.x * 256 + threadIdx.x;  // NCOMB*1024
    int j = idx & 1023;
    int i = idx >> 10;
    float v;
    if (i < 1024) {
        const float* dr = dtw + i * 32;
        v = 0.f;
#pragma unroll
        for (int k = 0; k < 32; ++k) v = fmaf(dr[k], xpw[k * 1024 + j], v);
    } else if (i < 1056) {
        v = xpw[(i - 1024 + 32) * 1024 + j];
    } else {
        v = 0.f;
    }
    wcomb[idx] = (bf16_t)v;
}

// ---------------- bf16 MFMA GEMM: C = A @ W^T -----------------------------
// A:(M,K) bf16, W:(N,K) bf16. BK=64, 128x128 tile, 4 waves (2x2) of 64x64.
// global_load_lds(16B) direct staging; XOR swizzle piece^=(row&7) applied to
// BOTH the global source (inverse) and the ds_read (rule #21) -> conflict-free.
// ACT: 0 none, 1 relu, 2 comb-mamba epilogue, 3 in_proj split epilogue.
template <int ACT, bool BIAS, bool RES, bool OUTBF>
__global__ __launch_bounds__(256) void mgemm_kernel(
    const bf16_t* __restrict__ A, const bf16_t* __restrict__ W,
    const float* __restrict__ bias, const float* __restrict__ res,
    void* __restrict__ Cv, int M, int N, int K, int ldc,
    const bf16_t* __restrict__ xcp, float* __restrict__ dxc,
    float* __restrict__ bcb, void* __restrict__ aux) {
    __shared__ bf16_t As[128 * 64];
    __shared__ bf16_t Bs[128 * 64];
    const int tid  = threadIdx.x;
    const int lane = tid & 63;
    const int wave = tid >> 6;
    const int wr = wave >> 1, wc = wave & 1;
    const int bm = blockIdx.y * 128, bn = blockIdx.x * 128;
    const int l16 = lane & 15, kgrp = lane >> 4;
    const int prow = tid >> 3;      // staging row (0..31) per iteration
    const int pp   = tid & 7;       // staging 16B piece within 128B row
    const int wbase = (tid & ~63) * 8;  // wave-uniform LDS bf16 offset

    f32x4 acc[4][4] = {};

    for (int k0 = 0; k0 < K; k0 += 64) {
        __syncthreads();
#pragma unroll
        for (int it = 0; it < 4; ++it) {
            int r  = it * 32 + prow;
            int gc = k0 + ((pp ^ (r & 7)) << 3);  // inverse-swizzled source col
            const bf16_t* ga = A + (size_t)(bm + r) * K + gc;
            const bf16_t* gb = W + (size_t)(bn + r) * K + gc;
            __builtin_amdgcn_global_load_lds((gp32)(const void*)ga,
                (lp32)(void*)(As + it * 2048 + wbase), 16, 0, 0);
            __builtin_amdgcn_global_load_lds((gp32)(const void*)gb,
                (lp32)(void*)(Bs + it * 2048 + wbase), 16, 0, 0);
        }
        __syncthreads();
#pragma unroll
        for (int ks = 0; ks < 2; ++ks) {
            bf16x8 af[4], bv[4];
#pragma unroll
            for (int i = 0; i < 4; ++i) {
                int ra = wr * 64 + i * 16 + l16;
                int rb = wc * 64 + i * 16 + l16;
                af[i] = *(const bf16x8*)(As + ra * 64 + ((((ks << 2) | kgrp) ^ (ra & 7)) << 3));
                bv[i] = *(const bf16x8*)(Bs + rb * 64 + ((((ks << 2) | kgrp) ^ (rb & 7)) << 3));
            }
#pragma unroll
            for (int i = 0; i < 4; ++i)
#pragma unroll
                for (int j = 0; j < 4; ++j)
                    acc[i][j] = __builtin_amdgcn_mfma_f32_16x16x32_bf16(
                        af[i], bv[j], acc[i][j], 0, 0, 0);
        }
    }
    // epilogue: C/D layout col=lane&15, row=(lane>>4)*4+q  [m89/m91 verified]
#pragma unroll
    for (int i = 0; i < 4; ++i) {
#pragma unroll
        for (int j = 0; j < 4; ++j) {
            int col = bn + wc * 64 + j * 16 + l16;
            if (ACT == 2) {
                if (col < 1024) {
                    float badd = bias[col];
#pragma unroll
                    for (int q = 0; q < 4; ++q) {
                        int row = bm + wr * 64 + i * 16 + kgrp * 4 + q;
                        float d = softplusf(acc[i][j][q] + badd);
                        ((float*)Cv)[(size_t)row * 1024 + col] = d;
                        dxc[(size_t)row * 1024 + col] =
                            d * (float)xcp[(size_t)row * 1024 + col];
                    }
                } else if (col < 1056) {
#pragma unroll
                    for (int q = 0; q < 4; ++q) {
                        int row = bm + wr * 64 + i * 16 + kgrp * 4 + q;
                        bcb[(size_t)row * 32 + (col - 1024)] = acc[i][j][q];
                    }
                }
            } else if (ACT == 3) {
#pragma unroll
                for (int q = 0; q < 4; ++q) {
                    int row = bm + wr * 64 + i * 16 + kgrp * 4 + q;
                    float v = acc[i][j][q];
                    if (col < 1024)
                        ((float*)Cv)[(size_t)row * 1024 + col] = v;
                    else
                        ((bf16_t*)aux)[(size_t)row * 1024 + (col - 1024)] = (bf16_t)v;
                }
            } else {
                float badd = BIAS ? bias[col] : 0.f;
#pragma unroll
                for (int q = 0; q < 4; ++q) {
                    int row = bm + wr * 64 + i * 16 + kgrp * 4 + q;
                    float v = acc[i][j][q] + badd;
                    if (RES) v += res[(size_t)row * ldc + col];
                    if (ACT == 1) v = fmaxf(v, 0.f);
                    if (OUTBF) ((bf16_t*)Cv)[(size_t)row * ldc + col] = (bf16_t)v;
                    else       ((float*)Cv)[(size_t)row * ldc + col] = v;
                }
            }
        }
    }
}

// ---------------- causal depthwise conv (D_CONV=4) + SiLU -> bf16 ---------
__global__ __launch_bounds__(256) void conv_silu_kernel(
    const float* __restrict__ xraw, const float* __restrict__ cw,
    const float* __restrict__ cb, bf16_t* __restrict__ out) {
    int idx = blockIdx.x * blockDim.x + threadIdx.x;  // ROWS*DI
    int c = idx & (DI - 1);
    int row = idx >> 10;
    int t = row & (LSEQ - 1);
    float acc = cb[c];
#pragma unroll
    for (int k = 0; k < 4; ++k) {
        int st = t + k - 3;
        if (st >= 0) acc = fmaf(cw[c * 4 + k], xraw[(size_t)(row + k - 3) * 1024 + c], acc);
    }
    out[idx] = (bf16_t)siluf(acc);
}

// ---------------- chunked parallel scan, half-split register version ------
// Thread owns 8 of 16 n-states for one e. gid = blockIdx.x*256+tid (0..2047
// per (ch,b)); e = gid>>1, half = gid&1. grid (8, NCH, 2).
__global__ __launch_bounds__(256) void scan1_kernel(
    const float* __restrict__ dbuf, const float* __restrict__ dxcb,
    const float* __restrict__ bc_in, const float* __restrict__ A_log,
    float* __restrict__ aprod, float* __restrict__ bacc) {
    int gid  = blockIdx.x * 256 + threadIdx.x;
    int e    = gid >> 1;
    int half = gid & 1;
    int ch = blockIdx.y;
    int b  = blockIdx.z;
    float cAn[8];
#pragma unroll
    for (int n = 0; n < 8; ++n)
        cAn[n] = -expf(A_log[e * 16 + half * 8 + n]) * 1.4426950408889634f;
    float ap[8], bc[8];
#pragma unroll
    for (int n = 0; n < 8; ++n) { ap[n] = 1.f; bc[n] = 0.f; }
    int row0 = b * LSEQ + ch * CHT;
    float d_c   = dbuf[(size_t)row0 * DI + e];
    float dxc_c = dxcb[(size_t)row0 * 1024 + e];
    for (int t = 0; t < CHT; ++t) {
        int row = row0 + t;
        float d_n = 0.f, dxc_n = 0.f;
        if (t + 1 < CHT) {
            d_n   = dbuf[(size_t)(row + 1) * DI + e];
            dxc_n = dxcb[(size_t)(row + 1) * 1024 + e];
        }
        const float* brow = bc_in + (size_t)row * 32 + half * 8;
        float4 b0 = *(const float4*)brow;
        float4 b1 = *(const float4*)(brow + 4);
        float Bn[8] = {b0.x, b0.y, b0.z, b0.w, b1.x, b1.y, b1.z, b1.w};
#pragma unroll
        for (int n = 0; n < 8; ++n) {
            float dA = exp2f(d_c * cAn[n]);
            ap[n] *= dA;
            bc[n] = fmaf(dA, bc[n], dxc_c * Bn[n]);
        }
        d_c = d_n; dxc_c = dxc_n;
    }
    size_t idx = ((size_t)((b * NCH + ch) * DI + e)) * 16 + half * 8;
    float4* apo = (float4*)(aprod + idx);
    float4* bco = (float4*)(bacc + idx);
#pragma unroll
    for (int q = 0; q < 2; ++q) {
        apo[q] = make_float4(ap[q * 4], ap[q * 4 + 1], ap[q * 4 + 2], ap[q * 4 + 3]);
        bco[q] = make_float4(bc[q * 4], bc[q * 4 + 1], bc[q * 4 + 2], bc[q * 4 + 3]);
    }
}

// scan2: serial combine across NCH chunks -> h_init per chunk.
// NOTE: hinit aliases aprod (read-before-write per index) — no __restrict__.
__global__ __launch_bounds__(256) void scan2_kernel(
    const float* aprod, const float* bacc, float* hinit) {
    int tid = blockIdx.x * 256 + threadIdx.x;  // 32768 = (b,e,n)
    int n = tid & 15;
    int e = (tid >> 4) & (DI - 1);
    int b = tid >> 14;
    float h = 0.f;
    for (int ch = 0; ch < NCH; ++ch) {
        size_t idx = ((size_t)((b * NCH + ch) * DI + e)) * 16 + n;
        float a  = aprod[idx];
        float bb = bacc[idx];
        hinit[idx] = h;
        h = fmaf(a, h, bb);
    }
}

// scan3: re-run each chunk from h_init; fuse C-contraction + D-skip + gate.
// Same half-split mapping as scan1; y-reduction via one shfl_xor(1).
__global__ __launch_bounds__(256) void scan3_kernel(
    const float* __restrict__ dbuf, const float* __restrict__ dxcb,
    const bf16_t* __restrict__ xcb, const bf16_t* __restrict__ zb,
    const float* __restrict__ bc_in, const float* __restrict__ A_log,
    const float* __restrict__ Dp, const float* __restrict__ hinit,
    bf16_t* __restrict__ yg) {
    int gid  = blockIdx.x * 256 + threadIdx.x;
    int e    = gid >> 1;
    int half = gid & 1;
    int ch = blockIdx.y;
    int b  = blockIdx.z;
    float cAn[8];
#pragma unroll
    for (int n = 0; n < 8; ++n)
        cAn[n] = -expf(A_log[e * 16 + half * 8 + n]) * 1.4426950408889634f;
    float h[8];
    {
        const float4* hp = (const float4*)(hinit +
            ((size_t)((b * NCH + ch) * DI + e)) * 16 + half * 8);
#pragma unroll
        for (int q = 0; q < 2; ++q) {
            float4 v = hp[q];
            h[q * 4] = v.x; h[q * 4 + 1] = v.y; h[q * 4 + 2] = v.z; h[q * 4 + 3] = v.w;
        }
    }
    float Dpe = Dp[e];
    int row0 = b * LSEQ + ch * CHT;
    float d_c   = dbuf[(size_t)row0 * DI + e];
    float dxc_c = dxcb[(size_t)row0 * 1024 + e];
    float xc_c  = (float)xcb[(size_t)row0 * 1024 + e];
    float z_c   = (float)zb[(size_t)row0 * 1024 + e];
    for (int t = 0; t < CHT; ++t) {
        int row = row0 + t;
        float d_n = 0.f, dxc_n = 0.f, xc_n = 0.f, z_n = 0.f;
        if (t + 1 < CHT) {
            d_n   = dbuf[(size_t)(row + 1) * DI + e];
            dxc_n = dxcb[(size_t)(row + 1) * 1024 + e];
            xc_n  = (float)xcb[(size_t)(row + 1) * 1024 + e];
            z_n   = (float)zb[(size_t)(row + 1) * 1024 + e];
        }
        const float* brow = bc_in + (size_t)row * 32;
        float4 b0 = *(const float4*)(brow + half * 8);
        float4 b1 = *(const float4*)(brow + half * 8 + 4);
        float4 c0 = *(const float4*)(brow + 16 + half * 8);
        float4 c1 = *(const float4*)(brow + 16 + half * 8 + 4);
        float Bn[8] = {b0.x, b0.y, b0.z, b0.w, b1.x, b1.y, b1.z, b1.w};
        float Cn[8] = {c0.x, c0.y, c0.z, c0.w, c1.x, c1.y, c1.z, c1.w};
        float y = half ? 0.f : Dpe * xc_c;
#pragma unroll
        for (int n = 0; n < 8; ++n) {
            float dA = exp2f(d_c * cAn[n]);
            h[n] = fmaf(dA, h[n], dxc_c * Bn[n]);
            y = fmaf(h[n], Cn[n], y);
        }
        y += __shfl_xor(y, 1);
        if (half == 0)
            yg[(size_t)row * DI + e] = (bf16_t)(y * siluf(z_c));
        d_c = d_n; dxc_c = dxc_n; xc_c = xc_n; z_c = z_n;
    }
}

// ---------------- elementwise add ----------------
__global__ __launch_bounds__(256) void add_kernel(const float* __restrict__ a,
                                                  const float* __restrict__ b,
                                                  float* __restrict__ c, int n) {
    int i = blockIdx.x * blockDim.x + threadIdx.x;
    if (i < n) c[i] = a[i] + b[i];
}

extern "C" void kernel_launch(void* const* d_in, const int* in_sizes, int n_in,
                              void* d_out, int out_size, void* d_ws, size_t ws_size,
                              hipStream_t stream) {
    const float* x    = (const float*)d_in[0];
    const float* ipw  = (const float*)d_in[1];
    const float* cw   = (const float*)d_in[2];
    const float* cb   = (const float*)d_in[3];
    const float* xpw  = (const float*)d_in[4];
    const float* dtw  = (const float*)d_in[5];
    const float* dtb  = (const float*)d_in[6];
    const float* alog = (const float*)d_in[7];
    const float* dpar = (const float*)d_in[8];
    const float* opw  = (const float*)d_in[9];
    const float* rmsw = (const float*)d_in[10];
    const float* ln1w = (const float*)d_in[11];
    const float* ln1b = (const float*)d_in[12];
    const float* ln2w = (const float*)d_in[13];
    const float* ln2b = (const float*)d_in[14];
    const float* fw1  = (const float*)d_in[15];
    const float* fb1  = (const float*)d_in[16];
    const float* fw2  = (const float*)d_in[17];
    const float* fb2  = (const float*)d_in[18];
    const float* finw = (const float*)d_in[19];
    const float* finb = (const float*)d_in[20];
    float* out = (float*)d_out;

    const size_t MF = 1u << 20;
    float*  ws    = (float*)d_ws;
    float*  h     = ws;                                  // 2 MF fp32
    bf16_t* hnb   = (bf16_t*)(ws + 2 * MF);              // 1 MF slot (2M bf16)
    float*  xdx   = ws + 3 * MF;                         // 4 MF (xraw -> dxc; later midb)
    bf16_t* zb    = (bf16_t*)(ws + 7 * MF);              // 2 MF slot (4M bf16; later x3b)
    bf16_t* xcb   = (bf16_t*)(ws + 9 * MF);              // 2 MF slot (4M bf16)
    float*  bcbuf = ws + 11 * MF;                        // 0.125 MF (ROWS*32)
    float*  dbuf  = ws + 11 * MF + MF / 8;               // 4 MF (d; later x2)
    float*  shab  = ws + 15 * MF + MF / 8;               // 2 MF shared: bacc / ygb
    float*  aprod = ws + 17 * MF + MF / 8;               // 2 MF (hinit aliases)
    bf16_t* warena = (bf16_t*)(ws + 19 * MF + MF / 8);   // 6.82M bf16 (3.25 MF)
    float*  bacc  = shab;
    bf16_t* ygb   = (bf16_t*)shab;
    float*  hinit = aprod;                               // alias (scan2 RAW-safe)
    // arena offsets (bf16 elements)
    const size_t IPW_OFF = 0, OPW_OFF = 2097152, FW1_OFF = 3145728,
                 FW2_OFF = 3670016, FINW_OFF = 4194304, WC_OFF = 4456448;

    // 0. weights -> bf16 arena; both layers' Wcomb (weights-only, hoisted)
    cvt_kernel<<<17408, 256, 0, stream>>>(ipw, opw, fw1, fw2, finw, warena);
    for (int i = 0; i < 2; ++i)
        wd_kernel<<<NCOMB * 1024 / 256, 256, 0, stream>>>(
            dtw + (size_t)i * DI * 32, xpw + (size_t)i * 64 * DI,
            warena + WC_OFF + (size_t)i * NCOMB * 1024);
    // 1. h = LN1(x)  (fp32)
    ln_kernel<false><<<ROWS, 256, 0, stream>>>(x, ln1w, ln1b, h);

    for (int i = 0; i < 2; ++i) {
        const bf16_t* ipwb_i = warena + IPW_OFF + (size_t)i * 2048 * 512;
        const bf16_t* opwb_i = warena + OPW_OFF + (size_t)i * 512 * 1024;
        const bf16_t* wcombb = warena + WC_OFF + (size_t)i * NCOMB * 1024;
        const float* cw_i   = cw   + (size_t)i * DI * 4;
        const float* cb_i   = cb   + (size_t)i * DI;
        const float* dtb_i  = dtb  + (size_t)i * DI;
        const float* alog_i = alog + (size_t)i * DI * 16;
        const float* dp_i   = dpar + (size_t)i * DI;
        const float* rms_i  = rmsw + (size_t)i * DM;

        // hnb = RMS(h) bf16
        rms_kernel<<<ROWS, 256, 0, stream>>>(h, rms_i, hnb);
        // in_proj: cols<1024 -> xdx fp32 (conv input), cols>=1024 -> zb bf16
        mgemm_kernel<3, false, false, false><<<dim3(16, 32), 256, 0, stream>>>(
            hnb, ipwb_i, nullptr, nullptr, xdx, ROWS, 2048, 512, 1024,
            nullptr, nullptr, nullptr, zb);
        // xcb = silu(conv(xdx)) bf16
        conv_silu_kernel<<<ROWS * DI / 256, 256, 0, stream>>>(xdx, cw_i, cb_i, xcb);
        // combined: d=softplus(.)->dbuf; dxc=d*xc->xdx; B/C->bcbuf
        mgemm_kernel<2, false, false, false><<<dim3(NCOMB / 128, 32), 256, 0, stream>>>(
            xcb, wcombb, dtb_i, nullptr, dbuf, ROWS, NCOMB, 1024, 1024,
            xcb, xdx, bcbuf, nullptr);
        // chunked parallel scan
        scan1_kernel<<<dim3(8, NCH, 2), 256, 0, stream>>>(dbuf, xdx, bcbuf, alog_i,
                                                          aprod, bacc);
        scan2_kernel<<<128, 256, 0, stream>>>(aprod, bacc, hinit);
        scan3_kernel<<<dim3(8, NCH, 2), 256, 0, stream>>>(dbuf, xdx, xcb, zb, bcbuf,
                                                          alog_i, dp_i, hinit, ygb);
        // h = h + ygb @ opw^T
        mgemm_kernel<0, false, true, false><<<dim3(4, 32), 256, 0, stream>>>(
            ygb, opwb_i, nullptr, h, h, ROWS, DM, 1024, DM,
            nullptr, nullptr, nullptr, nullptr);
    }

    // x2 = x + h  (fp32, in dbuf slot)
    float* x2 = dbuf;
    add_kernel<<<ROWS * DM / 256, 256, 0, stream>>>(x, h, x2, ROWS * DM);
    // hnb = LN2(x2) bf16
    ln_kernel<true><<<ROWS, 256, 0, stream>>>(x2, ln2w, ln2b, hnb);
    // mid = relu(hnb @ fw1^T + fb1) bf16 (in xdx slot)
    bf16_t* midb = (bf16_t*)xdx;
    mgemm_kernel<1, true, false, true><<<dim3(8, 32), 256, 0, stream>>>(
        hnb, warena + FW1_OFF, fb1, nullptr, midb, ROWS, DI, 512, DI,
        nullptr, nullptr, nullptr, nullptr);
    // x3 = x2 + mid @ fw2^T + fb2  bf16 (in zb slot)
    bf16_t* x3b = zb;
    mgemm_kernel<0, true, true, true><<<dim3(4, 32), 256, 0, stream>>>(
        midb, warena + FW2_OFF, fb2, x2, x3b, ROWS, DM, 1024, DM,
        nullptr, nullptr, nullptr, nullptr);
    // out = x3 @ finw^T + finb  fp32
    mgemm_kernel<0, true, false, false><<<dim3(4, 32), 256, 0, stream>>>(
        x3b, warena + FINW_OFF, finb, nullptr, out, ROWS, DM, 512, DM,
        nullptr, nullptr, nullptr, nullptr);
}

// Round 11
// 512.100 us; speedup vs baseline: 10.4896x; 1.1105x over previous
//
#include <hip/hip_runtime.h>
#include <math.h>

#define ROWS 4096   // B * L
#define LSEQ 2048
#define DM   512
#define DI   1024
#define NCH  64            // scan chunks per sequence
#define CHT  (LSEQ / NCH)  // 32 timesteps per chunk
#define NCOMB 1152         // combined x_proj/dt GEMM N (1024 delta + 32 B/C + 96 pad)

typedef __bf16 bf16_t;
typedef bf16_t bf16x8 __attribute__((ext_vector_type(8)));
typedef float f32x4 __attribute__((ext_vector_type(4)));
typedef unsigned int u32;
typedef const __attribute__((address_space(1))) u32* gp32;
typedef __attribute__((address_space(3))) u32* lp32;

__device__ __forceinline__ float siluf(float v) { return v / (1.f + expf(-v)); }
__device__ __forceinline__ float softplusf(float v) {
    return fmaxf(v, 0.f) + log1pf(expf(-fabsf(v)));
}

// ---------------- LN1: one block per row of 512, fp32 out ----------------
__global__ __launch_bounds__(256) void ln_kernel(const float* __restrict__ x,
                                                 const float* __restrict__ w,
                                                 const float* __restrict__ b,
                                                 float* __restrict__ out) {
    int row = blockIdx.x;
    int tid = threadIdx.x;
    const float* xr = x + (size_t)row * DM;
    float v0 = xr[tid], v1 = xr[tid + 256];
    float sum = v0 + v1, sq = v0 * v0 + v1 * v1;
    for (int o = 32; o > 0; o >>= 1) {
        sum += __shfl_down(sum, o);
        sq  += __shfl_down(sq, o);
    }
    __shared__ float s1[4], s2[4];
    int wid = tid >> 6, lane = tid & 63;
    if (lane == 0) { s1[wid] = sum; s2[wid] = sq; }
    __syncthreads();
    sum = s1[0] + s1[1] + s1[2] + s1[3];
    sq  = s2[0] + s2[1] + s2[2] + s2[3];
    float mu  = sum * (1.f / DM);
    float var = sq * (1.f / DM) - mu * mu;
    float r   = rsqrtf(var + 1e-5f);
    out[(size_t)row * DM + tid]       = (v0 - mu) * r * w[tid] + b[tid];
    out[(size_t)row * DM + tid + 256] = (v1 - mu) * r * w[tid + 256] + b[tid + 256];
}

// ---------------- LN2 fused with residual add: x2 = x + h; outb = LN(x2) --
__global__ __launch_bounds__(256) void ln_add_kernel(
    const float* __restrict__ x, const float* __restrict__ hres,
    const float* __restrict__ w, const float* __restrict__ b,
    float* __restrict__ x2, bf16_t* __restrict__ outb) {
    int row = blockIdx.x;
    int tid = threadIdx.x;
    size_t base = (size_t)row * DM;
    float v0 = x[base + tid] + hres[base + tid];
    float v1 = x[base + tid + 256] + hres[base + tid + 256];
    x2[base + tid] = v0;
    x2[base + tid + 256] = v1;
    float sum = v0 + v1, sq = v0 * v0 + v1 * v1;
    for (int o = 32; o > 0; o >>= 1) {
        sum += __shfl_down(sum, o);
        sq  += __shfl_down(sq, o);
    }
    __shared__ float s1[4], s2[4];
    int wid = tid >> 6, lane = tid & 63;
    if (lane == 0) { s1[wid] = sum; s2[wid] = sq; }
    __syncthreads();
    sum = s1[0] + s1[1] + s1[2] + s1[3];
    sq  = s2[0] + s2[1] + s2[2] + s2[3];
    float mu  = sum * (1.f / DM);
    float var = sq * (1.f / DM) - mu * mu;
    float r   = rsqrtf(var + 1e-5f);
    outb[base + tid]       = (bf16_t)((v0 - mu) * r * w[tid] + b[tid]);
    outb[base + tid + 256] = (bf16_t)((v1 - mu) * r * w[tid + 256] + b[tid + 256]);
}

// ---------------- RMSNorm: one block per row of 512, bf16 out -------------
__global__ __launch_bounds__(256) void rms_kernel(const float* __restrict__ x,
                                                  const float* __restrict__ w,
                                                  bf16_t* __restrict__ out) {
    int row = blockIdx.x;
    int tid = threadIdx.x;
    const float* xr = x + (size_t)row * DM;
    float v0 = xr[tid], v1 = xr[tid + 256];
    float sq = v0 * v0 + v1 * v1;
    for (int o = 32; o > 0; o >>= 1) sq += __shfl_down(sq, o);
    __shared__ float s2[4];
    int wid = tid >> 6, lane = tid & 63;
    if (lane == 0) s2[wid] = sq;
    __syncthreads();
    sq = s2[0] + s2[1] + s2[2] + s2[3];
    float r = rsqrtf(sq * (1.f / DM) + 1e-5f);
    out[(size_t)row * DM + tid]       = (bf16_t)(v0 * r * w[tid]);
    out[(size_t)row * DM + tid + 256] = (bf16_t)(v1 * r * w[tid + 256]);
}

// ---------------- weight f32 -> bf16 arena converter ----------------------
__global__ __launch_bounds__(256) void cvt_kernel(
    const float* __restrict__ ipw, const float* __restrict__ opw,
    const float* __restrict__ fw1, const float* __restrict__ fw2,
    const float* __restrict__ finw, bf16_t* __restrict__ arena) {
    int idx = blockIdx.x * 256 + threadIdx.x;
    float v;
    if (idx < 2097152)      v = ipw[idx];
    else if (idx < 3145728) v = opw[idx - 2097152];
    else if (idx < 3670016) v = fw1[idx - 3145728];
    else if (idx < 4194304) v = fw2[idx - 3670016];
    else                    v = finw[idx - 4194304];
    arena[idx] = (bf16_t)v;
}

// ---------------- Wcomb builder (bf16 out) --------------------------------
__global__ __launch_bounds__(256) void wd_kernel(
    const float* __restrict__ dtw, const float* __restrict__ xpw,
    bf16_t* __restrict__ wcomb) {
    int idx = blockIdx.x * 256 + threadIdx.x;  // NCOMB*1024
    int j = idx & 1023;
    int i = idx >> 10;
    float v;
    if (i < 1024) {
        const float* dr = dtw + i * 32;
        v = 0.f;
#pragma unroll
        for (int k = 0; k < 32; ++k) v = fmaf(dr[k], xpw[k * 1024 + j], v);
    } else if (i < 1056) {
        v = xpw[(i - 1024 + 32) * 1024 + j];
    } else {
        v = 0.f;
    }
    wcomb[idx] = (bf16_t)v;
}

// ---------------- bf16 MFMA GEMM: C = A @ W^T -----------------------------
// BM = BMF*32 x 128 tile, 4 waves (2x2), each wave (BM/2)x64, BK=64.
// 1D grid with XCD-chunked swizzle (gridDim.x % 8 == 0); id -> (bm, bn) with
// bn fastest so each XCD chunk shares A-panels (L2 locality).
// global_load_lds(16B) staging; XOR swizzle (row&7) on source+read (rule 21).
// ACT: 0 none, 1 relu, 2 comb-mamba epilogue, 3 in_proj split epilogue.
template <int BMF, int ACT, bool BIAS, bool RES, bool OUTBF>
__global__ __launch_bounds__(256) void mgemm_kernel(
    const bf16_t* __restrict__ A, const bf16_t* __restrict__ W,
    const float* __restrict__ bias, const float* __restrict__ res,
    void* __restrict__ Cv, int nbn, int K, int ldc,
    const bf16_t* __restrict__ xcp, bf16_t* __restrict__ dxc,
    float* __restrict__ bcb, void* __restrict__ aux) {
    constexpr int BM = BMF * 32;
    __shared__ bf16_t As[BM * 64];
    __shared__ bf16_t Bs[128 * 64];
    const int tid  = threadIdx.x;
    const int lane = tid & 63;
    const int wave = tid >> 6;
    const int wr = wave >> 1, wc = wave & 1;
    const int l16 = lane & 15, kgrp = lane >> 4;
    const int prow = tid >> 3;
    const int pp   = tid & 7;
    const int wbase = (tid & ~63) * 8;
    // XCD-chunked swizzle (bijective since gridDim.x % 8 == 0)
    const int cpx = (int)gridDim.x >> 3;
    const int id  = ((int)blockIdx.x & 7) * cpx + ((int)blockIdx.x >> 3);
    const int bn  = (id % nbn) * 128;
    const int bm  = (id / nbn) * BM;

    f32x4 acc[BMF][4] = {};

    for (int k0 = 0; k0 < K; k0 += 64) {
        __syncthreads();
#pragma unroll
        for (int it = 0; it < BMF; ++it) {
            int r  = it * 32 + prow;
            int gc = k0 + ((pp ^ (r & 7)) << 3);
            __builtin_amdgcn_global_load_lds(
                (gp32)(const void*)(A + (size_t)(bm + r) * K + gc),
                (lp32)(void*)(As + it * 2048 + wbase), 16, 0, 0);
        }
#pragma unroll
        for (int it = 0; it < 4; ++it) {
            int r  = it * 32 + prow;
            int gc = k0 + ((pp ^ (r & 7)) << 3);
            __builtin_amdgcn_global_load_lds(
                (gp32)(const void*)(W + (size_t)(bn + r) * K + gc),
                (lp32)(void*)(Bs + it * 2048 + wbase), 16, 0, 0);
        }
        __syncthreads();
#pragma unroll
        for (int ks = 0; ks < 2; ++ks) {
            bf16x8 af[BMF], bv[4];
#pragma unroll
            for (int i = 0; i < BMF; ++i) {
                int ra = wr * (BM / 2) + i * 16 + l16;
                af[i] = *(const bf16x8*)(As + ra * 64 + ((((ks << 2) | kgrp) ^ (ra & 7)) << 3));
            }
#pragma unroll
            for (int j = 0; j < 4; ++j) {
                int rb = wc * 64 + j * 16 + l16;
                bv[j] = *(const bf16x8*)(Bs + rb * 64 + ((((ks << 2) | kgrp) ^ (rb & 7)) << 3));
            }
#pragma unroll
            for (int i = 0; i < BMF; ++i)
#pragma unroll
                for (int j = 0; j < 4; ++j)
                    acc[i][j] = __builtin_amdgcn_mfma_f32_16x16x32_bf16(
                        af[i], bv[j], acc[i][j], 0, 0, 0);
        }
    }
    // epilogue: C/D layout col=lane&15, row=(lane>>4)*4+q  [m89/m91 verified]
#pragma unroll
    for (int i = 0; i < BMF; ++i) {
#pragma unroll
        for (int j = 0; j < 4; ++j) {
            int col = bn + wc * 64 + j * 16 + l16;
            if (ACT == 2) {
                if (col < 1024) {
                    float badd = bias[col];
#pragma unroll
                    for (int q = 0; q < 4; ++q) {
                        int row = bm + wr * (BM / 2) + i * 16 + kgrp * 4 + q;
                        float d = softplusf(acc[i][j][q] + badd);
                        ((bf16_t*)Cv)[(size_t)row * 1024 + col] = (bf16_t)d;
                        dxc[(size_t)row * 1024 + col] =
                            (bf16_t)(d * (float)xcp[(size_t)row * 1024 + col]);
                    }
                } else if (col < 1056) {
#pragma unroll
                    for (int q = 0; q < 4; ++q) {
                        int row = bm + wr * (BM / 2) + i * 16 + kgrp * 4 + q;
                        bcb[(size_t)row * 32 + (col - 1024)] = acc[i][j][q];
                    }
                }
            } else if (ACT == 3) {
#pragma unroll
                for (int q = 0; q < 4; ++q) {
                    int row = bm + wr * (BM / 2) + i * 16 + kgrp * 4 + q;
                    float v = acc[i][j][q];
                    if (col < 1024)
                        ((bf16_t*)Cv)[(size_t)row * 1024 + col] = (bf16_t)v;
                    else
                        ((bf16_t*)aux)[(size_t)row * 1024 + (col - 1024)] = (bf16_t)v;
                }
            } else {
                float badd = BIAS ? bias[col] : 0.f;
#pragma unroll
                for (int q = 0; q < 4; ++q) {
                    int row = bm + wr * (BM / 2) + i * 16 + kgrp * 4 + q;
                    float v = acc[i][j][q] + badd;
                    if (RES) v += res[(size_t)row * ldc + col];
                    if (ACT == 1) v = fmaxf(v, 0.f);
                    if (OUTBF) ((bf16_t*)Cv)[(size_t)row * ldc + col] = (bf16_t)v;
                    else       ((float*)Cv)[(size_t)row * ldc + col] = v;
                }
            }
        }
    }
}

// ---------------- causal depthwise conv (D_CONV=4) + SiLU, bf16 in/out ----
__global__ __launch_bounds__(256) void conv_silu_kernel(
    const bf16_t* __restrict__ xraw, const float* __restrict__ cw,
    const float* __restrict__ cb, bf16_t* __restrict__ out) {
    int idx = blockIdx.x * blockDim.x + threadIdx.x;  // ROWS*DI
    int c = idx & (DI - 1);
    int row = idx >> 10;
    int t = row & (LSEQ - 1);
    float acc = cb[c];
#pragma unroll
    for (int k = 0; k < 4; ++k) {
        int st = t + k - 3;
        if (st >= 0)
            acc = fmaf(cw[c * 4 + k], (float)xraw[(size_t)(row + k - 3) * 1024 + c], acc);
    }
    out[idx] = (bf16_t)siluf(acc);
}

// ---------------- chunked parallel scan, half-split register version ------
// Thread owns 8 of 16 n-states for one e. grid (8, NCH, 2).
__global__ __launch_bounds__(256) void scan1_kernel(
    const bf16_t* __restrict__ dbuf, const bf16_t* __restrict__ dxcb,
    const float* __restrict__ bc_in, const float* __restrict__ A_log,
    float* __restrict__ aprod, float* __restrict__ bacc) {
    int gid  = blockIdx.x * 256 + threadIdx.x;
    int e    = gid >> 1;
    int half = gid & 1;
    int ch = blockIdx.y;
    int b  = blockIdx.z;
    float cAn[8];
#pragma unroll
    for (int n = 0; n < 8; ++n)
        cAn[n] = -expf(A_log[e * 16 + half * 8 + n]) * 1.4426950408889634f;
    float ap[8], bc[8];
#pragma unroll
    for (int n = 0; n < 8; ++n) { ap[n] = 1.f; bc[n] = 0.f; }
    int row0 = b * LSEQ + ch * CHT;
    float d_c   = (float)dbuf[(size_t)row0 * DI + e];
    float dxc_c = (float)dxcb[(size_t)row0 * 1024 + e];
    for (int t = 0; t < CHT; ++t) {
        int row = row0 + t;
        float d_n = 0.f, dxc_n = 0.f;
        if (t + 1 < CHT) {
            d_n   = (float)dbuf[(size_t)(row + 1) * DI + e];
            dxc_n = (float)dxcb[(size_t)(row + 1) * 1024 + e];
        }
        const float* brow = bc_in + (size_t)row * 32 + half * 8;
        float4 b0 = *(const float4*)brow;
        float4 b1 = *(const float4*)(brow + 4);
        float Bn[8] = {b0.x, b0.y, b0.z, b0.w, b1.x, b1.y, b1.z, b1.w};
#pragma unroll
        for (int n = 0; n < 8; ++n) {
            float dA = exp2f(d_c * cAn[n]);
            ap[n] *= dA;
            bc[n] = fmaf(dA, bc[n], dxc_c * Bn[n]);
        }
        d_c = d_n; dxc_c = dxc_n;
    }
    size_t idx = ((size_t)((b * NCH + ch) * DI + e)) * 16 + half * 8;
    float4* apo = (float4*)(aprod + idx);
    float4* bco = (float4*)(bacc + idx);
#pragma unroll
    for (int q = 0; q < 2; ++q) {
        apo[q] = make_float4(ap[q * 4], ap[q * 4 + 1], ap[q * 4 + 2], ap[q * 4 + 3]);
        bco[q] = make_float4(bc[q * 4], bc[q * 4 + 1], bc[q * 4 + 2], bc[q * 4 + 3]);
    }
}

// -------- cross-chunk scan, 3-pass 8x8 hierarchy (replaces serial-64) -----
// pass A: compose 8 chunks per group. thread=(b,grp,e,n), 262144 threads.
__global__ __launch_bounds__(256) void scan2a_kernel(
    const float* __restrict__ aprod, const float* __restrict__ bacc,
    float* __restrict__ gA, float* __restrict__ gB) {
    int t = blockIdx.x * 256 + threadIdx.x;
    int n = t & 15, e = (t >> 4) & 1023, grp = (t >> 14) & 7, b = t >> 17;
    float A = 1.f, B = 0.f;
    for (int i = 0; i < 8; ++i) {
        int ch = grp * 8 + i;
        size_t idx = ((size_t)((b * NCH + ch) * DI + e)) * 16 + n;
        float a = aprod[idx], bb = bacc[idx];
        A = a * A;
        B = fmaf(a, B, bb);
    }
    size_t g = ((size_t)((b * 8 + grp) * DI + e)) * 16 + n;
    gA[g] = A; gB[g] = B;
}
// pass B: serial scan over 8 groups. 32768 threads.
__global__ __launch_bounds__(256) void scan2b_kernel(
    const float* __restrict__ gA, const float* __restrict__ gB,
    float* __restrict__ ghin) {
    int t = blockIdx.x * 256 + threadIdx.x;
    int n = t & 15, e = (t >> 4) & 1023, b = t >> 14;
    float h = 0.f;
    for (int g = 0; g < 8; ++g) {
        size_t idx = ((size_t)((b * 8 + g) * DI + e)) * 16 + n;
        ghin[idx] = h;
        h = fmaf(gA[idx], h, gB[idx]);
    }
}
// pass C: within-group h_init; hinit overwrites aprod (read-before-write).
__global__ __launch_bounds__(256) void scan2c_kernel(
    const float* __restrict__ ghin, float* aprod_hinit,
    const float* __restrict__ bacc) {
    int t = blockIdx.x * 256 + threadIdx.x;
    int n = t & 15, e = (t >> 4) & 1023, grp = (t >> 14) & 7, b = t >> 17;
    float h = ghin[((size_t)((b * 8 + grp) * DI + e)) * 16 + n];
    for (int i = 0; i < 8; ++i) {
        int ch = grp * 8 + i;
        size_t idx = ((size_t)((b * NCH + ch) * DI + e)) * 16 + n;
        float a = aprod_hinit[idx], bb = bacc[idx];
        aprod_hinit[idx] = h;
        h = fmaf(a, h, bb);
    }
}

// scan3: re-run each chunk from h_init; fuse C-contraction + D-skip + gate.
__global__ __launch_bounds__(256) void scan3_kernel(
    const bf16_t* __restrict__ dbuf, const bf16_t* __restrict__ dxcb,
    const bf16_t* __restrict__ xcb, const bf16_t* __restrict__ zb,
    const float* __restrict__ bc_in, const float* __restrict__ A_log,
    const float* __restrict__ Dp, const float* __restrict__ hinit,
    bf16_t* __restrict__ yg) {
    int gid  = blockIdx.x * 256 + threadIdx.x;
    int e    = gid >> 1;
    int half = gid & 1;
    int ch = blockIdx.y;
    int b  = blockIdx.z;
    float cAn[8];
#pragma unroll
    for (int n = 0; n < 8; ++n)
        cAn[n] = -expf(A_log[e * 16 + half * 8 + n]) * 1.4426950408889634f;
    float h[8];
    {
        const float4* hp = (const float4*)(hinit +
            ((size_t)((b * NCH + ch) * DI + e)) * 16 + half * 8);
#pragma unroll
        for (int q = 0; q < 2; ++q) {
            float4 v = hp[q];
            h[q * 4] = v.x; h[q * 4 + 1] = v.y; h[q * 4 + 2] = v.z; h[q * 4 + 3] = v.w;
        }
    }
    float Dpe = Dp[e];
    int row0 = b * LSEQ + ch * CHT;
    float d_c   = (float)dbuf[(size_t)row0 * DI + e];
    float dxc_c = (float)dxcb[(size_t)row0 * 1024 + e];
    float xc_c  = (float)xcb[(size_t)row0 * 1024 + e];
    float z_c   = (float)zb[(size_t)row0 * 1024 + e];
    for (int t = 0; t < CHT; ++t) {
        int row = row0 + t;
        float d_n = 0.f, dxc_n = 0.f, xc_n = 0.f, z_n = 0.f;
        if (t + 1 < CHT) {
            d_n   = (float)dbuf[(size_t)(row + 1) * DI + e];
            dxc_n = (float)dxcb[(size_t)(row + 1) * 1024 + e];
            xc_n  = (float)xcb[(size_t)(row + 1) * 1024 + e];
            z_n   = (float)zb[(size_t)(row + 1) * 1024 + e];
        }
        const float* brow = bc_in + (size_t)row * 32;
        float4 b0 = *(const float4*)(brow + half * 8);
        float4 b1 = *(const float4*)(brow + half * 8 + 4);
        float4 c0 = *(const float4*)(brow + 16 + half * 8);
        float4 c1 = *(const float4*)(brow + 16 + half * 8 + 4);
        float Bn[8] = {b0.x, b0.y, b0.z, b0.w, b1.x, b1.y, b1.z, b1.w};
        float Cn[8] = {c0.x, c0.y, c0.z, c0.w, c1.x, c1.y, c1.z, c1.w};
        float y = half ? 0.f : Dpe * xc_c;
#pragma unroll
        for (int n = 0; n < 8; ++n) {
            float dA = exp2f(d_c * cAn[n]);
            h[n] = fmaf(dA, h[n], dxc_c * Bn[n]);
            y = fmaf(h[n], Cn[n], y);
        }
        y += __shfl_xor(y, 1);
        if (half == 0)
            yg[(size_t)row * DI + e] = (bf16_t)(y * siluf(z_c));
        d_c = d_n; dxc_c = dxc_n; xc_c = xc_n; z_c = z_n;
    }
}

extern "C" void kernel_launch(void* const* d_in, const int* in_sizes, int n_in,
                              void* d_out, int out_size, void* d_ws, size_t ws_size,
                              hipStream_t stream) {
    const float* x    = (const float*)d_in[0];
    const float* ipw  = (const float*)d_in[1];
    const float* cw   = (const float*)d_in[2];
    const float* cb   = (const float*)d_in[3];
    const float* xpw  = (const float*)d_in[4];
    const float* dtw  = (const float*)d_in[5];
    const float* dtb  = (const float*)d_in[6];
    const float* alog = (const float*)d_in[7];
    const float* dpar = (const float*)d_in[8];
    const float* opw  = (const float*)d_in[9];
    const float* rmsw = (const float*)d_in[10];
    const float* ln1w = (const float*)d_in[11];
    const float* ln1b = (const float*)d_in[12];
    const float* ln2w = (const float*)d_in[13];
    const float* ln2b = (const float*)d_in[14];
    const float* fw1  = (const float*)d_in[15];
    const float* fb1  = (const float*)d_in[16];
    const float* fw2  = (const float*)d_in[17];
    const float* fb2  = (const float*)d_in[18];
    const float* finw = (const float*)d_in[19];
    const float* finb = (const float*)d_in[20];
    float* out = (float*)d_out;

    // ---- workspace layout (MF = 1M floats = 4MB). ROWSxDI bf16 buffers are
    // 4M bf16 = 2 MF each (the round-10 bug was sizing these at 1 MF).
    const size_t MF = 1u << 20;
    float*  ws     = (float*)d_ws;
    float*  h      = ws;                                // 0..2    fp32 ROWSxDM
    bf16_t* hnb    = (bf16_t*)(ws + 2 * MF);            // 2..3    bf16 ROWSxDM
    bf16_t* xrawb  = (bf16_t*)(ws + 3 * MF);            // 3..5    bf16 ROWSxDI
    bf16_t* zb     = (bf16_t*)(ws + 5 * MF);            // 5..7    bf16 ROWSxDI
    bf16_t* xcb    = (bf16_t*)(ws + 7 * MF);            // 7..9    bf16 ROWSxDI (later midb)
    bf16_t* dbufb  = (bf16_t*)(ws + 9 * MF);            // 9..11   bf16 ROWSxDI (later x2)
    bf16_t* dxcbb  = (bf16_t*)(ws + 11 * MF);           // 11..13  bf16 ROWSxDI (later x3b)
    float*  bcbuf  = ws + 13 * MF;                      // 13..13.125 fp32 ROWSx32
    bf16_t* ygb    = (bf16_t*)(ws + 13 * MF + MF / 4);  // 13.25..15.25 bf16 ROWSxDI
    float*  aprod  = ws + 15 * MF + MF / 4;             // 15.25..17.25 (hinit aliases)
    float*  bacc   = ws + 17 * MF + MF / 4;             // 17.25..19.25
    float*  gsA    = ws + 19 * MF + MF / 4;             // 19.25..19.5
    float*  gsB    = ws + 19 * MF + MF / 2;             // 19.5..19.75
    float*  ghin   = ws + 19 * MF + 3 * MF / 4;         // 19.75..20
    bf16_t* warena = (bf16_t*)(ws + 20 * MF);           // 20..23.25 (6.8M bf16)
    // overlays (dead-before-write):
    float*  x2     = (float*)dbufb;                     // dbufb dead after scan3
    bf16_t* midb   = xcb;                               // xcb dead after scan3
    bf16_t* x3b    = dxcbb;                             // dxcbb dead after scan3
    float*  hinit  = aprod;                             // scan2c RAW-safe in-place
    const size_t IPW_OFF = 0, OPW_OFF = 2097152, FW1_OFF = 3145728,
                 FW2_OFF = 3670016, FINW_OFF = 4194304, WC_OFF = 4456448;

    // 0. weights -> bf16 arena; both layers' Wcomb (weights-only)
    cvt_kernel<<<17408, 256, 0, stream>>>(ipw, opw, fw1, fw2, finw, warena);
    for (int i = 0; i < 2; ++i)
        wd_kernel<<<NCOMB * 1024 / 256, 256, 0, stream>>>(
            dtw + (size_t)i * DI * 32, xpw + (size_t)i * 64 * DI,
            warena + WC_OFF + (size_t)i * NCOMB * 1024);
    // 1. h = LN1(x)
    ln_kernel<<<ROWS, 256, 0, stream>>>(x, ln1w, ln1b, h);

    for (int i = 0; i < 2; ++i) {
        const bf16_t* ipwb_i = warena + IPW_OFF + (size_t)i * 2048 * 512;
        const bf16_t* opwb_i = warena + OPW_OFF + (size_t)i * 512 * 1024;
        const bf16_t* wcombb = warena + WC_OFF + (size_t)i * NCOMB * 1024;
        const float* cw_i   = cw   + (size_t)i * DI * 4;
        const float* cb_i   = cb   + (size_t)i * DI;
        const float* dtb_i  = dtb  + (size_t)i * DI;
        const float* alog_i = alog + (size_t)i * DI * 16;
        const float* dp_i   = dpar + (size_t)i * DI;
        const float* rms_i  = rmsw + (size_t)i * DM;

        // hnb = RMS(h) bf16
        rms_kernel<<<ROWS, 256, 0, stream>>>(h, rms_i, hnb);
        // in_proj (BM=64): cols<1024 -> xrawb bf16, cols>=1024 -> zb bf16
        mgemm_kernel<2, 3, false, false, false><<<1024, 256, 0, stream>>>(
            hnb, ipwb_i, nullptr, nullptr, xrawb, 16, 512, 1024,
            nullptr, nullptr, nullptr, zb);
        // xcb = silu(conv(xrawb)) bf16
        conv_silu_kernel<<<ROWS * DI / 256, 256, 0, stream>>>(xrawb, cw_i, cb_i, xcb);
        // combined: d=softplus(.)->dbufb bf16; dxc=d*xc->dxcbb bf16; B/C->bcbuf
        mgemm_kernel<2, 2, false, false, false><<<576, 256, 0, stream>>>(
            xcb, wcombb, dtb_i, nullptr, dbufb, 9, 1024, 1024,
            xcb, dxcbb, bcbuf, nullptr);
        // chunked parallel scan
        scan1_kernel<<<dim3(8, NCH, 2), 256, 0, stream>>>(dbufb, dxcbb, bcbuf,
                                                          alog_i, aprod, bacc);
        scan2a_kernel<<<1024, 256, 0, stream>>>(aprod, bacc, gsA, gsB);
        scan2b_kernel<<<128, 256, 0, stream>>>(gsA, gsB, ghin);
        scan2c_kernel<<<1024, 256, 0, stream>>>(ghin, aprod, bacc);
        scan3_kernel<<<dim3(8, NCH, 2), 256, 0, stream>>>(dbufb, dxcbb, xcb, zb,
                                                          bcbuf, alog_i, dp_i,
                                                          hinit, ygb);
        // h = h + ygb @ opw^T  (BM=64, 256 blocks)
        mgemm_kernel<2, 0, false, true, false><<<256, 256, 0, stream>>>(
            ygb, opwb_i, nullptr, h, h, 4, 1024, DM,
            nullptr, nullptr, nullptr, nullptr);
    }

    // x2 = x + h; hnb = LN2(x2)  (fused; x2 overlays dbufb)
    ln_add_kernel<<<ROWS, 256, 0, stream>>>(x, h, ln2w, ln2b, x2, hnb);
    // mid = relu(hnb @ fw1^T + fb1) bf16 (midb overlays xcb)
    mgemm_kernel<2, 1, true, false, true><<<512, 256, 0, stream>>>(
        hnb, warena + FW1_OFF, fb1, nullptr, midb, 8, 512, DI,
        nullptr, nullptr, nullptr, nullptr);
    // x3 = x2 + mid @ fw2^T + fb2  bf16 (x3b overlays dxcbb)
    mgemm_kernel<2, 0, true, true, true><<<256, 256, 0, stream>>>(
        midb, warena + FW2_OFF, fb2, x2, x3b, 4, 1024, DM,
        nullptr, nullptr, nullptr, nullptr);
    // out = x3 @ finw^T + finb  fp32
    mgemm_kernel<2, 0, true, false, false><<<256, 256, 0, stream>>>(
        x3b, warena + FINW_OFF, finb, nullptr, out, 4, 512, DM,
        nullptr, nullptr, nullptr, nullptr);
}

// Round 12
// 505.807 us; speedup vs baseline: 10.6201x; 1.0124x over previous
//
#include <hip/hip_runtime.h>
#include <math.h>

#define ROWS 4096   // B * L
#define LSEQ 2048
#define DM   512
#define DI   1024
#define NCH  64            // scan chunks per sequence
#define CHT  (LSEQ / NCH)  // 32 timesteps per chunk
#define NCOMB 1152         // combined x_proj/dt GEMM N (1024 delta + 32 B/C + 96 pad)

typedef __bf16 bf16_t;
typedef bf16_t bf16x8 __attribute__((ext_vector_type(8)));
typedef float f32x4 __attribute__((ext_vector_type(4)));
typedef unsigned int u32;
typedef const __attribute__((address_space(1))) u32* gp32;
typedef __attribute__((address_space(3))) u32* lp32;

__device__ __forceinline__ float siluf(float v) { return v / (1.f + expf(-v)); }
__device__ __forceinline__ float softplusf(float v) {
    return fmaxf(v, 0.f) + log1pf(expf(-fabsf(v)));
}

// ---------------- LN1: one block per row of 512, fp32 out ----------------
__global__ __launch_bounds__(256) void ln_kernel(const float* __restrict__ x,
                                                 const float* __restrict__ w,
                                                 const float* __restrict__ b,
                                                 float* __restrict__ out) {
    int row = blockIdx.x;
    int tid = threadIdx.x;
    const float* xr = x + (size_t)row * DM;
    float v0 = xr[tid], v1 = xr[tid + 256];
    float sum = v0 + v1, sq = v0 * v0 + v1 * v1;
    for (int o = 32; o > 0; o >>= 1) {
        sum += __shfl_down(sum, o);
        sq  += __shfl_down(sq, o);
    }
    __shared__ float s1[4], s2[4];
    int wid = tid >> 6, lane = tid & 63;
    if (lane == 0) { s1[wid] = sum; s2[wid] = sq; }
    __syncthreads();
    sum = s1[0] + s1[1] + s1[2] + s1[3];
    sq  = s2[0] + s2[1] + s2[2] + s2[3];
    float mu  = sum * (1.f / DM);
    float var = sq * (1.f / DM) - mu * mu;
    float r   = rsqrtf(var + 1e-5f);
    out[(size_t)row * DM + tid]       = (v0 - mu) * r * w[tid] + b[tid];
    out[(size_t)row * DM + tid + 256] = (v1 - mu) * r * w[tid + 256] + b[tid + 256];
}

// ---------------- LN2 fused with residual add: x2 = x + h; outb = LN(x2) --
__global__ __launch_bounds__(256) void ln_add_kernel(
    const float* __restrict__ x, const float* __restrict__ hres,
    const float* __restrict__ w, const float* __restrict__ b,
    float* __restrict__ x2, bf16_t* __restrict__ outb) {
    int row = blockIdx.x;
    int tid = threadIdx.x;
    size_t base = (size_t)row * DM;
    float v0 = x[base + tid] + hres[base + tid];
    float v1 = x[base + tid + 256] + hres[base + tid + 256];
    x2[base + tid] = v0;
    x2[base + tid + 256] = v1;
    float sum = v0 + v1, sq = v0 * v0 + v1 * v1;
    for (int o = 32; o > 0; o >>= 1) {
        sum += __shfl_down(sum, o);
        sq  += __shfl_down(sq, o);
    }
    __shared__ float s1[4], s2[4];
    int wid = tid >> 6, lane = tid & 63;
    if (lane == 0) { s1[wid] = sum; s2[wid] = sq; }
    __syncthreads();
    sum = s1[0] + s1[1] + s1[2] + s1[3];
    sq  = s2[0] + s2[1] + s2[2] + s2[3];
    float mu  = sum * (1.f / DM);
    float var = sq * (1.f / DM) - mu * mu;
    float r   = rsqrtf(var + 1e-5f);
    outb[base + tid]       = (bf16_t)((v0 - mu) * r * w[tid] + b[tid]);
    outb[base + tid + 256] = (bf16_t)((v1 - mu) * r * w[tid + 256] + b[tid + 256]);
}

// ---------------- RMSNorm: one block per row of 512, bf16 out -------------
__global__ __launch_bounds__(256) void rms_kernel(const float* __restrict__ x,
                                                  const float* __restrict__ w,
                                                  bf16_t* __restrict__ out) {
    int row = blockIdx.x;
    int tid = threadIdx.x;
    const float* xr = x + (size_t)row * DM;
    float v0 = xr[tid], v1 = xr[tid + 256];
    float sq = v0 * v0 + v1 * v1;
    for (int o = 32; o > 0; o >>= 1) sq += __shfl_down(sq, o);
    __shared__ float s2[4];
    int wid = tid >> 6, lane = tid & 63;
    if (lane == 0) s2[wid] = sq;
    __syncthreads();
    sq = s2[0] + s2[1] + s2[2] + s2[3];
    float r = rsqrtf(sq * (1.f / DM) + 1e-5f);
    out[(size_t)row * DM + tid]       = (bf16_t)(v0 * r * w[tid]);
    out[(size_t)row * DM + tid + 256] = (bf16_t)(v1 * r * w[tid + 256]);
}

// ---------------- weight f32 -> bf16 arena converter ----------------------
__global__ __launch_bounds__(256) void cvt_kernel(
    const float* __restrict__ ipw, const float* __restrict__ opw,
    const float* __restrict__ fw1, const float* __restrict__ fw2,
    const float* __restrict__ finw, bf16_t* __restrict__ arena) {
    int idx = blockIdx.x * 256 + threadIdx.x;
    float v;
    if (idx < 2097152)      v = ipw[idx];
    else if (idx < 3145728) v = opw[idx - 2097152];
    else if (idx < 3670016) v = fw1[idx - 3145728];
    else if (idx < 4194304) v = fw2[idx - 3670016];
    else                    v = finw[idx - 4194304];
    arena[idx] = (bf16_t)v;
}

// ---------------- Wcomb builder, both layers (bf16 out) -------------------
// layer = blockIdx.y. rows 0-1023 = dtw@xpw[:32]; 1024-1055 = xpw[32:64]; 0.
__global__ __launch_bounds__(256) void wd_kernel(
    const float* __restrict__ dtw_all, const float* __restrict__ xpw_all,
    bf16_t* __restrict__ wcomb_all) {
    int layer = blockIdx.y;
    const float* dtw = dtw_all + (size_t)layer * DI * 32;
    const float* xpw = xpw_all + (size_t)layer * 64 * DI;
    bf16_t* wcomb = wcomb_all + (size_t)layer * NCOMB * 1024;
    int idx = blockIdx.x * 256 + threadIdx.x;  // NCOMB*1024
    int j = idx & 1023;
    int i = idx >> 10;
    float v;
    if (i < 1024) {
        const float* dr = dtw + i * 32;
        v = 0.f;
#pragma unroll
        for (int k = 0; k < 32; ++k) v = fmaf(dr[k], xpw[k * 1024 + j], v);
    } else if (i < 1056) {
        v = xpw[(i - 1024 + 32) * 1024 + j];
    } else {
        v = 0.f;
    }
    wcomb[idx] = (bf16_t)v;
}

// ---------------- bf16 MFMA GEMM: C = A @ W^T, 2-phase double-buffered ----
// BM = BMF*32 x 128 tile, 4 waves (2x2), each wave (BM/2)x64, BK=64.
// Double-buffered LDS: STAGE(next) issued BEFORE compute(cur); single
// __syncthreads per K-step (its vmcnt(0) drain lands after compute overlap).
// 1D grid with XCD-chunked swizzle (gridDim.x % 8 == 0), bn fastest.
// XOR swizzle (row&7) on global source + ds_read (rule 21) -> conflict-free.
// ACT: 0 none, 1 relu, 2 comb-mamba epilogue (d only), 3 in_proj split.
template <int BMF, int ACT, bool BIAS, bool RES, bool OUTBF>
__global__ __launch_bounds__(256) void mgemm_kernel(
    const bf16_t* __restrict__ A, const bf16_t* __restrict__ W,
    const float* __restrict__ bias, const float* __restrict__ res,
    void* __restrict__ Cv, int nbn, int K, int ldc,
    float* __restrict__ bcb, void* __restrict__ aux) {
    constexpr int BM = BMF * 32;
    __shared__ bf16_t As[2][BM * 64];
    __shared__ bf16_t Bs[2][128 * 64];
    const int tid  = threadIdx.x;
    const int lane = tid & 63;
    const int wave = tid >> 6;
    const int wr = wave >> 1, wc = wave & 1;
    const int l16 = lane & 15, kgrp = lane >> 4;
    const int prow = tid >> 3;
    const int pp   = tid & 7;
    const int wbase = (tid & ~63) * 8;
    // XCD-chunked swizzle (bijective since gridDim.x % 8 == 0)
    const int cpx = (int)gridDim.x >> 3;
    const int id  = ((int)blockIdx.x & 7) * cpx + ((int)blockIdx.x >> 3);
    const int bn  = (id % nbn) * 128;
    const int bm  = (id / nbn) * BM;

    f32x4 acc[BMF][4] = {};

#define STAGE(buf, k0)                                                        \
    {                                                                         \
        _Pragma("unroll")                                                     \
        for (int it = 0; it < BMF; ++it) {                                    \
            int r  = it * 32 + prow;                                          \
            int gc = (k0) + ((pp ^ (r & 7)) << 3);                            \
            __builtin_amdgcn_global_load_lds(                                 \
                (gp32)(const void*)(A + (size_t)(bm + r) * K + gc),           \
                (lp32)(void*)(As[buf] + it * 2048 + wbase), 16, 0, 0);        \
        }                                                                     \
        _Pragma("unroll")                                                     \
        for (int it = 0; it < 4; ++it) {                                      \
            int r  = it * 32 + prow;                                          \
            int gc = (k0) + ((pp ^ (r & 7)) << 3);                            \
            __builtin_amdgcn_global_load_lds(                                 \
                (gp32)(const void*)(W + (size_t)(bn + r) * K + gc),           \
                (lp32)(void*)(Bs[buf] + it * 2048 + wbase), 16, 0, 0);        \
        }                                                                     \
    }

    const int NT = K >> 6;
    STAGE(0, 0);
    __syncthreads();
    for (int t = 0; t < NT; ++t) {
        const int cur = t & 1;
        if (t + 1 < NT) STAGE(cur ^ 1, (t + 1) << 6);
#pragma unroll
        for (int ks = 0; ks < 2; ++ks) {
            bf16x8 af[BMF], bv[4];
#pragma unroll
            for (int i = 0; i < BMF; ++i) {
                int ra = wr * (BM / 2) + i * 16 + l16;
                af[i] = *(const bf16x8*)(As[cur] + ra * 64 +
                        ((((ks << 2) | kgrp) ^ (ra & 7)) << 3));
            }
#pragma unroll
            for (int j = 0; j < 4; ++j) {
                int rb = wc * 64 + j * 16 + l16;
                bv[j] = *(const bf16x8*)(Bs[cur] + rb * 64 +
                        ((((ks << 2) | kgrp) ^ (rb & 7)) << 3));
            }
#pragma unroll
            for (int i = 0; i < BMF; ++i)
#pragma unroll
                for (int j = 0; j < 4; ++j)
                    acc[i][j] = __builtin_amdgcn_mfma_f32_16x16x32_bf16(
                        af[i], bv[j], acc[i][j], 0, 0, 0);
        }
        __syncthreads();  // drains next-tile loads (overlapped with MFMA above)
    }
#undef STAGE
    // epilogue: C/D layout col=lane&15, row=(lane>>4)*4+q  [m89/m91 verified]
#pragma unroll
    for (int i = 0; i < BMF; ++i) {
#pragma unroll
        for (int j = 0; j < 4; ++j) {
            int col = bn + wc * 64 + j * 16 + l16;
            if (ACT == 2) {
                if (col < 1024) {
                    float badd = bias[col];
#pragma unroll
                    for (int q = 0; q < 4; ++q) {
                        int row = bm + wr * (BM / 2) + i * 16 + kgrp * 4 + q;
                        float d = softplusf(acc[i][j][q] + badd);
                        ((bf16_t*)Cv)[(size_t)row * 1024 + col] = (bf16_t)d;
                    }
                } else if (col < 1056) {
#pragma unroll
                    for (int q = 0; q < 4; ++q) {
                        int row = bm + wr * (BM / 2) + i * 16 + kgrp * 4 + q;
                        bcb[(size_t)row * 32 + (col - 1024)] = acc[i][j][q];
                    }
                }
            } else if (ACT == 3) {
#pragma unroll
                for (int q = 0; q < 4; ++q) {
                    int row = bm + wr * (BM / 2) + i * 16 + kgrp * 4 + q;
                    float v = acc[i][j][q];
                    if (col < 1024)
                        ((bf16_t*)Cv)[(size_t)row * 1024 + col] = (bf16_t)v;
                    else
                        ((bf16_t*)aux)[(size_t)row * 1024 + (col - 1024)] = (bf16_t)v;
                }
            } else {
                float badd = BIAS ? bias[col] : 0.f;
#pragma unroll
                for (int q = 0; q < 4; ++q) {
                    int row = bm + wr * (BM / 2) + i * 16 + kgrp * 4 + q;
                    float v = acc[i][j][q] + badd;
                    if (RES) v += res[(size_t)row * ldc + col];
                    if (ACT == 1) v = fmaxf(v, 0.f);
                    if (OUTBF) ((bf16_t*)Cv)[(size_t)row * ldc + col] = (bf16_t)v;
                    else       ((float*)Cv)[(size_t)row * ldc + col] = v;
                }
            }
        }
    }
}

// ---------------- causal depthwise conv (D_CONV=4) + SiLU, bf16 in/out ----
__global__ __launch_bounds__(256) void conv_silu_kernel(
    const bf16_t* __restrict__ xraw, const float* __restrict__ cw,
    const float* __restrict__ cb, bf16_t* __restrict__ out) {
    int idx = blockIdx.x * blockDim.x + threadIdx.x;  // ROWS*DI
    int c = idx & (DI - 1);
    int row = idx >> 10;
    int t = row & (LSEQ - 1);
    float acc = cb[c];
#pragma unroll
    for (int k = 0; k < 4; ++k) {
        int st = t + k - 3;
        if (st >= 0)
            acc = fmaf(cw[c * 4 + k], (float)xraw[(size_t)(row + k - 3) * 1024 + c], acc);
    }
    out[idx] = (bf16_t)siluf(acc);
}

// ---------------- chunked parallel scan, half-split register version ------
// Thread owns 8 of 16 n-states for one e; dxc = d*xc computed on the fly.
__global__ __launch_bounds__(256) void scan1_kernel(
    const bf16_t* __restrict__ dbuf, const bf16_t* __restrict__ xcb,
    const float* __restrict__ bc_in, const float* __restrict__ A_log,
    float* __restrict__ aprod, float* __restrict__ bacc) {
    int gid  = blockIdx.x * 256 + threadIdx.x;
    int e    = gid >> 1;
    int half = gid & 1;
    int ch = blockIdx.y;
    int b  = blockIdx.z;
    float cAn[8];
#pragma unroll
    for (int n = 0; n < 8; ++n)
        cAn[n] = -expf(A_log[e * 16 + half * 8 + n]) * 1.4426950408889634f;
    float ap[8], bc[8];
#pragma unroll
    for (int n = 0; n < 8; ++n) { ap[n] = 1.f; bc[n] = 0.f; }
    int row0 = b * LSEQ + ch * CHT;
    float d_c  = (float)dbuf[(size_t)row0 * DI + e];
    float xc_c = (float)xcb[(size_t)row0 * 1024 + e];
    for (int t = 0; t < CHT; ++t) {
        int row = row0 + t;
        float d_n = 0.f, xc_n = 0.f;
        if (t + 1 < CHT) {
            d_n  = (float)dbuf[(size_t)(row + 1) * DI + e];
            xc_n = (float)xcb[(size_t)(row + 1) * 1024 + e];
        }
        const float* brow = bc_in + (size_t)row * 32 + half * 8;
        float4 b0 = *(const float4*)brow;
        float4 b1 = *(const float4*)(brow + 4);
        float Bn[8] = {b0.x, b0.y, b0.z, b0.w, b1.x, b1.y, b1.z, b1.w};
        float dxc_c = d_c * xc_c;
#pragma unroll
        for (int n = 0; n < 8; ++n) {
            float dA = exp2f(d_c * cAn[n]);
            ap[n] *= dA;
            bc[n] = fmaf(dA, bc[n], dxc_c * Bn[n]);
        }
        d_c = d_n; xc_c = xc_n;
    }
    size_t idx = ((size_t)((b * NCH + ch) * DI + e)) * 16 + half * 8;
    float4* apo = (float4*)(aprod + idx);
    float4* bco = (float4*)(bacc + idx);
#pragma unroll
    for (int q = 0; q < 2; ++q) {
        apo[q] = make_float4(ap[q * 4], ap[q * 4 + 1], ap[q * 4 + 2], ap[q * 4 + 3]);
        bco[q] = make_float4(bc[q * 4], bc[q * 4 + 1], bc[q * 4 + 2], bc[q * 4 + 3]);
    }
}

// -------- cross-chunk scan, 3-pass 8x8 hierarchy --------------------------
__global__ __launch_bounds__(256) void scan2a_kernel(
    const float* __restrict__ aprod, const float* __restrict__ bacc,
    float* __restrict__ gA, float* __restrict__ gB) {
    int t = blockIdx.x * 256 + threadIdx.x;
    int n = t & 15, e = (t >> 4) & 1023, grp = (t >> 14) & 7, b = t >> 17;
    float A = 1.f, B = 0.f;
    for (int i = 0; i < 8; ++i) {
        int ch = grp * 8 + i;
        size_t idx = ((size_t)((b * NCH + ch) * DI + e)) * 16 + n;
        float a = aprod[idx], bb = bacc[idx];
        A = a * A;
        B = fmaf(a, B, bb);
    }
    size_t g = ((size_t)((b * 8 + grp) * DI + e)) * 16 + n;
    gA[g] = A; gB[g] = B;
}
__global__ __launch_bounds__(256) void scan2b_kernel(
    const float* __restrict__ gA, const float* __restrict__ gB,
    float* __restrict__ ghin) {
    int t = blockIdx.x * 256 + threadIdx.x;
    int n = t & 15, e = (t >> 4) & 1023, b = t >> 14;
    float h = 0.f;
    for (int g = 0; g < 8; ++g) {
        size_t idx = ((size_t)((b * 8 + g) * DI + e)) * 16 + n;
        ghin[idx] = h;
        h = fmaf(gA[idx], h, gB[idx]);
    }
}
// pass C: within-group h_init; hinit overwrites aprod (read-before-write).
__global__ __launch_bounds__(256) void scan2c_kernel(
    const float* __restrict__ ghin, float* aprod_hinit,
    const float* __restrict__ bacc) {
    int t = blockIdx.x * 256 + threadIdx.x;
    int n = t & 15, e = (t >> 4) & 1023, grp = (t >> 14) & 7, b = t >> 17;
    float h = ghin[((size_t)((b * 8 + grp) * DI + e)) * 16 + n];
    for (int i = 0; i < 8; ++i) {
        int ch = grp * 8 + i;
        size_t idx = ((size_t)((b * NCH + ch) * DI + e)) * 16 + n;
        float a = aprod_hinit[idx], bb = bacc[idx];
        aprod_hinit[idx] = h;
        h = fmaf(a, h, bb);
    }
}

// scan3: re-run each chunk from h_init; fuse C-contraction + D-skip + gate.
__global__ __launch_bounds__(256) void scan3_kernel(
    const bf16_t* __restrict__ dbuf, const bf16_t* __restrict__ xcb,
    const bf16_t* __restrict__ zb, const float* __restrict__ bc_in,
    const float* __restrict__ A_log, const float* __restrict__ Dp,
    const float* __restrict__ hinit, bf16_t* __restrict__ yg) {
    int gid  = blockIdx.x * 256 + threadIdx.x;
    int e    = gid >> 1;
    int half = gid & 1;
    int ch = blockIdx.y;
    int b  = blockIdx.z;
    float cAn[8];
#pragma unroll
    for (int n = 0; n < 8; ++n)
        cAn[n] = -expf(A_log[e * 16 + half * 8 + n]) * 1.4426950408889634f;
    float h[8];
    {
        const float4* hp = (const float4*)(hinit +
            ((size_t)((b * NCH + ch) * DI + e)) * 16 + half * 8);
#pragma unroll
        for (int q = 0; q < 2; ++q) {
            float4 v = hp[q];
            h[q * 4] = v.x; h[q * 4 + 1] = v.y; h[q * 4 + 2] = v.z; h[q * 4 + 3] = v.w;
        }
    }
    float Dpe = Dp[e];
    int row0 = b * LSEQ + ch * CHT;
    float d_c  = (float)dbuf[(size_t)row0 * DI + e];
    float xc_c = (float)xcb[(size_t)row0 * 1024 + e];
    float z_c  = (float)zb[(size_t)row0 * 1024 + e];
    for (int t = 0; t < CHT; ++t) {
        int row = row0 + t;
        float d_n = 0.f, xc_n = 0.f, z_n = 0.f;
        if (t + 1 < CHT) {
            d_n  = (float)dbuf[(size_t)(row + 1) * DI + e];
            xc_n = (float)xcb[(size_t)(row + 1) * 1024 + e];
            z_n  = (float)zb[(size_t)(row + 1) * 1024 + e];
        }
        const float* brow = bc_in + (size_t)row * 32;
        float4 b0 = *(const float4*)(brow + half * 8);
        float4 b1 = *(const float4*)(brow + half * 8 + 4);
        float4 c0 = *(const float4*)(brow + 16 + half * 8);
        float4 c1 = *(const float4*)(brow + 16 + half * 8 + 4);
        float Bn[8] = {b0.x, b0.y, b0.z, b0.w, b1.x, b1.y, b1.z, b1.w};
        float Cn[8] = {c0.x, c0.y, c0.z, c0.w, c1.x, c1.y, c1.z, c1.w};
        float dxc_c = d_c * xc_c;
        float y = half ? 0.f : Dpe * xc_c;
#pragma unroll
        for (int n = 0; n < 8; ++n) {
            float dA = exp2f(d_c * cAn[n]);
            h[n] = fmaf(dA, h[n], dxc_c * Bn[n]);
            y = fmaf(h[n], Cn[n], y);
        }
        y += __shfl_xor(y, 1);
        if (half == 0)
            yg[(size_t)row * DI + e] = (bf16_t)(y * siluf(z_c));
        d_c = d_n; xc_c = xc_n; z_c = z_n;
    }
}

extern "C" void kernel_launch(void* const* d_in, const int* in_sizes, int n_in,
                              void* d_out, int out_size, void* d_ws, size_t ws_size,
                              hipStream_t stream) {
    const float* x    = (const float*)d_in[0];
    const float* ipw  = (const float*)d_in[1];
    const float* cw   = (const float*)d_in[2];
    const float* cb   = (const float*)d_in[3];
    const float* xpw  = (const float*)d_in[4];
    const float* dtw  = (const float*)d_in[5];
    const float* dtb  = (const float*)d_in[6];
    const float* alog = (const float*)d_in[7];
    const float* dpar = (const float*)d_in[8];
    const float* opw  = (const float*)d_in[9];
    const float* rmsw = (const float*)d_in[10];
    const float* ln1w = (const float*)d_in[11];
    const float* ln1b = (const float*)d_in[12];
    const float* ln2w = (const float*)d_in[13];
    const float* ln2b = (const float*)d_in[14];
    const float* fw1  = (const float*)d_in[15];
    const float* fb1  = (const float*)d_in[16];
    const float* fw2  = (const float*)d_in[17];
    const float* fb2  = (const float*)d_in[18];
    const float* finw = (const float*)d_in[19];
    const float* finb = (const float*)d_in[20];
    float* out = (float*)d_out;

    // ---- workspace layout (MF = 1M floats = 4MB); ROWSxDI bf16 = 2 MF each
    const size_t MF = 1u << 20;
    float*  ws     = (float*)d_ws;
    float*  h      = ws;                                // 0..2    fp32 ROWSxDM
    bf16_t* hnb    = (bf16_t*)(ws + 2 * MF);            // 2..3    bf16 ROWSxDM
    bf16_t* xrawb  = (bf16_t*)(ws + 3 * MF);            // 3..5    bf16 ROWSxDI
    bf16_t* zb     = (bf16_t*)(ws + 5 * MF);            // 5..7    bf16 ROWSxDI
    bf16_t* xcb    = (bf16_t*)(ws + 7 * MF);            // 7..9    bf16 ROWSxDI (later midb)
    bf16_t* dbufb  = (bf16_t*)(ws + 9 * MF);            // 9..11   bf16 ROWSxDI (later x2)
    bf16_t* spareb = (bf16_t*)(ws + 11 * MF);           // 11..13  (x3b lives here)
    float*  bcbuf  = ws + 13 * MF;                      // 13..13.125 fp32 ROWSx32
    bf16_t* ygb    = (bf16_t*)(ws + 13 * MF + MF / 4);  // 13.25..15.25 bf16 ROWSxDI
    float*  aprod  = ws + 15 * MF + MF / 4;             // 15.25..17.25 (hinit aliases)
    float*  bacc   = ws + 17 * MF + MF / 4;             // 17.25..19.25
    float*  gsA    = ws + 19 * MF + MF / 4;             // 19.25..19.5
    float*  gsB    = ws + 19 * MF + MF / 2;             // 19.5..19.75
    float*  ghin   = ws + 19 * MF + 3 * MF / 4;         // 19.75..20
    bf16_t* warena = (bf16_t*)(ws + 20 * MF);           // 20..23.25 (6.8M bf16)
    // overlays (dead-before-write):
    float*  x2     = (float*)dbufb;                     // dbufb dead after scan3
    bf16_t* midb   = xcb;                               // xcb dead after scan3
    bf16_t* x3b    = spareb;
    float*  hinit  = aprod;                             // scan2c RAW-safe in-place
    const size_t IPW_OFF = 0, OPW_OFF = 2097152, FW1_OFF = 3145728,
                 FW2_OFF = 3670016, FINW_OFF = 4194304, WC_OFF = 4456448;

    // 0. weights -> bf16 arena; both layers' Wcomb (weights-only)
    cvt_kernel<<<17408, 256, 0, stream>>>(ipw, opw, fw1, fw2, finw, warena);
    wd_kernel<<<dim3(NCOMB * 1024 / 256, 2), 256, 0, stream>>>(
        dtw, xpw, warena + WC_OFF);
    // 1. h = LN1(x)
    ln_kernel<<<ROWS, 256, 0, stream>>>(x, ln1w, ln1b, h);

    for (int i = 0; i < 2; ++i) {
        const bf16_t* ipwb_i = warena + IPW_OFF + (size_t)i * 2048 * 512;
        const bf16_t* opwb_i = warena + OPW_OFF + (size_t)i * 512 * 1024;
        const bf16_t* wcombb = warena + WC_OFF + (size_t)i * NCOMB * 1024;
        const float* cw_i   = cw   + (size_t)i * DI * 4;
        const float* cb_i   = cb   + (size_t)i * DI;
        const float* dtb_i  = dtb  + (size_t)i * DI;
        const float* alog_i = alog + (size_t)i * DI * 16;
        const float* dp_i   = dpar + (size_t)i * DI;
        const float* rms_i  = rmsw + (size_t)i * DM;

        // hnb = RMS(h) bf16
        rms_kernel<<<ROWS, 256, 0, stream>>>(h, rms_i, hnb);
        // in_proj (BM=64): cols<1024 -> xrawb bf16, cols>=1024 -> zb bf16
        mgemm_kernel<2, 3, false, false, false><<<1024, 256, 0, stream>>>(
            hnb, ipwb_i, nullptr, nullptr, xrawb, 16, 512, 1024,
            nullptr, zb);
        // xcb = silu(conv(xrawb)) bf16
        conv_silu_kernel<<<ROWS * DI / 256, 256, 0, stream>>>(xrawb, cw_i, cb_i, xcb);
        // combined: d=softplus(.)->dbufb bf16; B/C->bcbuf
        mgemm_kernel<2, 2, false, false, false><<<576, 256, 0, stream>>>(
            xcb, wcombb, dtb_i, nullptr, dbufb, 9, 1024, 1024,
            bcbuf, nullptr);
        // chunked parallel scan (dxc computed on the fly from d, xc)
        scan1_kernel<<<dim3(8, NCH, 2), 256, 0, stream>>>(dbufb, xcb, bcbuf,
                                                          alog_i, aprod, bacc);
        scan2a_kernel<<<1024, 256, 0, stream>>>(aprod, bacc, gsA, gsB);
        scan2b_kernel<<<128, 256, 0, stream>>>(gsA, gsB, ghin);
        scan2c_kernel<<<1024, 256, 0, stream>>>(ghin, aprod, bacc);
        scan3_kernel<<<dim3(8, NCH, 2), 256, 0, stream>>>(dbufb, xcb, zb,
                                                          bcbuf, alog_i, dp_i,
                                                          hinit, ygb);
        // h = h + ygb @ opw^T  (BM=64, 256 blocks)
        mgemm_kernel<2, 0, false, true, false><<<256, 256, 0, stream>>>(
            ygb, opwb_i, nullptr, h, h, 4, 1024, DM,
            nullptr, nullptr);
    }

    // x2 = x + h; hnb = LN2(x2)  (fused; x2 overlays dbufb)
    ln_add_kernel<<<ROWS, 256, 0, stream>>>(x, h, ln2w, ln2b, x2, hnb);
    // mid = relu(hnb @ fw1^T + fb1) bf16 (midb overlays xcb)
    mgemm_kernel<2, 1, true, false, true><<<512, 256, 0, stream>>>(
        hnb, warena + FW1_OFF, fb1, nullptr, midb, 8, 512, DI,
        nullptr, nullptr);
    // x3 = x2 + mid @ fw2^T + fb2  bf16
    mgemm_kernel<2, 0, true, true, true><<<256, 256, 0, stream>>>(
        midb, warena + FW2_OFF, fb2, x2, x3b, 4, 1024, DM,
        nullptr, nullptr);
    // out = x3 @ finw^T + finb  fp32
    mgemm_kernel<2, 0, true, false, false><<<256, 256, 0, stream>>>(
        x3b, warena + FINW_OFF, finb, nullptr, out, 4, 512, DM,
        nullptr, nullptr);
}